// Round 2
// baseline (917.850 us; speedup 1.0000x reference)
//
#include <hip/hip_runtime.h>
#include <hip/hip_bf16.h>
#include <stdint.h>

#define T_LEN 1024
#define HIDN  1024
#define NH    16
#define DKV   64
#define KCONV 4
#define CG_IT 15
#define CC    32              // chunk length
#define NC    (T_LEN / CC)    // 32 chunks

__device__ __forceinline__ float softplusf(float x) {
    return x > 20.f ? x : log1pf(expf(x));
}

// ---------------------------------------------------------------------------
// Tiled GEMM: C[M,N] = A[M,K] @ B[K,N], all fp32.
// BM=BN=64, BK=16, 256 threads, 4x4 micro-tile.
// ---------------------------------------------------------------------------
__global__ __launch_bounds__(256) void gemm64(const float* __restrict__ A,
                                              const float* __restrict__ B,
                                              float* __restrict__ C,
                                              int M, int N, int K)
{
    __shared__ float sA[16][68];
    __shared__ float sB[16][68];
    const int tid = threadIdx.x;
    const int bm = blockIdx.y * 64, bn = blockIdx.x * 64;
    const int tm = tid >> 4, tn = tid & 15;
    const int lam = tid >> 2, lak = (tid & 3) * 4;     // A loader: row, k-offset
    const int lbk = tid >> 4, lbn = (tid & 15) * 4;    // B loader: k, n-offset

    float acc[4][4];
#pragma unroll
    for (int i = 0; i < 4; i++)
#pragma unroll
        for (int j = 0; j < 4; j++) acc[i][j] = 0.f;

    for (int k0 = 0; k0 < K; k0 += 16) {
        float4 a4 = *reinterpret_cast<const float4*>(
            A + (size_t)(bm + lam) * K + k0 + lak);
        sA[lak + 0][lam] = a4.x; sA[lak + 1][lam] = a4.y;
        sA[lak + 2][lam] = a4.z; sA[lak + 3][lam] = a4.w;

        float4 b4 = *reinterpret_cast<const float4*>(
            B + (size_t)(k0 + lbk) * N + bn + lbn);
        *reinterpret_cast<float4*>(&sB[lbk][lbn]) = b4;
        __syncthreads();

#pragma unroll
        for (int kk = 0; kk < 16; kk++) {
            float4 av = *reinterpret_cast<const float4*>(&sA[kk][tm * 4]);
            float4 bv = *reinterpret_cast<const float4*>(&sB[kk][tn * 4]);
            float am[4] = {av.x, av.y, av.z, av.w};
            float bm_[4] = {bv.x, bv.y, bv.z, bv.w};
#pragma unroll
            for (int i = 0; i < 4; i++)
#pragma unroll
                for (int j = 0; j < 4; j++) acc[i][j] += am[i] * bm_[j];
        }
        __syncthreads();
    }

#pragma unroll
    for (int i = 0; i < 4; i++) {
        int m = bm + tm * 4 + i;
        float4 v4 = make_float4(acc[i][0], acc[i][1], acc[i][2], acc[i][3]);
        *reinterpret_cast<float4*>(C + (size_t)m * N + bn + tn * 4) = v4;
    }
}

// ---------------------------------------------------------------------------
// g / beta projections + nonlinearities.  One thread per (token_row, head).
// ---------------------------------------------------------------------------
__global__ __launch_bounds__(256) void proj_gb(const float* __restrict__ hidden,
                                               const float* __restrict__ Wa,
                                               const float* __restrict__ Wb,
                                               const float* __restrict__ bb,
                                               const float* __restrict__ A_log,
                                               const float* __restrict__ dt_bias,
                                               float* __restrict__ g_out,
                                               float* __restrict__ beta_out)
{
    int idx = blockIdx.x * 256 + threadIdx.x;   // over (B*T)*NH = 32768
    int row = idx >> 4, h = idx & 15;
    const float* hr = hidden + (size_t)row * HIDN;
    float da = 0.f, db = 0.f;
    for (int i = 0; i < HIDN; i++) {
        float x = hr[i];
        da += x * Wa[i * NH + h];
        db += x * Wb[i * NH + h];
    }
    float sp = softplusf(da + dt_bias[h]);
    g_out[idx]    = -expf(A_log[h]) * sp;
    beta_out[idx] = 1.f / (1.f + expf(-(db + bb[h])));
}

// ---------------------------------------------------------------------------
// Inclusive cumsum of g over t per (b,h); also transposes beta to [b,h,t].
// ---------------------------------------------------------------------------
__global__ __launch_bounds__(1024) void cumsum_g(const float* __restrict__ g_in,
                                                 const float* __restrict__ beta_in,
                                                 float* __restrict__ G_out,
                                                 float* __restrict__ betaT)
{
    __shared__ float s[1024];
    int bh = blockIdx.x;                 // 0..31
    int b = bh >> 4, h = bh & 15;
    int t = threadIdx.x;
    size_t src = ((size_t)(b * T_LEN) + t) * NH + h;
    s[t] = g_in[src];
    float bt = beta_in[src];
    __syncthreads();
    for (int off = 1; off < 1024; off <<= 1) {
        float tmp = (t >= off) ? s[t - off] : 0.f;
        __syncthreads();
        s[t] += tmp;
        __syncthreads();
    }
    G_out[(size_t)bh * T_LEN + t] = s[t];
    betaT[(size_t)bh * T_LEN + t] = bt;
}

// ---------------------------------------------------------------------------
// causal depthwise conv (K=4) + silu + per-head l2norm.  One wave per (b,t,h).
// ---------------------------------------------------------------------------
__global__ __launch_bounds__(256) void conv_silu_l2(const float* __restrict__ pre,
                                                    const float* __restrict__ Wc,
                                                    float* __restrict__ out)
{
    int gid = blockIdx.x * 4 + (threadIdx.x >> 6);    // 0 .. B*T*NH-1
    int lane = threadIdx.x & 63;
    int h = gid & 15;
    int t = (gid >> 4) & (T_LEN - 1);
    int b = gid >> 14;
    int c = h * DKV + lane;
    float acc = 0.f;
#pragma unroll
    for (int i = 0; i < KCONV; i++) {
        int ts = t - (KCONV - 1) + i;
        if (ts >= 0)
            acc += pre[((size_t)(b * T_LEN) + ts) * HIDN + c] * Wc[c * KCONV + i];
    }
    float y = acc / (1.f + expf(-acc));          // silu
    float ss = y * y;
#pragma unroll
    for (int m = 1; m < 64; m <<= 1) ss += __shfl_xor(ss, m);
    out[((size_t)(b * T_LEN) + t) * HIDN + c] = y * rsqrtf(ss + 1e-6f);
}

// ---------------------------------------------------------------------------
// Sequential pass over chunks: materialize chunk-start Hkk/Hkv states.
// grid = 32 (b,h) * 8 row-groups = 256 blocks; 256 threads.
// ---------------------------------------------------------------------------
__global__ __launch_bounds__(256) void chunk_carry(const float* __restrict__ kbuf,
                                                   const float* __restrict__ vbuf,
                                                   const float* __restrict__ G,
                                                   const float* __restrict__ betaT,
                                                   float* __restrict__ Hkk0,
                                                   float* __restrict__ Hkv0)
{
    __shared__ float sK[CC][64];
    __shared__ float sV[CC][64];
    __shared__ float sW[CC];
    int bid = blockIdx.x;
    int rg = bid & 7, bh = bid >> 3;
    int b = bh >> 4, h = bh & 15;
    int tid = threadIdx.x;

    float ckk[2] = {0.f, 0.f}, ckv[2] = {0.f, 0.f};
    int irow[2], jl[2];
#pragma unroll
    for (int e = 0; e < 2; e++) {
        int idx = tid + e * 256;
        irow[e] = rg * 8 + (idx >> 6);
        jl[e] = idx & 63;
    }

    for (int c = 0; c < NC; c++) {
        int t0 = c * CC;
        // write state at chunk start
#pragma unroll
        for (int e = 0; e < 2; e++) {
            size_t off = (((size_t)(bh * NC) + c) * 64 + irow[e]) * 64 + jl[e];
            Hkk0[off] = ckk[e];
            Hkv0[off] = ckv[e];
        }
        // stage chunk K,V
#pragma unroll
        for (int p = 0; p < 2; p++) {
            int f = tid * 4 + p * 1024;
            int s = f >> 6, d = f & 63;
            size_t ga = (((size_t)(b * T_LEN) + t0 + s) * NH + h) * 64 + d;
            *reinterpret_cast<float4*>(&sK[s][d]) = *reinterpret_cast<const float4*>(&kbuf[ga]);
            *reinterpret_cast<float4*>(&sV[s][d]) = *reinterpret_cast<const float4*>(&vbuf[ga]);
        }
        float Gend  = G[(size_t)bh * T_LEN + t0 + CC - 1];
        float Gprev = (t0 > 0) ? G[(size_t)bh * T_LEN + t0 - 1] : 0.f;
        float dec = expf(Gend - Gprev);
        if (tid < CC) {
            sW[tid] = expf(Gend - G[(size_t)bh * T_LEN + t0 + tid]) *
                      betaT[(size_t)bh * T_LEN + t0 + tid];
        }
        __syncthreads();
#pragma unroll
        for (int e = 0; e < 2; e++) {
            float akk = 0.f, akv = 0.f;
            int i = irow[e], j = jl[e];
            for (int s = 0; s < CC; s++) {
                float w = sW[s];
                float ki = sK[s][i];
                akk += w * ki * sK[s][j];
                akv += w * ki * sV[s][j];
            }
            ckk[e] = dec * ckk[e] + akk;
            ckv[e] = dec * ckv[e] + akv;
        }
        __syncthreads();
    }
}

// ---------------------------------------------------------------------------
// Main chunk kernel: 32 lockstep CG solves + output + RMS norm per block.
// grid = 32 (b,h) * 32 chunks = 1024 blocks; 256 threads = (t=tid>>3, g=tid&7),
// thread owns d in [8g, 8g+8).
// ---------------------------------------------------------------------------
__global__ __launch_bounds__(256) void scan_chunk(const float* __restrict__ qbuf,
                                                  const float* __restrict__ kbuf,
                                                  const float* __restrict__ vbuf,
                                                  const float* __restrict__ G,
                                                  const float* __restrict__ betaT,
                                                  const float* __restrict__ Hkk0,
                                                  const float* __restrict__ Hkv0,
                                                  const float* __restrict__ lambda_p,
                                                  const float* __restrict__ norm_w,
                                                  float* __restrict__ o_out)
{
    __shared__ float sK[CC][64];
    __shared__ float sV[CC][64];
    __shared__ float sP[CC][64];
    __shared__ float sM[CC][CC];
    __shared__ float sCo[CC][CC];
    __shared__ float sH[64 * 64];
    __shared__ float sLam[64];
    __shared__ float sE[CC];
    __shared__ float sGl[CC];
    __shared__ float sBt[CC];

    int bid = blockIdx.x;
    int chunk = bid & (NC - 1);
    int bh = bid >> 5;
    int b = bh >> 4, h = bh & 15;
    int tid = threadIdx.x;
    int t = tid >> 3, g8 = tid & 7, d0 = g8 * 8;
    int t0 = chunk * CC;

    size_t rowb = (((size_t)(b * T_LEN) + t0 + t) * NH + h) * 64;

    float x[8], r[8];
    {
        float4 k0v = *reinterpret_cast<const float4*>(&kbuf[rowb + d0]);
        float4 k1v = *reinterpret_cast<const float4*>(&kbuf[rowb + d0 + 4]);
        *reinterpret_cast<float4*>(&sK[t][d0]) = k0v;
        *reinterpret_cast<float4*>(&sK[t][d0 + 4]) = k1v;
        float4 v0v = *reinterpret_cast<const float4*>(&vbuf[rowb + d0]);
        float4 v1v = *reinterpret_cast<const float4*>(&vbuf[rowb + d0 + 4]);
        *reinterpret_cast<float4*>(&sV[t][d0]) = v0v;
        *reinterpret_cast<float4*>(&sV[t][d0 + 4]) = v1v;
        float4 q0 = *reinterpret_cast<const float4*>(&qbuf[rowb + d0]);
        float4 q1 = *reinterpret_cast<const float4*>(&qbuf[rowb + d0 + 4]);
        r[0] = q0.x; r[1] = q0.y; r[2] = q0.z; r[3] = q0.w;
        r[4] = q1.x; r[5] = q1.y; r[6] = q1.z; r[7] = q1.w;
#pragma unroll
        for (int j = 0; j < 8; j++) x[j] = 0.f;
        *reinterpret_cast<float4*>(&sP[t][d0]) = q0;
        *reinterpret_cast<float4*>(&sP[t][d0 + 4]) = q1;
    }
    {
        size_t hb = ((size_t)(bh * NC) + chunk) * 4096;
#pragma unroll
        for (int p = 0; p < 4; p++) {
            int f = p * 1024 + tid * 4;
            *reinterpret_cast<float4*>(&sH[f]) =
                *reinterpret_cast<const float4*>(&Hkk0[hb + f]);
        }
    }
    if (tid < 64) sLam[tid] = softplusf(lambda_p[h * 64 + tid]) + 0.25f;
    if (tid < CC) {
        float Gv = G[(size_t)bh * T_LEN + t0 + tid];
        sGl[tid] = Gv;
        float Gprev = (t0 > 0) ? G[(size_t)bh * T_LEN + t0 - 1] : 0.f;
        sE[tid] = expf(Gv - Gprev);
        sBt[tid] = betaT[(size_t)bh * T_LEN + t0 + tid];
    }
    __syncthreads();

    // causal decay/beta coefficient matrix
#pragma unroll
    for (int si = 0; si < 4; si++) {
        int s = g8 * 4 + si;
        sCo[t][s] = (s <= t) ? expf(sGl[t] - sGl[s]) * sBt[s] : 0.f;
    }
    float rs;
    {
        float pr = 0.f;
#pragma unroll
        for (int j = 0; j < 8; j++) pr += r[j] * r[j];
        pr += __shfl_xor(pr, 1); pr += __shfl_xor(pr, 2); pr += __shfl_xor(pr, 4);
        rs = pr;
    }
    __syncthreads();
    float e_t = sE[t];

    for (int it = 0; it < CG_IT; it++) {
        // ---- M[t][s] = Co[t][s] * <P[t], K[s]> ----
#pragma unroll
        for (int si = 0; si < 4; si++) {
            int s = g8 * 4 + si;
            const float4* pr4 = reinterpret_cast<const float4*>(&sP[t][0]);
            const float4* kr4 = reinterpret_cast<const float4*>(&sK[s][0]);
            float acc = 0.f;
#pragma unroll
            for (int j = 0; j < 16; j++) {
                float4 a = pr4[j], bq = kr4[j];
                acc += a.x * bq.x + a.y * bq.y + a.z * bq.z + a.w * bq.w;
            }
            sM[t][s] = sCo[t][s] * acc;
        }
        __syncthreads();
        // ---- AP = lam*p + M@K + e_t * (P @ Hkk0) ----
        float ap[8];
#pragma unroll
        for (int j = 0; j < 8; j++) ap[j] = sLam[d0 + j] * sP[t][d0 + j];
        for (int s = 0; s < CC; s++) {
            float m = sM[t][s];
            float4 ka = *reinterpret_cast<const float4*>(&sK[s][d0]);
            float4 kb = *reinterpret_cast<const float4*>(&sK[s][d0 + 4]);
            ap[0] += m * ka.x; ap[1] += m * ka.y; ap[2] += m * ka.z; ap[3] += m * ka.w;
            ap[4] += m * kb.x; ap[5] += m * kb.y; ap[6] += m * kb.z; ap[7] += m * kb.w;
        }
        float a2[8];
#pragma unroll
        for (int j = 0; j < 8; j++) a2[j] = 0.f;
        for (int j = 0; j < 64; j++) {
            float pj = sP[t][j];
            float4 ha = *reinterpret_cast<const float4*>(&sH[j * 64 + d0]);
            float4 hb = *reinterpret_cast<const float4*>(&sH[j * 64 + d0 + 4]);
            a2[0] += pj * ha.x; a2[1] += pj * ha.y; a2[2] += pj * ha.z; a2[3] += pj * ha.w;
            a2[4] += pj * hb.x; a2[5] += pj * hb.y; a2[6] += pj * hb.z; a2[7] += pj * hb.w;
        }
#pragma unroll
        for (int j = 0; j < 8; j++) ap[j] += e_t * a2[j];
        // ---- scalars ----
        float pap = 0.f;
        float pold[8];
#pragma unroll
        for (int j = 0; j < 8; j++) {
            pold[j] = sP[t][d0 + j];
            pap += pold[j] * ap[j];
        }
        pap += __shfl_xor(pap, 1); pap += __shfl_xor(pap, 2); pap += __shfl_xor(pap, 4);
        float alpha = rs / (pap + 1e-12f);
        float rsn = 0.f;
#pragma unroll
        for (int j = 0; j < 8; j++) {
            x[j] += alpha * pold[j];
            r[j] -= alpha * ap[j];
            rsn += r[j] * r[j];
        }
        rsn += __shfl_xor(rsn, 1); rsn += __shfl_xor(rsn, 2); rsn += __shfl_xor(rsn, 4);
        float btac = rsn / (rs + 1e-12f);
        rs = rsn;
        __syncthreads();            // all reads of sP done
#pragma unroll
        for (int j = 0; j < 8; j++) sP[t][d0 + j] = r[j] + btac * pold[j];
        __syncthreads();
    }

    // ---- output phase: sP <- X, sH <- Hkv0 ----
#pragma unroll
    for (int j = 0; j < 8; j++) sP[t][d0 + j] = x[j];
    {
        size_t hb = ((size_t)(bh * NC) + chunk) * 4096;
#pragma unroll
        for (int p = 0; p < 4; p++) {
            int f = p * 1024 + tid * 4;
            *reinterpret_cast<float4*>(&sH[f]) =
                *reinterpret_cast<const float4*>(&Hkv0[hb + f]);
        }
    }
    __syncthreads();
#pragma unroll
    for (int si = 0; si < 4; si++) {
        int s = g8 * 4 + si;
        const float4* xr4 = reinterpret_cast<const float4*>(&sP[t][0]);
        const float4* kr4 = reinterpret_cast<const float4*>(&sK[s][0]);
        float acc = 0.f;
#pragma unroll
        for (int j = 0; j < 16; j++) {
            float4 a = xr4[j], bq = kr4[j];
            acc += a.x * bq.x + a.y * bq.y + a.z * bq.z + a.w * bq.w;
        }
        sM[t][s] = sCo[t][s] * acc;
    }
    __syncthreads();
    float o[8];
#pragma unroll
    for (int j = 0; j < 8; j++) o[j] = 0.f;
    for (int s = 0; s < CC; s++) {
        float m = sM[t][s];
        float4 va = *reinterpret_cast<const float4*>(&sV[s][d0]);
        float4 vb = *reinterpret_cast<const float4*>(&sV[s][d0 + 4]);
        o[0] += m * va.x; o[1] += m * va.y; o[2] += m * va.z; o[3] += m * va.w;
        o[4] += m * vb.x; o[5] += m * vb.y; o[6] += m * vb.z; o[7] += m * vb.w;
    }
    float a2[8];
#pragma unroll
    for (int j = 0; j < 8; j++) a2[j] = 0.f;
    for (int j = 0; j < 64; j++) {
        float xj = sP[t][j];
        float4 ha = *reinterpret_cast<const float4*>(&sH[j * 64 + d0]);
        float4 hb = *reinterpret_cast<const float4*>(&sH[j * 64 + d0 + 4]);
        a2[0] += xj * ha.x; a2[1] += xj * ha.y; a2[2] += xj * ha.z; a2[3] += xj * ha.w;
        a2[4] += xj * hb.x; a2[5] += xj * hb.y; a2[6] += xj * hb.z; a2[7] += xj * hb.w;
    }
#pragma unroll
    for (int j = 0; j < 8; j++) o[j] += e_t * a2[j];
    // RMS norm over dv
    float ss = 0.f;
#pragma unroll
    for (int j = 0; j < 8; j++) ss += o[j] * o[j];
    ss += __shfl_xor(ss, 1); ss += __shfl_xor(ss, 2); ss += __shfl_xor(ss, 4);
    float scale = rsqrtf(ss * (1.f / 64.f) + 1e-5f);
#pragma unroll
    for (int j = 0; j < 8; j++) o[j] *= scale * norm_w[d0 + j];
    float4 o0 = make_float4(o[0], o[1], o[2], o[3]);
    float4 o1 = make_float4(o[4], o[5], o[6], o[7]);
    *reinterpret_cast<float4*>(&o_out[rowb + d0]) = o0;
    *reinterpret_cast<float4*>(&o_out[rowb + d0 + 4]) = o1;
}

// ---------------------------------------------------------------------------
extern "C" void kernel_launch(void* const* d_in, const int* in_sizes, int n_in,
                              void* d_out, int out_size, void* d_ws, size_t ws_size,
                              hipStream_t stream)
{
    const float* hidden   = (const float*)d_in[0];
    const float* Wq       = (const float*)d_in[1];
    const float* Wk       = (const float*)d_in[2];
    const float* Wv       = (const float*)d_in[3];
    const float* Wa       = (const float*)d_in[4];
    const float* Wb       = (const float*)d_in[5];
    const float* bb       = (const float*)d_in[6];
    const float* A_log    = (const float*)d_in[7];
    const float* dt_bias  = (const float*)d_in[8];
    const float* lambda_p = (const float*)d_in[9];
    const float* Wconv_q  = (const float*)d_in[10];
    const float* Wconv_k  = (const float*)d_in[11];
    const float* norm_w   = (const float*)d_in[12];
    const float* Wo       = (const float*)d_in[13];
    float* out = (float*)d_out;

    float* ws = (float*)d_ws;
    const size_t SZ_BIG = (size_t)2 * T_LEN * HIDN;   // 2M floats
    float* qpre = ws;
    float* kpre = qpre + SZ_BIG;
    float* vbuf = kpre + SZ_BIG;
    float* qbuf = vbuf + SZ_BIG;
    float* kbuf = qbuf + SZ_BIG;
    float* gbuf = kbuf + SZ_BIG;                      // 32768
    float* bbuf = gbuf + 32768;
    float* Gbuf = bbuf + 32768;
    float* btT  = Gbuf + 32768;
    float* Hkk0 = btT + 32768;                        // 32*NC*4096 = 4M floats
    float* Hkv0 = Hkk0 + (size_t)32 * NC * 4096;
    float* obuf = qpre;                               // reuse (qpre dead after conv)

    dim3 gg(HIDN / 64, (2 * T_LEN) / 64);             // (16, 32)
    gemm64<<<gg, 256, 0, stream>>>(hidden, Wq, qpre, 2 * T_LEN, HIDN, HIDN);
    gemm64<<<gg, 256, 0, stream>>>(hidden, Wk, kpre, 2 * T_LEN, HIDN, HIDN);
    gemm64<<<gg, 256, 0, stream>>>(hidden, Wv, vbuf, 2 * T_LEN, HIDN, HIDN);
    proj_gb<<<128, 256, 0, stream>>>(hidden, Wa, Wb, bb, A_log, dt_bias, gbuf, bbuf);
    cumsum_g<<<32, 1024, 0, stream>>>(gbuf, bbuf, Gbuf, btT);
    conv_silu_l2<<<2 * T_LEN * NH / 4, 256, 0, stream>>>(qpre, Wconv_q, qbuf);
    conv_silu_l2<<<2 * T_LEN * NH / 4, 256, 0, stream>>>(kpre, Wconv_k, kbuf);
    chunk_carry<<<256, 256, 0, stream>>>(kbuf, vbuf, Gbuf, btT, Hkk0, Hkv0);
    scan_chunk<<<1024, 256, 0, stream>>>(qbuf, kbuf, vbuf, Gbuf, btT, Hkk0, Hkv0,
                                         lambda_p, norm_w, obuf);
    gemm64<<<gg, 256, 0, stream>>>(obuf, Wo, out, 2 * T_LEN, HIDN, HIDN);
}

// Round 3
// 693.676 us; speedup vs baseline: 1.3232x; 1.3232x over previous
//
#include <hip/hip_runtime.h>
#include <hip/hip_bf16.h>
#include <stdint.h>

#define T_LEN 1024
#define HIDN  1024
#define NH    16
#define DKV   64
#define KCONV 4
#define CG_IT 15
#define CC    32              // chunk length
#define NC    (T_LEN / CC)    // 32 chunks
#define PAD   68              // padded row stride: (68t+j)%32 = (4t+j)%32 -> conflict-free

__device__ __forceinline__ float softplusf(float x) {
    return x > 20.f ? x : log1pf(expf(x));
}

// ---------------------------------------------------------------------------
// Tiled GEMM: C[M,N] = A[M,K] @ B[K,N], all fp32.
// BM=BN=64, BK=16, 256 threads, 4x4 micro-tile.
// ---------------------------------------------------------------------------
__global__ __launch_bounds__(256) void gemm64(const float* __restrict__ A,
                                              const float* __restrict__ B,
                                              float* __restrict__ C,
                                              int M, int N, int K)
{
    __shared__ float sA[16][68];
    __shared__ float sB[16][68];
    const int tid = threadIdx.x;
    const int bm = blockIdx.y * 64, bn = blockIdx.x * 64;
    const int tm = tid >> 4, tn = tid & 15;
    const int lam = tid >> 2, lak = (tid & 3) * 4;
    const int lbk = tid >> 4, lbn = (tid & 15) * 4;

    float acc[4][4];
#pragma unroll
    for (int i = 0; i < 4; i++)
#pragma unroll
        for (int j = 0; j < 4; j++) acc[i][j] = 0.f;

    for (int k0 = 0; k0 < K; k0 += 16) {
        float4 a4 = *reinterpret_cast<const float4*>(
            A + (size_t)(bm + lam) * K + k0 + lak);
        sA[lak + 0][lam] = a4.x; sA[lak + 1][lam] = a4.y;
        sA[lak + 2][lam] = a4.z; sA[lak + 3][lam] = a4.w;

        float4 b4 = *reinterpret_cast<const float4*>(
            B + (size_t)(k0 + lbk) * N + bn + lbn);
        *reinterpret_cast<float4*>(&sB[lbk][lbn]) = b4;
        __syncthreads();

#pragma unroll
        for (int kk = 0; kk < 16; kk++) {
            float4 av = *reinterpret_cast<const float4*>(&sA[kk][tm * 4]);
            float4 bv = *reinterpret_cast<const float4*>(&sB[kk][tn * 4]);
            float am[4] = {av.x, av.y, av.z, av.w};
            float bm_[4] = {bv.x, bv.y, bv.z, bv.w};
#pragma unroll
            for (int i = 0; i < 4; i++)
#pragma unroll
                for (int j = 0; j < 4; j++) acc[i][j] += am[i] * bm_[j];
        }
        __syncthreads();
    }

#pragma unroll
    for (int i = 0; i < 4; i++) {
        int m = bm + tm * 4 + i;
        float4 v4 = make_float4(acc[i][0], acc[i][1], acc[i][2], acc[i][3]);
        *reinterpret_cast<float4*>(C + (size_t)m * N + bn + tn * 4) = v4;
    }
}

// ---------------------------------------------------------------------------
// g / beta projections + nonlinearities.  One thread per (token_row, head).
// ---------------------------------------------------------------------------
__global__ __launch_bounds__(256) void proj_gb(const float* __restrict__ hidden,
                                               const float* __restrict__ Wa,
                                               const float* __restrict__ Wb,
                                               const float* __restrict__ bb,
                                               const float* __restrict__ A_log,
                                               const float* __restrict__ dt_bias,
                                               float* __restrict__ g_out,
                                               float* __restrict__ beta_out)
{
    int idx = blockIdx.x * 256 + threadIdx.x;   // over (B*T)*NH = 32768
    int row = idx >> 4, h = idx & 15;
    const float* hr = hidden + (size_t)row * HIDN;
    float da = 0.f, db = 0.f;
    for (int i = 0; i < HIDN; i++) {
        float x = hr[i];
        da += x * Wa[i * NH + h];
        db += x * Wb[i * NH + h];
    }
    float sp = softplusf(da + dt_bias[h]);
    g_out[idx]    = -expf(A_log[h]) * sp;
    beta_out[idx] = 1.f / (1.f + expf(-(db + bb[h])));
}

// ---------------------------------------------------------------------------
// Inclusive cumsum of g over t per (b,h); also transposes beta to [b,h,t].
// ---------------------------------------------------------------------------
__global__ __launch_bounds__(1024) void cumsum_g(const float* __restrict__ g_in,
                                                 const float* __restrict__ beta_in,
                                                 float* __restrict__ G_out,
                                                 float* __restrict__ betaT)
{
    __shared__ float s[1024];
    int bh = blockIdx.x;                 // 0..31
    int b = bh >> 4, h = bh & 15;
    int t = threadIdx.x;
    size_t src = ((size_t)(b * T_LEN) + t) * NH + h;
    s[t] = g_in[src];
    float bt = beta_in[src];
    __syncthreads();
    for (int off = 1; off < 1024; off <<= 1) {
        float tmp = (t >= off) ? s[t - off] : 0.f;
        __syncthreads();
        s[t] += tmp;
        __syncthreads();
    }
    G_out[(size_t)bh * T_LEN + t] = s[t];
    betaT[(size_t)bh * T_LEN + t] = bt;
}

// ---------------------------------------------------------------------------
// causal depthwise conv (K=4) + silu + per-head l2norm.  One wave per (b,t,h).
// ---------------------------------------------------------------------------
__global__ __launch_bounds__(256) void conv_silu_l2(const float* __restrict__ pre,
                                                    const float* __restrict__ Wc,
                                                    float* __restrict__ out)
{
    int gid = blockIdx.x * 4 + (threadIdx.x >> 6);    // 0 .. B*T*NH-1
    int lane = threadIdx.x & 63;
    int h = gid & 15;
    int t = (gid >> 4) & (T_LEN - 1);
    int b = gid >> 14;
    int c = h * DKV + lane;
    float acc = 0.f;
#pragma unroll
    for (int i = 0; i < KCONV; i++) {
        int ts = t - (KCONV - 1) + i;
        if (ts >= 0)
            acc += pre[((size_t)(b * T_LEN) + ts) * HIDN + c] * Wc[c * KCONV + i];
    }
    float y = acc / (1.f + expf(-acc));          // silu
    float ss = y * y;
#pragma unroll
    for (int m = 1; m < 64; m <<= 1) ss += __shfl_xor(ss, m);
    out[((size_t)(b * T_LEN) + t) * HIDN + c] = y * rsqrtf(ss + 1e-6f);
}

// ---------------------------------------------------------------------------
// Sequential pass over chunks: materialize chunk-start Hkk/Hkv states.
// grid = 32 (b,h) * 2 row-halves = 64 blocks; 256 threads.
// Register double-buffering of next chunk's K/V/G/beta.
// ---------------------------------------------------------------------------
__global__ __launch_bounds__(256) void chunk_carry(const float* __restrict__ kbuf,
                                                   const float* __restrict__ vbuf,
                                                   const float* __restrict__ G,
                                                   const float* __restrict__ betaT,
                                                   float* __restrict__ Hkk0,
                                                   float* __restrict__ Hkv0)
{
    __shared__ float sK[CC][PAD];
    __shared__ float sV[CC][PAD];
    __shared__ float sW[CC];
    int bid = blockIdx.x;                 // 64 blocks
    int bh = bid >> 1, half = bid & 1;
    int b = bh >> 4, h = bh & 15;
    int tid = threadIdx.x;
    int i = half * 32 + (tid >> 3);       // row index 0..63
    int j0 = (tid & 7) * 8;               // column group

    // loader mapping: thread loads 32B (2 float4) of one row per matrix
    int ls = tid >> 3;                    // staging row 0..31
    int ld = (tid & 7) * 8;               // staging col
    const float* Gb  = G + (size_t)bh * T_LEN;
    const float* Btb = betaT + (size_t)bh * T_LEN;

    float ckk[8], ckv[8];
#pragma unroll
    for (int j = 0; j < 8; j++) { ckk[j] = 0.f; ckv[j] = 0.f; }

    // stage chunk 0
    {
        size_t ga = (((size_t)(b * T_LEN) + ls) * NH + h) * 64 + ld;
        *reinterpret_cast<float4*>(&sK[ls][ld])     = *reinterpret_cast<const float4*>(&kbuf[ga]);
        *reinterpret_cast<float4*>(&sK[ls][ld + 4]) = *reinterpret_cast<const float4*>(&kbuf[ga + 4]);
        *reinterpret_cast<float4*>(&sV[ls][ld])     = *reinterpret_cast<const float4*>(&vbuf[ga]);
        *reinterpret_cast<float4*>(&sV[ls][ld + 4]) = *reinterpret_cast<const float4*>(&vbuf[ga + 4]);
        if (tid < CC) {
            float gv = Gb[tid];
            float bv = Btb[tid];
            float gend = __shfl(gv, 31);
            sW[tid] = expf(gend - gv) * bv;
        }
    }
    __syncthreads();

    for (int c = 0; c < NC; c++) {
        int t0 = c * CC;
        // write chunk-start state
        size_t ob = (((size_t)(bh * NC) + c) * 64 + i) * 64 + j0;
        *reinterpret_cast<float4*>(&Hkk0[ob])     = make_float4(ckk[0], ckk[1], ckk[2], ckk[3]);
        *reinterpret_cast<float4*>(&Hkk0[ob + 4]) = make_float4(ckk[4], ckk[5], ckk[6], ckk[7]);
        *reinterpret_cast<float4*>(&Hkv0[ob])     = make_float4(ckv[0], ckv[1], ckv[2], ckv[3]);
        *reinterpret_cast<float4*>(&Hkv0[ob + 4]) = make_float4(ckv[4], ckv[5], ckv[6], ckv[7]);

        // prefetch next chunk into registers
        float4 kf0, kf1, vf0, vf1;
        float gnv = 0.f, bnv = 0.f;
        if (c + 1 < NC) {
            int t0n = t0 + CC;
            size_t ga = (((size_t)(b * T_LEN) + t0n + ls) * NH + h) * 64 + ld;
            kf0 = *reinterpret_cast<const float4*>(&kbuf[ga]);
            kf1 = *reinterpret_cast<const float4*>(&kbuf[ga + 4]);
            vf0 = *reinterpret_cast<const float4*>(&vbuf[ga]);
            vf1 = *reinterpret_cast<const float4*>(&vbuf[ga + 4]);
            if (tid < CC) { gnv = Gb[t0n + tid]; bnv = Btb[t0n + tid]; }
        }

        float gend  = Gb[t0 + CC - 1];
        float gprev = (t0 > 0) ? Gb[t0 - 1] : 0.f;
        float dec = expf(gend - gprev);

        float akk[8], akv[8];
#pragma unroll
        for (int j = 0; j < 8; j++) { akk[j] = 0.f; akv[j] = 0.f; }
#pragma unroll 4
        for (int s = 0; s < CC; s++) {
            float wk = sW[s] * sK[s][i];
            float4 ka = *reinterpret_cast<const float4*>(&sK[s][j0]);
            float4 kb = *reinterpret_cast<const float4*>(&sK[s][j0 + 4]);
            float4 va = *reinterpret_cast<const float4*>(&sV[s][j0]);
            float4 vb = *reinterpret_cast<const float4*>(&sV[s][j0 + 4]);
            akk[0] += wk * ka.x; akk[1] += wk * ka.y; akk[2] += wk * ka.z; akk[3] += wk * ka.w;
            akk[4] += wk * kb.x; akk[5] += wk * kb.y; akk[6] += wk * kb.z; akk[7] += wk * kb.w;
            akv[0] += wk * va.x; akv[1] += wk * va.y; akv[2] += wk * va.z; akv[3] += wk * va.w;
            akv[4] += wk * vb.x; akv[5] += wk * vb.y; akv[6] += wk * vb.z; akv[7] += wk * vb.w;
        }
#pragma unroll
        for (int j = 0; j < 8; j++) {
            ckk[j] = dec * ckk[j] + akk[j];
            ckv[j] = dec * ckv[j] + akv[j];
        }
        __syncthreads();
        if (c + 1 < NC) {
            *reinterpret_cast<float4*>(&sK[ls][ld])     = kf0;
            *reinterpret_cast<float4*>(&sK[ls][ld + 4]) = kf1;
            *reinterpret_cast<float4*>(&sV[ls][ld])     = vf0;
            *reinterpret_cast<float4*>(&sV[ls][ld + 4]) = vf1;
            if (tid < CC) {
                float gendn = __shfl(gnv, 31);
                sW[tid] = expf(gendn - gnv) * bnv;
            }
            __syncthreads();
        }
    }
}

// ---------------------------------------------------------------------------
// Main chunk kernel: 32 lockstep CG solves + output + RMS norm per block.
// grid = 1024 blocks (32 bh x 32 chunks); 256 threads = (t=tid>>3, g8=tid&7).
// All cross-thread traffic inside the CG loop is intra-wave -> no barriers.
// ---------------------------------------------------------------------------
__global__ __launch_bounds__(256) void scan_chunk(const float* __restrict__ qbuf,
                                                  const float* __restrict__ kbuf,
                                                  const float* __restrict__ vbuf,
                                                  const float* __restrict__ G,
                                                  const float* __restrict__ betaT,
                                                  const float* __restrict__ Hkk0,
                                                  const float* __restrict__ Hkv0,
                                                  const float* __restrict__ lambda_p,
                                                  const float* __restrict__ norm_w,
                                                  float* __restrict__ o_out)
{
    __shared__ float sK[CC][PAD];        // K rows; later overlaid with V
    __shared__ float sP[CC][PAD];        // CG direction p; later X
    __shared__ float sH[64 * 64];        // Hkk0; later Hkv0
    __shared__ float sCo[CC][36];        // causal decay*beta coefficients
    __shared__ float sGl[CC];
    __shared__ float sBt[CC];
    __shared__ float sE[CC];

    int bid = blockIdx.x;
    int chunk = bid & (NC - 1);
    int bh = bid >> 5;
    int b = bh >> 4, h = bh & 15;
    int tid = threadIdx.x;
    int t = tid >> 3, g8 = tid & 7, d0 = g8 * 8;
    int t0 = chunk * CC;

    size_t rowb = (((size_t)(b * T_LEN) + t0 + t) * NH + h) * 64;

    float p[8], r[8], x[8], lamr[8], nw[8];
    {
        float4 k0 = *reinterpret_cast<const float4*>(&kbuf[rowb + d0]);
        float4 k1 = *reinterpret_cast<const float4*>(&kbuf[rowb + d0 + 4]);
        *reinterpret_cast<float4*>(&sK[t][d0])     = k0;
        *reinterpret_cast<float4*>(&sK[t][d0 + 4]) = k1;
        float4 q0 = *reinterpret_cast<const float4*>(&qbuf[rowb + d0]);
        float4 q1 = *reinterpret_cast<const float4*>(&qbuf[rowb + d0 + 4]);
        *reinterpret_cast<float4*>(&sP[t][d0])     = q0;
        *reinterpret_cast<float4*>(&sP[t][d0 + 4]) = q1;
        p[0] = q0.x; p[1] = q0.y; p[2] = q0.z; p[3] = q0.w;
        p[4] = q1.x; p[5] = q1.y; p[6] = q1.z; p[7] = q1.w;
#pragma unroll
        for (int j = 0; j < 8; j++) { r[j] = p[j]; x[j] = 0.f; }
    }
#pragma unroll
    for (int j = 0; j < 8; j++) {
        lamr[j] = softplusf(lambda_p[h * 64 + d0 + j]) + 0.25f;
        nw[j]   = norm_w[d0 + j];
    }
    size_t hb = ((size_t)(bh * NC) + chunk) * 4096;
#pragma unroll
    for (int pp = 0; pp < 4; pp++) {
        int f = pp * 1024 + tid * 4;
        *reinterpret_cast<float4*>(&sH[f]) = *reinterpret_cast<const float4*>(&Hkk0[hb + f]);
    }
    if (tid < CC) {
        float Gv = G[(size_t)bh * T_LEN + t0 + tid];
        sGl[tid] = Gv;
        float Gp = (t0 > 0) ? G[(size_t)bh * T_LEN + t0 - 1] : 0.f;
        sE[tid] = expf(Gv - Gp);
        sBt[tid] = betaT[(size_t)bh * T_LEN + t0 + tid];
    }
    __syncthreads();

    // coefficient row t (intra-wave producer/consumer)
    {
        float gl_t = sGl[t];
#pragma unroll
        for (int si = 0; si < 4; si++) {
            int s = si * 8 + g8;
            sCo[t][s] = (s <= t) ? expf(gl_t - sGl[s]) * sBt[s] : 0.f;
        }
    }
    float e_t = sE[t];
    __threadfence_block();

    float rs;
    {
        float pr = 0.f;
#pragma unroll
        for (int j = 0; j < 8; j++) pr += r[j] * r[j];
        pr += __shfl_xor(pr, 1); pr += __shfl_xor(pr, 2); pr += __shfl_xor(pr, 4);
        rs = pr;
    }

    for (int it = 0; it < CG_IT; it++) {
        float ap[8];
#pragma unroll
        for (int j = 0; j < 8; j++) ap[j] = lamr[j] * p[j];
        // fused: dot = <P_t,K_s> (coop over g8), m = Co*dot, ap += m*K_s
#pragma unroll 4
        for (int s = 0; s < CC; s++) {
            float4 ka = *reinterpret_cast<const float4*>(&sK[s][d0]);
            float4 kb = *reinterpret_cast<const float4*>(&sK[s][d0 + 4]);
            float dot = p[0] * ka.x + p[1] * ka.y + p[2] * ka.z + p[3] * ka.w
                      + p[4] * kb.x + p[5] * kb.y + p[6] * kb.z + p[7] * kb.w;
            dot += __shfl_xor(dot, 1); dot += __shfl_xor(dot, 2); dot += __shfl_xor(dot, 4);
            float m = sCo[t][s] * dot;
            ap[0] += m * ka.x; ap[1] += m * ka.y; ap[2] += m * ka.z; ap[3] += m * ka.w;
            ap[4] += m * kb.x; ap[5] += m * kb.y; ap[6] += m * kb.z; ap[7] += m * kb.w;
        }
        // ap += e_t * (P_t @ Hkk0)
        float a2[8];
#pragma unroll
        for (int j = 0; j < 8; j++) a2[j] = 0.f;
#pragma unroll 8
        for (int j = 0; j < 64; j++) {
            float pj = sP[t][j];
            float4 ha = *reinterpret_cast<const float4*>(&sH[j * 64 + d0]);
            float4 hc = *reinterpret_cast<const float4*>(&sH[j * 64 + d0 + 4]);
            a2[0] += pj * ha.x; a2[1] += pj * ha.y; a2[2] += pj * ha.z; a2[3] += pj * ha.w;
            a2[4] += pj * hc.x; a2[5] += pj * hc.y; a2[6] += pj * hc.z; a2[7] += pj * hc.w;
        }
#pragma unroll
        for (int j = 0; j < 8; j++) ap[j] += e_t * a2[j];
        // CG scalars
        float pap = 0.f;
#pragma unroll
        for (int j = 0; j < 8; j++) pap += p[j] * ap[j];
        pap += __shfl_xor(pap, 1); pap += __shfl_xor(pap, 2); pap += __shfl_xor(pap, 4);
        float alpha = rs / (pap + 1e-12f);
        float rsn = 0.f;
#pragma unroll
        for (int j = 0; j < 8; j++) {
            x[j] += alpha * p[j];
            r[j] -= alpha * ap[j];
            rsn += r[j] * r[j];
        }
        rsn += __shfl_xor(rsn, 1); rsn += __shfl_xor(rsn, 2); rsn += __shfl_xor(rsn, 4);
        float btac = rsn / (rs + 1e-12f);
        rs = rsn;
#pragma unroll
        for (int j = 0; j < 8; j++) p[j] = r[j] + btac * p[j];
        *reinterpret_cast<float4*>(&sP[t][d0])     = make_float4(p[0], p[1], p[2], p[3]);
        *reinterpret_cast<float4*>(&sP[t][d0 + 4]) = make_float4(p[4], p[5], p[6], p[7]);
        __threadfence_block();
    }

    // ---- output phase ----
    // m_out[s] = Co[t][s] * <X_t, K_s>, kept in registers (lane g8 holds s=g8 mod 8)
    float mreg[4];
#pragma unroll 4
    for (int s = 0; s < CC; s++) {
        float4 ka = *reinterpret_cast<const float4*>(&sK[s][d0]);
        float4 kb = *reinterpret_cast<const float4*>(&sK[s][d0 + 4]);
        float dot = x[0] * ka.x + x[1] * ka.y + x[2] * ka.z + x[3] * ka.w
                  + x[4] * kb.x + x[5] * kb.y + x[6] * kb.z + x[7] * kb.w;
        dot += __shfl_xor(dot, 1); dot += __shfl_xor(dot, 2); dot += __shfl_xor(dot, 4);
        float m = sCo[t][s] * dot;
        if ((s & 7) == g8) mreg[s >> 3] = m;
    }
    // X into sP
    *reinterpret_cast<float4*>(&sP[t][d0])     = make_float4(x[0], x[1], x[2], x[3]);
    *reinterpret_cast<float4*>(&sP[t][d0 + 4]) = make_float4(x[4], x[5], x[6], x[7]);
    __syncthreads();                    // all waves done with sK (K) reads
    // overlay V into sK storage, Hkv0 into sH
    {
        float4 v0 = *reinterpret_cast<const float4*>(&vbuf[rowb + d0]);
        float4 v1 = *reinterpret_cast<const float4*>(&vbuf[rowb + d0 + 4]);
        *reinterpret_cast<float4*>(&sK[t][d0])     = v0;
        *reinterpret_cast<float4*>(&sK[t][d0 + 4]) = v1;
    }
#pragma unroll
    for (int pp = 0; pp < 4; pp++) {
        int f = pp * 1024 + tid * 4;
        *reinterpret_cast<float4*>(&sH[f]) = *reinterpret_cast<const float4*>(&Hkv0[hb + f]);
    }
    __syncthreads();

    float o[8];
#pragma unroll
    for (int j = 0; j < 8; j++) o[j] = 0.f;
#pragma unroll 4
    for (int s = 0; s < CC; s++) {
        float m = __shfl(mreg[s >> 3], s & 7, 8);
        float4 va = *reinterpret_cast<const float4*>(&sK[s][d0]);
        float4 vb = *reinterpret_cast<const float4*>(&sK[s][d0 + 4]);
        o[0] += m * va.x; o[1] += m * va.y; o[2] += m * va.z; o[3] += m * va.w;
        o[4] += m * vb.x; o[5] += m * vb.y; o[6] += m * vb.z; o[7] += m * vb.w;
    }
    float a2[8];
#pragma unroll
    for (int j = 0; j < 8; j++) a2[j] = 0.f;
#pragma unroll 8
    for (int j = 0; j < 64; j++) {
        float xj = sP[t][j];
        float4 ha = *reinterpret_cast<const float4*>(&sH[j * 64 + d0]);
        float4 hc = *reinterpret_cast<const float4*>(&sH[j * 64 + d0 + 4]);
        a2[0] += xj * ha.x; a2[1] += xj * ha.y; a2[2] += xj * ha.z; a2[3] += xj * ha.w;
        a2[4] += xj * hc.x; a2[5] += xj * hc.y; a2[6] += xj * hc.z; a2[7] += xj * hc.w;
    }
#pragma unroll
    for (int j = 0; j < 8; j++) o[j] += e_t * a2[j];
    // RMS norm over dv
    float ss = 0.f;
#pragma unroll
    for (int j = 0; j < 8; j++) ss += o[j] * o[j];
    ss += __shfl_xor(ss, 1); ss += __shfl_xor(ss, 2); ss += __shfl_xor(ss, 4);
    float scale = rsqrtf(ss * (1.f / 64.f) + 1e-5f);
#pragma unroll
    for (int j = 0; j < 8; j++) o[j] *= scale * nw[j];
    *reinterpret_cast<float4*>(&o_out[rowb + d0])     = make_float4(o[0], o[1], o[2], o[3]);
    *reinterpret_cast<float4*>(&o_out[rowb + d0 + 4]) = make_float4(o[4], o[5], o[6], o[7]);
}

// ---------------------------------------------------------------------------
extern "C" void kernel_launch(void* const* d_in, const int* in_sizes, int n_in,
                              void* d_out, int out_size, void* d_ws, size_t ws_size,
                              hipStream_t stream)
{
    const float* hidden   = (const float*)d_in[0];
    const float* Wq       = (const float*)d_in[1];
    const float* Wk       = (const float*)d_in[2];
    const float* Wv       = (const float*)d_in[3];
    const float* Wa       = (const float*)d_in[4];
    const float* Wb       = (const float*)d_in[5];
    const float* bb       = (const float*)d_in[6];
    const float* A_log    = (const float*)d_in[7];
    const float* dt_bias  = (const float*)d_in[8];
    const float* lambda_p = (const float*)d_in[9];
    const float* Wconv_q  = (const float*)d_in[10];
    const float* Wconv_k  = (const float*)d_in[11];
    const float* norm_w   = (const float*)d_in[12];
    const float* Wo       = (const float*)d_in[13];
    float* out = (float*)d_out;

    float* ws = (float*)d_ws;
    const size_t SZ_BIG = (size_t)2 * T_LEN * HIDN;   // 2M floats
    float* qpre = ws;
    float* kpre = qpre + SZ_BIG;
    float* vbuf = kpre + SZ_BIG;
    float* qbuf = vbuf + SZ_BIG;
    float* kbuf = qbuf + SZ_BIG;
    float* gbuf = kbuf + SZ_BIG;                      // 32768
    float* bbuf = gbuf + 32768;
    float* Gbuf = bbuf + 32768;
    float* btT  = Gbuf + 32768;
    float* Hkk0 = btT + 32768;                        // 32*NC*4096 = 4M floats
    float* Hkv0 = Hkk0 + (size_t)32 * NC * 4096;
    float* obuf = qpre;                               // reuse (qpre dead after conv)

    dim3 gg(HIDN / 64, (2 * T_LEN) / 64);             // (16, 32)
    gemm64<<<gg, 256, 0, stream>>>(hidden, Wq, qpre, 2 * T_LEN, HIDN, HIDN);
    gemm64<<<gg, 256, 0, stream>>>(hidden, Wk, kpre, 2 * T_LEN, HIDN, HIDN);
    gemm64<<<gg, 256, 0, stream>>>(hidden, Wv, vbuf, 2 * T_LEN, HIDN, HIDN);
    proj_gb<<<128, 256, 0, stream>>>(hidden, Wa, Wb, bb, A_log, dt_bias, gbuf, bbuf);
    cumsum_g<<<32, 1024, 0, stream>>>(gbuf, bbuf, Gbuf, btT);
    conv_silu_l2<<<2 * T_LEN * NH / 4, 256, 0, stream>>>(qpre, Wconv_q, qbuf);
    conv_silu_l2<<<2 * T_LEN * NH / 4, 256, 0, stream>>>(kpre, Wconv_k, kbuf);
    chunk_carry<<<64, 256, 0, stream>>>(kbuf, vbuf, Gbuf, btT, Hkk0, Hkv0);
    scan_chunk<<<1024, 256, 0, stream>>>(qbuf, kbuf, vbuf, Gbuf, btT, Hkk0, Hkv0,
                                         lambda_p, norm_w, obuf);
    gemm64<<<gg, 256, 0, stream>>>(obuf, Wo, out, 2 * T_LEN, HIDN, HIDN);
}

// Round 4
// 528.367 us; speedup vs baseline: 1.7371x; 1.3129x over previous
//
#include <hip/hip_runtime.h>
#include <hip/hip_bf16.h>
#include <stdint.h>

#define T_LEN 1024
#define HIDN  1024
#define NH    16
#define DKV   64
#define KCONV 4
#define CG_IT 15
#define CC    32              // chunk length
#define NC    (T_LEN / CC)    // 32 chunks
#define PAD   68              // padded row stride (fp32 LDS tiles)

typedef __attribute__((ext_vector_type(8))) short          bf16x8;
typedef __attribute__((ext_vector_type(8))) unsigned short u16x8;
typedef __attribute__((ext_vector_type(4))) unsigned short u16x4;
typedef __attribute__((ext_vector_type(4))) float          f32x4;

__device__ __forceinline__ float softplusf(float x) {
    return x > 20.f ? x : log1pf(expf(x));
}
__device__ __forceinline__ unsigned short f2bf(float x) {
    __hip_bfloat16 b = __float2bfloat16(x);
    return *reinterpret_cast<unsigned short*>(&b);
}

// ---------------------------------------------------------------------------
// cast fp32 -> bf16, vectorized (n multiple of 1024)
// ---------------------------------------------------------------------------
__global__ __launch_bounds__(256) void cast_bf16(const float* __restrict__ src,
                                                 unsigned short* __restrict__ dst,
                                                 int n4)
{
    int i = blockIdx.x * 256 + threadIdx.x;
    if (i >= n4) return;
    float4 v = *reinterpret_cast<const float4*>(src + (size_t)i * 4);
    u16x4 o;
    o.x = f2bf(v.x); o.y = f2bf(v.y); o.z = f2bf(v.z); o.w = f2bf(v.w);
    *reinterpret_cast<u16x4*>(dst + (size_t)i * 4) = o;
}

// ---------------------------------------------------------------------------
// cast + transpose: W fp32 [K][N] -> WT bf16 [N][K].  64x64 tiles, 256 thr.
// ---------------------------------------------------------------------------
__global__ __launch_bounds__(256) void transpose_cast(const float* __restrict__ W,
                                                      unsigned short* __restrict__ WT,
                                                      int K, int N)
{
    __shared__ unsigned short sT[64][68];
    int n0 = blockIdx.x * 64, k0 = blockIdx.y * 64;
    int tid = threadIdx.x;
    int rr = tid >> 4, cc4 = (tid & 15) * 4;
#pragma unroll
    for (int p = 0; p < 4; p++) {
        int r = p * 16 + rr;                       // k-row in tile
        float4 v = *reinterpret_cast<const float4*>(&W[(size_t)(k0 + r) * N + n0 + cc4]);
        sT[cc4 + 0][r] = f2bf(v.x);
        sT[cc4 + 1][r] = f2bf(v.y);
        sT[cc4 + 2][r] = f2bf(v.z);
        sT[cc4 + 3][r] = f2bf(v.w);
    }
    __syncthreads();
#pragma unroll
    for (int p = 0; p < 4; p++) {
        int r = p * 16 + rr;                       // n-row in tile
        u16x4 v = *reinterpret_cast<const u16x4*>(&sT[r][cc4]);
        *reinterpret_cast<u16x4*>(&WT[(size_t)(n0 + r) * K + k0 + cc4]) = v;
    }
}

// ---------------------------------------------------------------------------
// bf16 MFMA GEMM (TN): C[M,N] = A[M,K] @ B^T where Bt is [N][K] (K-contig).
// Tile 64x64, BK=32, 256 threads = 4 waves; wave w does m-strip [16w,16w+16)
// with 4 MFMAs (16x16x32) per K-step.  C is fp32.
// ---------------------------------------------------------------------------
__global__ __launch_bounds__(256) void gemm_bf16(const unsigned short* __restrict__ A,
                                                 const unsigned short* __restrict__ Bt,
                                                 float* __restrict__ C,
                                                 int M, int N, int K)
{
    __shared__ unsigned short sA[64][40];   // 80B row stride, 16B-aligned frags
    __shared__ unsigned short sB[64][40];
    const int tid = threadIdx.x;
    const int bm = blockIdx.y * 64, bn = blockIdx.x * 64;
    const int w = tid >> 6, lane = tid & 63;
    const int l16 = lane & 15, quad = lane >> 4;
    const int lrow = tid >> 2, lk = (tid & 3) * 8;   // staging: 64 rows x 32 k

    f32x4 acc[4];
#pragma unroll
    for (int f = 0; f < 4; f++) acc[f] = (f32x4){0.f, 0.f, 0.f, 0.f};

    const size_t arow = (size_t)(bm + lrow) * K;
    const size_t brow = (size_t)(bn + lrow) * K;

    for (int k0 = 0; k0 < K; k0 += 32) {
        u16x8 av = *reinterpret_cast<const u16x8*>(A + arow + k0 + lk);
        u16x8 bv = *reinterpret_cast<const u16x8*>(Bt + brow + k0 + lk);
        *reinterpret_cast<u16x8*>(&sA[lrow][lk]) = av;
        *reinterpret_cast<u16x8*>(&sB[lrow][lk]) = bv;
        __syncthreads();

        bf16x8 aF = *reinterpret_cast<const bf16x8*>(&sA[w * 16 + l16][quad * 8]);
#pragma unroll
        for (int f = 0; f < 4; f++) {
            bf16x8 bF = *reinterpret_cast<const bf16x8*>(&sB[f * 16 + l16][quad * 8]);
            acc[f] = __builtin_amdgcn_mfma_f32_16x16x32_bf16(aF, bF, acc[f], 0, 0, 0);
        }
        __syncthreads();
    }

    // C/D layout: col = lane&15, row = quad*4 + reg
#pragma unroll
    for (int f = 0; f < 4; f++) {
#pragma unroll
        for (int i = 0; i < 4; i++) {
            int m = bm + w * 16 + quad * 4 + i;
            C[(size_t)m * N + bn + f * 16 + l16] = acc[f][i];
        }
    }
}

// ---------------------------------------------------------------------------
// g / beta projections + nonlinearities.  One thread per (token_row, head).
// ---------------------------------------------------------------------------
__global__ __launch_bounds__(256) void proj_gb(const float* __restrict__ hidden,
                                               const float* __restrict__ Wa,
                                               const float* __restrict__ Wb,
                                               const float* __restrict__ bb,
                                               const float* __restrict__ A_log,
                                               const float* __restrict__ dt_bias,
                                               float* __restrict__ g_out,
                                               float* __restrict__ beta_out)
{
    int idx = blockIdx.x * 256 + threadIdx.x;   // over (B*T)*NH = 32768
    int row = idx >> 4, h = idx & 15;
    const float* hr = hidden + (size_t)row * HIDN;
    float da = 0.f, db = 0.f;
    for (int i = 0; i < HIDN; i++) {
        float x = hr[i];
        da += x * Wa[i * NH + h];
        db += x * Wb[i * NH + h];
    }
    float sp = softplusf(da + dt_bias[h]);
    g_out[idx]    = -expf(A_log[h]) * sp;
    beta_out[idx] = 1.f / (1.f + expf(-(db + bb[h])));
}

// ---------------------------------------------------------------------------
// Inclusive cumsum of g over t per (b,h); also transposes beta to [b,h,t].
// ---------------------------------------------------------------------------
__global__ __launch_bounds__(1024) void cumsum_g(const float* __restrict__ g_in,
                                                 const float* __restrict__ beta_in,
                                                 float* __restrict__ G_out,
                                                 float* __restrict__ betaT)
{
    __shared__ float s[1024];
    int bh = blockIdx.x;                 // 0..31
    int b = bh >> 4, h = bh & 15;
    int t = threadIdx.x;
    size_t src = ((size_t)(b * T_LEN) + t) * NH + h;
    s[t] = g_in[src];
    float bt = beta_in[src];
    __syncthreads();
    for (int off = 1; off < 1024; off <<= 1) {
        float tmp = (t >= off) ? s[t - off] : 0.f;
        __syncthreads();
        s[t] += tmp;
        __syncthreads();
    }
    G_out[(size_t)bh * T_LEN + t] = s[t];
    betaT[(size_t)bh * T_LEN + t] = bt;
}

// ---------------------------------------------------------------------------
// causal depthwise conv (K=4) + silu + per-head l2norm.  One wave per (b,t,h).
// ---------------------------------------------------------------------------
__global__ __launch_bounds__(256) void conv_silu_l2(const float* __restrict__ pre,
                                                    const float* __restrict__ Wc,
                                                    float* __restrict__ out)
{
    int gid = blockIdx.x * 4 + (threadIdx.x >> 6);    // 0 .. B*T*NH-1
    int lane = threadIdx.x & 63;
    int h = gid & 15;
    int t = (gid >> 4) & (T_LEN - 1);
    int b = gid >> 14;
    int c = h * DKV + lane;
    float acc = 0.f;
#pragma unroll
    for (int i = 0; i < KCONV; i++) {
        int ts = t - (KCONV - 1) + i;
        if (ts >= 0)
            acc += pre[((size_t)(b * T_LEN) + ts) * HIDN + c] * Wc[c * KCONV + i];
    }
    float y = acc / (1.f + expf(-acc));          // silu
    float ss = y * y;
#pragma unroll
    for (int m = 1; m < 64; m <<= 1) ss += __shfl_xor(ss, m);
    out[((size_t)(b * T_LEN) + t) * HIDN + c] = y * rsqrtf(ss + 1e-6f);
}

// ---------------------------------------------------------------------------
// Sequential pass over chunks: materialize chunk-start Hkk/Hkv states.
// grid = 32 (b,h) * 2 row-halves = 64 blocks; 256 threads.
// ---------------------------------------------------------------------------
__global__ __launch_bounds__(256) void chunk_carry(const float* __restrict__ kbuf,
                                                   const float* __restrict__ vbuf,
                                                   const float* __restrict__ G,
                                                   const float* __restrict__ betaT,
                                                   float* __restrict__ Hkk0,
                                                   float* __restrict__ Hkv0)
{
    __shared__ float sK[CC][PAD];
    __shared__ float sV[CC][PAD];
    __shared__ float sW[CC];
    int bid = blockIdx.x;                 // 64 blocks
    int bh = bid >> 1, half = bid & 1;
    int b = bh >> 4, h = bh & 15;
    int tid = threadIdx.x;
    int i = half * 32 + (tid >> 3);       // row index 0..63
    int j0 = (tid & 7) * 8;               // column group

    int ls = tid >> 3;                    // staging row 0..31
    int ld = (tid & 7) * 8;               // staging col
    const float* Gb  = G + (size_t)bh * T_LEN;
    const float* Btb = betaT + (size_t)bh * T_LEN;

    float ckk[8], ckv[8];
#pragma unroll
    for (int j = 0; j < 8; j++) { ckk[j] = 0.f; ckv[j] = 0.f; }

    {
        size_t ga = (((size_t)(b * T_LEN) + ls) * NH + h) * 64 + ld;
        *reinterpret_cast<float4*>(&sK[ls][ld])     = *reinterpret_cast<const float4*>(&kbuf[ga]);
        *reinterpret_cast<float4*>(&sK[ls][ld + 4]) = *reinterpret_cast<const float4*>(&kbuf[ga + 4]);
        *reinterpret_cast<float4*>(&sV[ls][ld])     = *reinterpret_cast<const float4*>(&vbuf[ga]);
        *reinterpret_cast<float4*>(&sV[ls][ld + 4]) = *reinterpret_cast<const float4*>(&vbuf[ga + 4]);
        if (tid < CC) {
            float gv = Gb[tid];
            float bv = Btb[tid];
            float gend = __shfl(gv, 31);
            sW[tid] = expf(gend - gv) * bv;
        }
    }
    __syncthreads();

    for (int c = 0; c < NC; c++) {
        int t0 = c * CC;
        size_t ob = (((size_t)(bh * NC) + c) * 64 + i) * 64 + j0;
        *reinterpret_cast<float4*>(&Hkk0[ob])     = make_float4(ckk[0], ckk[1], ckk[2], ckk[3]);
        *reinterpret_cast<float4*>(&Hkk0[ob + 4]) = make_float4(ckk[4], ckk[5], ckk[6], ckk[7]);
        *reinterpret_cast<float4*>(&Hkv0[ob])     = make_float4(ckv[0], ckv[1], ckv[2], ckv[3]);
        *reinterpret_cast<float4*>(&Hkv0[ob + 4]) = make_float4(ckv[4], ckv[5], ckv[6], ckv[7]);

        float4 kf0, kf1, vf0, vf1;
        float gnv = 0.f, bnv = 0.f;
        if (c + 1 < NC) {
            int t0n = t0 + CC;
            size_t ga = (((size_t)(b * T_LEN) + t0n + ls) * NH + h) * 64 + ld;
            kf0 = *reinterpret_cast<const float4*>(&kbuf[ga]);
            kf1 = *reinterpret_cast<const float4*>(&kbuf[ga + 4]);
            vf0 = *reinterpret_cast<const float4*>(&vbuf[ga]);
            vf1 = *reinterpret_cast<const float4*>(&vbuf[ga + 4]);
            if (tid < CC) { gnv = Gb[t0n + tid]; bnv = Btb[t0n + tid]; }
        }

        float gend  = Gb[t0 + CC - 1];
        float gprev = (t0 > 0) ? Gb[t0 - 1] : 0.f;
        float dec = expf(gend - gprev);

        float akk[8], akv[8];
#pragma unroll
        for (int j = 0; j < 8; j++) { akk[j] = 0.f; akv[j] = 0.f; }
#pragma unroll 4
        for (int s = 0; s < CC; s++) {
            float wk = sW[s] * sK[s][i];
            float4 ka = *reinterpret_cast<const float4*>(&sK[s][j0]);
            float4 kb = *reinterpret_cast<const float4*>(&sK[s][j0 + 4]);
            float4 va = *reinterpret_cast<const float4*>(&sV[s][j0]);
            float4 vb = *reinterpret_cast<const float4*>(&sV[s][j0 + 4]);
            akk[0] += wk * ka.x; akk[1] += wk * ka.y; akk[2] += wk * ka.z; akk[3] += wk * ka.w;
            akk[4] += wk * kb.x; akk[5] += wk * kb.y; akk[6] += wk * kb.z; akk[7] += wk * kb.w;
            akv[0] += wk * va.x; akv[1] += wk * va.y; akv[2] += wk * va.z; akv[3] += wk * va.w;
            akv[4] += wk * vb.x; akv[5] += wk * vb.y; akv[6] += wk * vb.z; akv[7] += wk * vb.w;
        }
#pragma unroll
        for (int j = 0; j < 8; j++) {
            ckk[j] = dec * ckk[j] + akk[j];
            ckv[j] = dec * ckv[j] + akv[j];
        }
        __syncthreads();
        if (c + 1 < NC) {
            *reinterpret_cast<float4*>(&sK[ls][ld])     = kf0;
            *reinterpret_cast<float4*>(&sK[ls][ld + 4]) = kf1;
            *reinterpret_cast<float4*>(&sV[ls][ld])     = vf0;
            *reinterpret_cast<float4*>(&sV[ls][ld + 4]) = vf1;
            if (tid < CC) {
                float gendn = __shfl(gnv, 31);
                sW[tid] = expf(gendn - gnv) * bnv;
            }
            __syncthreads();
        }
    }
}

// ---------------------------------------------------------------------------
// Main chunk kernel: 32 lockstep CG solves + output + RMS norm per block.
// ---------------------------------------------------------------------------
__global__ __launch_bounds__(256) void scan_chunk(const float* __restrict__ qbuf,
                                                  const float* __restrict__ kbuf,
                                                  const float* __restrict__ vbuf,
                                                  const float* __restrict__ G,
                                                  const float* __restrict__ betaT,
                                                  const float* __restrict__ Hkk0,
                                                  const float* __restrict__ Hkv0,
                                                  const float* __restrict__ lambda_p,
                                                  const float* __restrict__ norm_w,
                                                  float* __restrict__ o_out)
{
    __shared__ float sK[CC][PAD];        // K rows; later overlaid with V
    __shared__ float sP[CC][PAD];        // CG direction p; later X
    __shared__ float sH[64 * 64];        // Hkk0; later Hkv0
    __shared__ float sCo[CC][36];
    __shared__ float sGl[CC];
    __shared__ float sBt[CC];
    __shared__ float sE[CC];

    int bid = blockIdx.x;
    int chunk = bid & (NC - 1);
    int bh = bid >> 5;
    int b = bh >> 4, h = bh & 15;
    int tid = threadIdx.x;
    int t = tid >> 3, g8 = tid & 7, d0 = g8 * 8;
    int t0 = chunk * CC;

    size_t rowb = (((size_t)(b * T_LEN) + t0 + t) * NH + h) * 64;

    float p[8], r[8], x[8], lamr[8], nw[8];
    {
        float4 k0 = *reinterpret_cast<const float4*>(&kbuf[rowb + d0]);
        float4 k1 = *reinterpret_cast<const float4*>(&kbuf[rowb + d0 + 4]);
        *reinterpret_cast<float4*>(&sK[t][d0])     = k0;
        *reinterpret_cast<float4*>(&sK[t][d0 + 4]) = k1;
        float4 q0 = *reinterpret_cast<const float4*>(&qbuf[rowb + d0]);
        float4 q1 = *reinterpret_cast<const float4*>(&qbuf[rowb + d0 + 4]);
        *reinterpret_cast<float4*>(&sP[t][d0])     = q0;
        *reinterpret_cast<float4*>(&sP[t][d0 + 4]) = q1;
        p[0] = q0.x; p[1] = q0.y; p[2] = q0.z; p[3] = q0.w;
        p[4] = q1.x; p[5] = q1.y; p[6] = q1.z; p[7] = q1.w;
#pragma unroll
        for (int j = 0; j < 8; j++) { r[j] = p[j]; x[j] = 0.f; }
    }
#pragma unroll
    for (int j = 0; j < 8; j++) {
        lamr[j] = softplusf(lambda_p[h * 64 + d0 + j]) + 0.25f;
        nw[j]   = norm_w[d0 + j];
    }
    size_t hb = ((size_t)(bh * NC) + chunk) * 4096;
#pragma unroll
    for (int pp = 0; pp < 4; pp++) {
        int f = pp * 1024 + tid * 4;
        *reinterpret_cast<float4*>(&sH[f]) = *reinterpret_cast<const float4*>(&Hkk0[hb + f]);
    }
    if (tid < CC) {
        float Gv = G[(size_t)bh * T_LEN + t0 + tid];
        sGl[tid] = Gv;
        float Gp = (t0 > 0) ? G[(size_t)bh * T_LEN + t0 - 1] : 0.f;
        sE[tid] = expf(Gv - Gp);
        sBt[tid] = betaT[(size_t)bh * T_LEN + t0 + tid];
    }
    __syncthreads();

    {
        float gl_t = sGl[t];
#pragma unroll
        for (int si = 0; si < 4; si++) {
            int s = si * 8 + g8;
            sCo[t][s] = (s <= t) ? expf(gl_t - sGl[s]) * sBt[s] : 0.f;
        }
    }
    float e_t = sE[t];
    __threadfence_block();

    float rs;
    {
        float pr = 0.f;
#pragma unroll
        for (int j = 0; j < 8; j++) pr += r[j] * r[j];
        pr += __shfl_xor(pr, 1); pr += __shfl_xor(pr, 2); pr += __shfl_xor(pr, 4);
        rs = pr;
    }

    for (int it = 0; it < CG_IT; it++) {
        float ap[8];
#pragma unroll
        for (int j = 0; j < 8; j++) ap[j] = lamr[j] * p[j];
#pragma unroll 4
        for (int s = 0; s < CC; s++) {
            float4 ka = *reinterpret_cast<const float4*>(&sK[s][d0]);
            float4 kb = *reinterpret_cast<const float4*>(&sK[s][d0 + 4]);
            float dot = p[0] * ka.x + p[1] * ka.y + p[2] * ka.z + p[3] * ka.w
                      + p[4] * kb.x + p[5] * kb.y + p[6] * kb.z + p[7] * kb.w;
            dot += __shfl_xor(dot, 1); dot += __shfl_xor(dot, 2); dot += __shfl_xor(dot, 4);
            float m = sCo[t][s] * dot;
            ap[0] += m * ka.x; ap[1] += m * ka.y; ap[2] += m * ka.z; ap[3] += m * ka.w;
            ap[4] += m * kb.x; ap[5] += m * kb.y; ap[6] += m * kb.z; ap[7] += m * kb.w;
        }
        float a2[8];
#pragma unroll
        for (int j = 0; j < 8; j++) a2[j] = 0.f;
#pragma unroll 8
        for (int j = 0; j < 64; j++) {
            float pj = sP[t][j];
            float4 ha = *reinterpret_cast<const float4*>(&sH[j * 64 + d0]);
            float4 hc = *reinterpret_cast<const float4*>(&sH[j * 64 + d0 + 4]);
            a2[0] += pj * ha.x; a2[1] += pj * ha.y; a2[2] += pj * ha.z; a2[3] += pj * ha.w;
            a2[4] += pj * hc.x; a2[5] += pj * hc.y; a2[6] += pj * hc.z; a2[7] += pj * hc.w;
        }
#pragma unroll
        for (int j = 0; j < 8; j++) ap[j] += e_t * a2[j];
        float pap = 0.f;
#pragma unroll
        for (int j = 0; j < 8; j++) pap += p[j] * ap[j];
        pap += __shfl_xor(pap, 1); pap += __shfl_xor(pap, 2); pap += __shfl_xor(pap, 4);
        float alpha = rs / (pap + 1e-12f);
        float rsn = 0.f;
#pragma unroll
        for (int j = 0; j < 8; j++) {
            x[j] += alpha * p[j];
            r[j] -= alpha * ap[j];
            rsn += r[j] * r[j];
        }
        rsn += __shfl_xor(rsn, 1); rsn += __shfl_xor(rsn, 2); rsn += __shfl_xor(rsn, 4);
        float btac = rsn / (rs + 1e-12f);
        rs = rsn;
#pragma unroll
        for (int j = 0; j < 8; j++) p[j] = r[j] + btac * p[j];
        *reinterpret_cast<float4*>(&sP[t][d0])     = make_float4(p[0], p[1], p[2], p[3]);
        *reinterpret_cast<float4*>(&sP[t][d0 + 4]) = make_float4(p[4], p[5], p[6], p[7]);
        __threadfence_block();
    }

    // ---- output phase ----
    float mreg[4];
#pragma unroll 4
    for (int s = 0; s < CC; s++) {
        float4 ka = *reinterpret_cast<const float4*>(&sK[s][d0]);
        float4 kb = *reinterpret_cast<const float4*>(&sK[s][d0 + 4]);
        float dot = x[0] * ka.x + x[1] * ka.y + x[2] * ka.z + x[3] * ka.w
                  + x[4] * kb.x + x[5] * kb.y + x[6] * kb.z + x[7] * kb.w;
        dot += __shfl_xor(dot, 1); dot += __shfl_xor(dot, 2); dot += __shfl_xor(dot, 4);
        float m = sCo[t][s] * dot;
        if ((s & 7) == g8) mreg[s >> 3] = m;
    }
    *reinterpret_cast<float4*>(&sP[t][d0])     = make_float4(x[0], x[1], x[2], x[3]);
    *reinterpret_cast<float4*>(&sP[t][d0 + 4]) = make_float4(x[4], x[5], x[6], x[7]);
    __syncthreads();
    {
        float4 v0 = *reinterpret_cast<const float4*>(&vbuf[rowb + d0]);
        float4 v1 = *reinterpret_cast<const float4*>(&vbuf[rowb + d0 + 4]);
        *reinterpret_cast<float4*>(&sK[t][d0])     = v0;
        *reinterpret_cast<float4*>(&sK[t][d0 + 4]) = v1;
    }
#pragma unroll
    for (int pp = 0; pp < 4; pp++) {
        int f = pp * 1024 + tid * 4;
        *reinterpret_cast<float4*>(&sH[f]) = *reinterpret_cast<const float4*>(&Hkv0[hb + f]);
    }
    __syncthreads();

    float o[8];
#pragma unroll
    for (int j = 0; j < 8; j++) o[j] = 0.f;
#pragma unroll 4
    for (int s = 0; s < CC; s++) {
        float m = __shfl(mreg[s >> 3], s & 7, 8);
        float4 va = *reinterpret_cast<const float4*>(&sK[s][d0]);
        float4 vb = *reinterpret_cast<const float4*>(&sK[s][d0 + 4]);
        o[0] += m * va.x; o[1] += m * va.y; o[2] += m * va.z; o[3] += m * va.w;
        o[4] += m * vb.x; o[5] += m * vb.y; o[6] += m * vb.z; o[7] += m * vb.w;
    }
    float a2[8];
#pragma unroll
    for (int j = 0; j < 8; j++) a2[j] = 0.f;
#pragma unroll 8
    for (int j = 0; j < 64; j++) {
        float xj = sP[t][j];
        float4 ha = *reinterpret_cast<const float4*>(&sH[j * 64 + d0]);
        float4 hc = *reinterpret_cast<const float4*>(&sH[j * 64 + d0 + 4]);
        a2[0] += xj * ha.x; a2[1] += xj * ha.y; a2[2] += xj * ha.z; a2[3] += xj * ha.w;
        a2[4] += xj * hc.x; a2[5] += xj * hc.y; a2[6] += xj * hc.z; a2[7] += xj * hc.w;
    }
#pragma unroll
    for (int j = 0; j < 8; j++) o[j] += e_t * a2[j];
    float ss = 0.f;
#pragma unroll
    for (int j = 0; j < 8; j++) ss += o[j] * o[j];
    ss += __shfl_xor(ss, 1); ss += __shfl_xor(ss, 2); ss += __shfl_xor(ss, 4);
    float scale = rsqrtf(ss * (1.f / 64.f) + 1e-5f);
#pragma unroll
    for (int j = 0; j < 8; j++) o[j] *= scale * nw[j];
    *reinterpret_cast<float4*>(&o_out[rowb + d0])     = make_float4(o[0], o[1], o[2], o[3]);
    *reinterpret_cast<float4*>(&o_out[rowb + d0 + 4]) = make_float4(o[4], o[5], o[6], o[7]);
}

// ---------------------------------------------------------------------------
extern "C" void kernel_launch(void* const* d_in, const int* in_sizes, int n_in,
                              void* d_out, int out_size, void* d_ws, size_t ws_size,
                              hipStream_t stream)
{
    const float* hidden   = (const float*)d_in[0];
    const float* Wq       = (const float*)d_in[1];
    const float* Wk       = (const float*)d_in[2];
    const float* Wv       = (const float*)d_in[3];
    const float* Wa       = (const float*)d_in[4];
    const float* Wb       = (const float*)d_in[5];
    const float* bb       = (const float*)d_in[6];
    const float* A_log    = (const float*)d_in[7];
    const float* dt_bias  = (const float*)d_in[8];
    const float* lambda_p = (const float*)d_in[9];
    const float* Wconv_q  = (const float*)d_in[10];
    const float* Wconv_k  = (const float*)d_in[11];
    const float* norm_w   = (const float*)d_in[12];
    const float* Wo       = (const float*)d_in[13];
    float* out = (float*)d_out;

    float* ws = (float*)d_ws;
    const size_t SZ_BIG = (size_t)2 * T_LEN * HIDN;   // 2M floats
    float* qpre = ws;
    float* kpre = qpre + SZ_BIG;
    float* vbuf = kpre + SZ_BIG;
    float* qbuf = vbuf + SZ_BIG;
    float* kbuf = qbuf + SZ_BIG;
    float* gbuf = kbuf + SZ_BIG;                      // 32768
    float* bbuf = gbuf + 32768;
    float* Gbuf = bbuf + 32768;
    float* btT  = Gbuf + 32768;
    float* Hkk0 = btT + 32768;                        // 4M floats (16 MB)
    float* Hkv0 = Hkk0 + (size_t)32 * NC * 4096;      // 4M floats (16 MB)
    unsigned short* WoT = (unsigned short*)(Hkv0 + (size_t)32 * NC * 4096);  // 1M u16
    float* obuf = qpre;                               // reuse (qpre dead after conv)

    // bf16 staging buffers aliased into regions that are dead until chunk_carry:
    unsigned short* hidden_bf = (unsigned short*)Hkv0;     // 2M u16 (4 MB < 16 MB)
    unsigned short* WqT = (unsigned short*)Hkk0;           // 1M u16 each
    unsigned short* WkT = WqT + (size_t)HIDN * HIDN;
    unsigned short* WvT = WkT + (size_t)HIDN * HIDN;
    unsigned short* obuf_bf = (unsigned short*)kpre;       // kpre dead after conv

    const int M = 2 * T_LEN;                          // 2048

    // casts & transposes
    cast_bf16<<<(M * HIDN / 4 + 255) / 256, 256, 0, stream>>>(hidden, hidden_bf, M * HIDN / 4);
    dim3 tg(HIDN / 64, HIDN / 64);                    // (16,16)
    transpose_cast<<<tg, 256, 0, stream>>>(Wq, WqT, HIDN, HIDN);
    transpose_cast<<<tg, 256, 0, stream>>>(Wk, WkT, HIDN, HIDN);
    transpose_cast<<<tg, 256, 0, stream>>>(Wv, WvT, HIDN, HIDN);
    transpose_cast<<<tg, 256, 0, stream>>>(Wo, WoT, HIDN, HIDN);

    // projections (bf16 MFMA)
    dim3 gg(HIDN / 64, M / 64);                       // (16, 32)
    gemm_bf16<<<gg, 256, 0, stream>>>(hidden_bf, WqT, qpre, M, HIDN, HIDN);
    gemm_bf16<<<gg, 256, 0, stream>>>(hidden_bf, WkT, kpre, M, HIDN, HIDN);
    gemm_bf16<<<gg, 256, 0, stream>>>(hidden_bf, WvT, vbuf, M, HIDN, HIDN);
    proj_gb<<<128, 256, 0, stream>>>(hidden, Wa, Wb, bb, A_log, dt_bias, gbuf, bbuf);
    cumsum_g<<<32, 1024, 0, stream>>>(gbuf, bbuf, Gbuf, btT);
    conv_silu_l2<<<M * NH / 4, 256, 0, stream>>>(qpre, Wconv_q, qbuf);
    conv_silu_l2<<<M * NH / 4, 256, 0, stream>>>(kpre, Wconv_k, kbuf);
    chunk_carry<<<64, 256, 0, stream>>>(kbuf, vbuf, Gbuf, btT, Hkk0, Hkv0);
    scan_chunk<<<1024, 256, 0, stream>>>(qbuf, kbuf, vbuf, Gbuf, btT, Hkk0, Hkv0,
                                         lambda_p, norm_w, obuf);
    cast_bf16<<<(M * HIDN / 4 + 255) / 256, 256, 0, stream>>>(obuf, obuf_bf, M * HIDN / 4);
    gemm_bf16<<<gg, 256, 0, stream>>>(obuf_bf, WoT, out, M, HIDN, HIDN);
}

// Round 5
// 361.471 us; speedup vs baseline: 2.5392x; 1.4617x over previous
//
#include <hip/hip_runtime.h>
#include <hip/hip_bf16.h>
#include <stdint.h>

#define T_LEN 1024
#define HIDN  1024
#define NH    16
#define DKV   64
#define KCONV 4
#define CG_IT 15
#define CC    32              // chunk length
#define NC    (T_LEN / CC)    // 32 chunks
#define PAD   68              // padded row stride (fp32 LDS tiles)

typedef __attribute__((ext_vector_type(8))) short          bf16x8;
typedef __attribute__((ext_vector_type(8))) unsigned short u16x8;
typedef __attribute__((ext_vector_type(4))) unsigned short u16x4;
typedef __attribute__((ext_vector_type(4))) float          f32x4;

__device__ __forceinline__ float softplusf(float x) {
    return x > 20.f ? x : log1pf(expf(x));
}
__device__ __forceinline__ unsigned short f2bf(float x) {
    __hip_bfloat16 b = __float2bfloat16(x);
    return *reinterpret_cast<unsigned short*>(&b);
}
__device__ __forceinline__ bf16x8 pack8(float4 a, float4 b) {
    union { bf16x8 v; unsigned short u[8]; } r;
    r.u[0] = f2bf(a.x); r.u[1] = f2bf(a.y); r.u[2] = f2bf(a.z); r.u[3] = f2bf(a.w);
    r.u[4] = f2bf(b.x); r.u[5] = f2bf(b.y); r.u[6] = f2bf(b.z); r.u[7] = f2bf(b.w);
    return r.v;
}

// ---------------------------------------------------------------------------
// cast fp32 -> bf16, vectorized
// ---------------------------------------------------------------------------
__global__ __launch_bounds__(256) void cast_bf16(const float* __restrict__ src,
                                                 unsigned short* __restrict__ dst,
                                                 int n4)
{
    int i = blockIdx.x * 256 + threadIdx.x;
    if (i >= n4) return;
    float4 v = *reinterpret_cast<const float4*>(src + (size_t)i * 4);
    u16x4 o;
    o.x = f2bf(v.x); o.y = f2bf(v.y); o.z = f2bf(v.z); o.w = f2bf(v.w);
    *reinterpret_cast<u16x4*>(dst + (size_t)i * 4) = o;
}

// ---------------------------------------------------------------------------
// cast + transpose: W fp32 [K][N] -> WT bf16 [N][K].
// ---------------------------------------------------------------------------
__global__ __launch_bounds__(256) void transpose_cast(const float* __restrict__ W,
                                                      unsigned short* __restrict__ WT,
                                                      int K, int N)
{
    __shared__ unsigned short sT[64][68];
    int n0 = blockIdx.x * 64, k0 = blockIdx.y * 64;
    int tid = threadIdx.x;
    int rr = tid >> 4, cc4 = (tid & 15) * 4;
#pragma unroll
    for (int p = 0; p < 4; p++) {
        int r = p * 16 + rr;
        float4 v = *reinterpret_cast<const float4*>(&W[(size_t)(k0 + r) * N + n0 + cc4]);
        sT[cc4 + 0][r] = f2bf(v.x);
        sT[cc4 + 1][r] = f2bf(v.y);
        sT[cc4 + 2][r] = f2bf(v.z);
        sT[cc4 + 3][r] = f2bf(v.w);
    }
    __syncthreads();
#pragma unroll
    for (int p = 0; p < 4; p++) {
        int r = p * 16 + rr;
        u16x4 v = *reinterpret_cast<const u16x4*>(&sT[r][cc4]);
        *reinterpret_cast<u16x4*>(&WT[(size_t)(n0 + r) * K + k0 + cc4]) = v;
    }
}

// ---------------------------------------------------------------------------
// bf16 MFMA GEMM (TN): C[M,N] = A[M,K] @ B^T, Bt is [N][K].  64x64 tile.
// ---------------------------------------------------------------------------
__global__ __launch_bounds__(256) void gemm_bf16(const unsigned short* __restrict__ A,
                                                 const unsigned short* __restrict__ Bt,
                                                 float* __restrict__ C,
                                                 int M, int N, int K)
{
    __shared__ unsigned short sA[64][40];
    __shared__ unsigned short sB[64][40];
    const int tid = threadIdx.x;
    const int bm = blockIdx.y * 64, bn = blockIdx.x * 64;
    const int w = tid >> 6, lane = tid & 63;
    const int l16 = lane & 15, quad = lane >> 4;
    const int lrow = tid >> 2, lk = (tid & 3) * 8;

    f32x4 acc[4];
#pragma unroll
    for (int f = 0; f < 4; f++) acc[f] = (f32x4){0.f, 0.f, 0.f, 0.f};

    const size_t arow = (size_t)(bm + lrow) * K;
    const size_t brow = (size_t)(bn + lrow) * K;

    for (int k0 = 0; k0 < K; k0 += 32) {
        u16x8 av = *reinterpret_cast<const u16x8*>(A + arow + k0 + lk);
        u16x8 bv = *reinterpret_cast<const u16x8*>(Bt + brow + k0 + lk);
        *reinterpret_cast<u16x8*>(&sA[lrow][lk]) = av;
        *reinterpret_cast<u16x8*>(&sB[lrow][lk]) = bv;
        __syncthreads();

        bf16x8 aF = *reinterpret_cast<const bf16x8*>(&sA[w * 16 + l16][quad * 8]);
#pragma unroll
        for (int f = 0; f < 4; f++) {
            bf16x8 bF = *reinterpret_cast<const bf16x8*>(&sB[f * 16 + l16][quad * 8]);
            acc[f] = __builtin_amdgcn_mfma_f32_16x16x32_bf16(aF, bF, acc[f], 0, 0, 0);
        }
        __syncthreads();
    }

#pragma unroll
    for (int f = 0; f < 4; f++) {
#pragma unroll
        for (int i = 0; i < 4; i++) {
            int m = bm + w * 16 + quad * 4 + i;
            C[(size_t)m * N + bn + f * 16 + l16] = acc[f][i];
        }
    }
}

// ---------------------------------------------------------------------------
// g / beta projections + nonlinearities.
// ---------------------------------------------------------------------------
__global__ __launch_bounds__(256) void proj_gb(const float* __restrict__ hidden,
                                               const float* __restrict__ Wa,
                                               const float* __restrict__ Wb,
                                               const float* __restrict__ bb,
                                               const float* __restrict__ A_log,
                                               const float* __restrict__ dt_bias,
                                               float* __restrict__ g_out,
                                               float* __restrict__ beta_out)
{
    int idx = blockIdx.x * 256 + threadIdx.x;
    int row = idx >> 4, h = idx & 15;
    const float* hr = hidden + (size_t)row * HIDN;
    float da = 0.f, db = 0.f;
    for (int i = 0; i < HIDN; i++) {
        float x = hr[i];
        da += x * Wa[i * NH + h];
        db += x * Wb[i * NH + h];
    }
    float sp = softplusf(da + dt_bias[h]);
    g_out[idx]    = -expf(A_log[h]) * sp;
    beta_out[idx] = 1.f / (1.f + expf(-(db + bb[h])));
}

// ---------------------------------------------------------------------------
// Inclusive cumsum of g over t per (b,h); transposes beta to [b,h,t].
// ---------------------------------------------------------------------------
__global__ __launch_bounds__(1024) void cumsum_g(const float* __restrict__ g_in,
                                                 const float* __restrict__ beta_in,
                                                 float* __restrict__ G_out,
                                                 float* __restrict__ betaT)
{
    __shared__ float s[1024];
    int bh = blockIdx.x;
    int b = bh >> 4, h = bh & 15;
    int t = threadIdx.x;
    size_t src = ((size_t)(b * T_LEN) + t) * NH + h;
    s[t] = g_in[src];
    float bt = beta_in[src];
    __syncthreads();
    for (int off = 1; off < 1024; off <<= 1) {
        float tmp = (t >= off) ? s[t - off] : 0.f;
        __syncthreads();
        s[t] += tmp;
        __syncthreads();
    }
    G_out[(size_t)bh * T_LEN + t] = s[t];
    betaT[(size_t)bh * T_LEN + t] = bt;
}

// ---------------------------------------------------------------------------
// causal depthwise conv (K=4) + silu + per-head l2norm.
// ---------------------------------------------------------------------------
__global__ __launch_bounds__(256) void conv_silu_l2(const float* __restrict__ pre,
                                                    const float* __restrict__ Wc,
                                                    float* __restrict__ out)
{
    int gid = blockIdx.x * 4 + (threadIdx.x >> 6);
    int lane = threadIdx.x & 63;
    int h = gid & 15;
    int t = (gid >> 4) & (T_LEN - 1);
    int b = gid >> 14;
    int c = h * DKV + lane;
    float acc = 0.f;
#pragma unroll
    for (int i = 0; i < KCONV; i++) {
        int ts = t - (KCONV - 1) + i;
        if (ts >= 0)
            acc += pre[((size_t)(b * T_LEN) + ts) * HIDN + c] * Wc[c * KCONV + i];
    }
    float y = acc / (1.f + expf(-acc));
    float ss = y * y;
#pragma unroll
    for (int m = 1; m < 64; m <<= 1) ss += __shfl_xor(ss, m);
    out[((size_t)(b * T_LEN) + t) * HIDN + c] = y * rsqrtf(ss + 1e-6f);
}

// ---------------------------------------------------------------------------
// Sequential pass over chunks: Hkk0 (as-is, symmetric) and Hkv0 stored
// TRANSPOSED ([dv][dk]) for the MFMA scan's B-fragment reads.
// ---------------------------------------------------------------------------
__global__ __launch_bounds__(256) void chunk_carry(const float* __restrict__ kbuf,
                                                   const float* __restrict__ vbuf,
                                                   const float* __restrict__ G,
                                                   const float* __restrict__ betaT,
                                                   float* __restrict__ Hkk0,
                                                   float* __restrict__ HkvT0)
{
    __shared__ float sK[CC][PAD];
    __shared__ float sV[CC][PAD];
    __shared__ float sW[CC];
    int bid = blockIdx.x;                 // 64 blocks
    int bh = bid >> 1, half = bid & 1;
    int b = bh >> 4, h = bh & 15;
    int tid = threadIdx.x;
    int i = half * 32 + (tid >> 3);       // row index 0..63 (dk for kk, dv for kvT)
    int j0 = (tid & 7) * 8;

    int ls = tid >> 3;
    int ld = (tid & 7) * 8;
    const float* Gb  = G + (size_t)bh * T_LEN;
    const float* Btb = betaT + (size_t)bh * T_LEN;

    float ckk[8], ckv[8];
#pragma unroll
    for (int j = 0; j < 8; j++) { ckk[j] = 0.f; ckv[j] = 0.f; }

    {
        size_t ga = (((size_t)(b * T_LEN) + ls) * NH + h) * 64 + ld;
        *reinterpret_cast<float4*>(&sK[ls][ld])     = *reinterpret_cast<const float4*>(&kbuf[ga]);
        *reinterpret_cast<float4*>(&sK[ls][ld + 4]) = *reinterpret_cast<const float4*>(&kbuf[ga + 4]);
        *reinterpret_cast<float4*>(&sV[ls][ld])     = *reinterpret_cast<const float4*>(&vbuf[ga]);
        *reinterpret_cast<float4*>(&sV[ls][ld + 4]) = *reinterpret_cast<const float4*>(&vbuf[ga + 4]);
        if (tid < CC) {
            float gv = Gb[tid];
            float bv = Btb[tid];
            float gend = __shfl(gv, 31);
            sW[tid] = expf(gend - gv) * bv;
        }
    }
    __syncthreads();

    for (int c = 0; c < NC; c++) {
        int t0 = c * CC;
        size_t ob = (((size_t)(bh * NC) + c) * 64 + i) * 64 + j0;
        *reinterpret_cast<float4*>(&Hkk0[ob])      = make_float4(ckk[0], ckk[1], ckk[2], ckk[3]);
        *reinterpret_cast<float4*>(&Hkk0[ob + 4])  = make_float4(ckk[4], ckk[5], ckk[6], ckk[7]);
        *reinterpret_cast<float4*>(&HkvT0[ob])     = make_float4(ckv[0], ckv[1], ckv[2], ckv[3]);
        *reinterpret_cast<float4*>(&HkvT0[ob + 4]) = make_float4(ckv[4], ckv[5], ckv[6], ckv[7]);

        float4 kf0, kf1, vf0, vf1;
        float gnv = 0.f, bnv = 0.f;
        if (c + 1 < NC) {
            int t0n = t0 + CC;
            size_t ga = (((size_t)(b * T_LEN) + t0n + ls) * NH + h) * 64 + ld;
            kf0 = *reinterpret_cast<const float4*>(&kbuf[ga]);
            kf1 = *reinterpret_cast<const float4*>(&kbuf[ga + 4]);
            vf0 = *reinterpret_cast<const float4*>(&vbuf[ga]);
            vf1 = *reinterpret_cast<const float4*>(&vbuf[ga + 4]);
            if (tid < CC) { gnv = Gb[t0n + tid]; bnv = Btb[t0n + tid]; }
        }

        float gend  = Gb[t0 + CC - 1];
        float gprev = (t0 > 0) ? Gb[t0 - 1] : 0.f;
        float dec = expf(gend - gprev);

        float akk[8], akv[8];
#pragma unroll
        for (int j = 0; j < 8; j++) { akk[j] = 0.f; akv[j] = 0.f; }
#pragma unroll 4
        for (int s = 0; s < CC; s++) {
            float wk = sW[s] * sK[s][i];      // row i of Hkk  (dk)
            float wv = sW[s] * sV[s][i];      // row i of HkvT (dv)
            float4 ka = *reinterpret_cast<const float4*>(&sK[s][j0]);
            float4 kb = *reinterpret_cast<const float4*>(&sK[s][j0 + 4]);
            akk[0] += wk * ka.x; akk[1] += wk * ka.y; akk[2] += wk * ka.z; akk[3] += wk * ka.w;
            akk[4] += wk * kb.x; akk[5] += wk * kb.y; akk[6] += wk * kb.z; akk[7] += wk * kb.w;
            akv[0] += wv * ka.x; akv[1] += wv * ka.y; akv[2] += wv * ka.z; akv[3] += wv * ka.w;
            akv[4] += wv * kb.x; akv[5] += wv * kb.y; akv[6] += wv * kb.z; akv[7] += wv * kb.w;
        }
#pragma unroll
        for (int j = 0; j < 8; j++) {
            ckk[j] = dec * ckk[j] + akk[j];
            ckv[j] = dec * ckv[j] + akv[j];
        }
        __syncthreads();
        if (c + 1 < NC) {
            *reinterpret_cast<float4*>(&sK[ls][ld])     = kf0;
            *reinterpret_cast<float4*>(&sK[ls][ld + 4]) = kf1;
            *reinterpret_cast<float4*>(&sV[ls][ld])     = vf0;
            *reinterpret_cast<float4*>(&sV[ls][ld + 4]) = vf1;
            if (tid < CC) {
                float gendn = __shfl(gnv, 31);
                sW[tid] = expf(gendn - gnv) * bnv;
            }
            __syncthreads();
        }
    }
}

// ---------------------------------------------------------------------------
// MFMA scan: ONE WAVE per (bh, chunk).  256 blocks x 4 waves = 1024 waves.
// C-layout state in registers; K/KT/H B-frags loop-invariant in registers;
// only LDS traffic is the C->A fragment round trip for P and M. No barriers.
// Output written directly as bf16 [row][HIDN].
// ---------------------------------------------------------------------------
__global__ __launch_bounds__(256, 1) void scan_mfma(
    const float* __restrict__ qbuf, const float* __restrict__ kbuf,
    const float* __restrict__ vbuf, const float* __restrict__ G,
    const float* __restrict__ betaT, const float* __restrict__ Hkk0,
    const float* __restrict__ HkvT0, const float* __restrict__ lambda_p,
    const float* __restrict__ norm_w, unsigned short* __restrict__ obf)
{
    __shared__ __align__(16) unsigned short sP[4][32][72];
    __shared__ __align__(16) unsigned short sM[4][32][40];

    const int tid = threadIdx.x;
    const int wv = tid >> 6, lane = tid & 63;
    const int quad = lane >> 4, l16 = lane & 15;
    const int W = blockIdx.x * 4 + wv;          // 0..1023
    const int bh = W >> 5, chunk = W & 31;
    const int b = bh >> 4, h = bh & 15;
    const int t0 = chunk * CC;
    unsigned short (*sPw)[72] = sP[wv];
    unsigned short (*sMw)[40] = sM[wv];

    const size_t rbase = ((size_t)(b * T_LEN + t0) * NH + h) * 64;  // row t -> rbase + t*1024
    const float* Gb = G + (size_t)bh * T_LEN + t0;
    const float* Bb = betaT + (size_t)bh * T_LEN + t0;
    const float Gprev = (chunk > 0) ? Gb[-1] : 0.f;

    // per-row (C-layout rows t = 16*tm + 4*quad + reg)
    float Gt[2][4], et[2][4];
#pragma unroll
    for (int tm = 0; tm < 2; tm++)
#pragma unroll
        for (int reg = 0; reg < 4; reg++) {
            float g = Gb[16 * tm + 4 * quad + reg];
            Gt[tm][reg] = g;
            et[tm][reg] = expf(g - Gprev);
        }
    float Co[2][2][4];
#pragma unroll
    for (int sn = 0; sn < 2; sn++) {
        int s = 16 * sn + l16;
        float Gs = Gb[s], bts = Bb[s];
#pragma unroll
        for (int tm = 0; tm < 2; tm++)
#pragma unroll
            for (int reg = 0; reg < 4; reg++) {
                int t = 16 * tm + 4 * quad + reg;
                Co[tm][sn][reg] = (s <= t) ? expf(Gt[tm][reg] - Gs) * bts : 0.f;
            }
    }
    float lam[4], nw[4];
#pragma unroll
    for (int f = 0; f < 4; f++) {
        lam[f] = softplusf(lambda_p[h * 64 + 16 * f + l16]) + 0.25f;
        nw[f]  = norm_w[16 * f + l16];
    }

    // K B-frags (D = P@K^T): Kb[sn][ks] element j = K[16sn+l16][8quad+32ks+j]
    bf16x8 Kb[2][2];
#pragma unroll
    for (int sn = 0; sn < 2; sn++) {
        const float* kr = kbuf + rbase + (size_t)(16 * sn + l16) * 1024;
#pragma unroll
        for (int ks = 0; ks < 2; ks++) {
            float4 a = *reinterpret_cast<const float4*>(kr + 8 * quad + 32 * ks);
            float4 c = *reinterpret_cast<const float4*>(kr + 8 * quad + 32 * ks + 4);
            Kb[sn][ks] = pack8(a, c);
        }
    }
    // KT B-frags (AP2 = M@K): KTb[f] element j = K[8quad+j][16f+l16]
    bf16x8 KTb[4];
#pragma unroll
    for (int f = 0; f < 4; f++) {
        union { bf16x8 v; unsigned short u[8]; } r;
#pragma unroll
        for (int j = 0; j < 8; j++)
            r.u[j] = f2bf(kbuf[rbase + (size_t)(8 * quad + j) * 1024 + 16 * f + l16]);
        KTb[f] = r.v;
    }
    // H B-frags (A2 = P@Hkk, symmetric): Hb[f][ks] el jj = Hkk[16f+l16][8quad+32ks+jj]
    const size_t hbase = ((size_t)(bh * NC) + chunk) * 4096;
    bf16x8 Hb[4][2];
#pragma unroll
    for (int f = 0; f < 4; f++) {
        const float* hr = Hkk0 + hbase + (size_t)(16 * f + l16) * 64;
#pragma unroll
        for (int ks = 0; ks < 2; ks++) {
            float4 a = *reinterpret_cast<const float4*>(hr + 8 * quad + 32 * ks);
            float4 c = *reinterpret_cast<const float4*>(hr + 8 * quad + 32 * ks + 4);
            Hb[f][ks] = pack8(a, c);
        }
    }

    // init X=0, P=R=q, rs
    f32x4 X[2][4], R[2][4], P[2][4];
    float rs8[2][4];
#pragma unroll
    for (int tm = 0; tm < 2; tm++)
#pragma unroll
        for (int reg = 0; reg < 4; reg++) rs8[tm][reg] = 0.f;
#pragma unroll
    for (int tm = 0; tm < 2; tm++)
#pragma unroll
        for (int f = 0; f < 4; f++) {
#pragma unroll
            for (int reg = 0; reg < 4; reg++) {
                float q = qbuf[rbase + (size_t)(16 * tm + 4 * quad + reg) * 1024 + 16 * f + l16];
                P[tm][f][reg] = q; R[tm][f][reg] = q; X[tm][f][reg] = 0.f;
                rs8[tm][reg] += q * q;
            }
        }
#pragma unroll
    for (int tm = 0; tm < 2; tm++)
#pragma unroll
        for (int reg = 0; reg < 4; reg++) {
            float v = rs8[tm][reg];
            v += __shfl_xor(v, 1); v += __shfl_xor(v, 2);
            v += __shfl_xor(v, 4); v += __shfl_xor(v, 8);
            rs8[tm][reg] = v;
        }

    const f32x4 zero4 = {0.f, 0.f, 0.f, 0.f};

#pragma unroll 1
    for (int it = 0; it < CG_IT; it++) {
        // P (C-layout) -> sPw bf16
#pragma unroll
        for (int tm = 0; tm < 2; tm++)
#pragma unroll
            for (int reg = 0; reg < 4; reg++)
#pragma unroll
                for (int f = 0; f < 4; f++)
                    sPw[16 * tm + 4 * quad + reg][16 * f + l16] = f2bf(P[tm][f][reg]);
        __threadfence_block();
        bf16x8 Pa[2][2];
#pragma unroll
        for (int tm = 0; tm < 2; tm++)
#pragma unroll
            for (int ks = 0; ks < 2; ks++)
                Pa[tm][ks] = *reinterpret_cast<const bf16x8*>(&sPw[16 * tm + l16][8 * quad + 32 * ks]);
        // D = P@K^T
        f32x4 D[2][2];
#pragma unroll
        for (int tm = 0; tm < 2; tm++)
#pragma unroll
            for (int sn = 0; sn < 2; sn++) {
                f32x4 d = __builtin_amdgcn_mfma_f32_16x16x32_bf16(Pa[tm][0], Kb[sn][0], zero4, 0, 0, 0);
                D[tm][sn] = __builtin_amdgcn_mfma_f32_16x16x32_bf16(Pa[tm][1], Kb[sn][1], d, 0, 0, 0);
            }
        // M = Co o D -> sMw bf16
#pragma unroll
        for (int tm = 0; tm < 2; tm++)
#pragma unroll
            for (int sn = 0; sn < 2; sn++)
#pragma unroll
                for (int reg = 0; reg < 4; reg++)
                    sMw[16 * tm + 4 * quad + reg][16 * sn + l16] = f2bf(Co[tm][sn][reg] * D[tm][sn][reg]);
        __threadfence_block();
        bf16x8 Ma[2];
#pragma unroll
        for (int tm = 0; tm < 2; tm++)
            Ma[tm] = *reinterpret_cast<const bf16x8*>(&sMw[16 * tm + l16][8 * quad]);
        // AP = M@K ; A2 = P@H ; combine
        f32x4 AP[2][4], A2[2][4];
#pragma unroll
        for (int tm = 0; tm < 2; tm++)
#pragma unroll
            for (int f = 0; f < 4; f++) {
                AP[tm][f] = __builtin_amdgcn_mfma_f32_16x16x32_bf16(Ma[tm], KTb[f], zero4, 0, 0, 0);
                f32x4 a = __builtin_amdgcn_mfma_f32_16x16x32_bf16(Pa[tm][0], Hb[f][0], zero4, 0, 0, 0);
                A2[tm][f] = __builtin_amdgcn_mfma_f32_16x16x32_bf16(Pa[tm][1], Hb[f][1], a, 0, 0, 0);
            }
#pragma unroll
        for (int tm = 0; tm < 2; tm++)
#pragma unroll
            for (int f = 0; f < 4; f++)
#pragma unroll
                for (int reg = 0; reg < 4; reg++)
                    AP[tm][f][reg] = lam[f] * P[tm][f][reg] + AP[tm][f][reg] + et[tm][reg] * A2[tm][f][reg];
        // CG scalars
        float alpha[2][4], rsn[2][4];
#pragma unroll
        for (int tm = 0; tm < 2; tm++)
#pragma unroll
            for (int reg = 0; reg < 4; reg++) {
                float s = 0.f;
#pragma unroll
                for (int f = 0; f < 4; f++) s += P[tm][f][reg] * AP[tm][f][reg];
                s += __shfl_xor(s, 1); s += __shfl_xor(s, 2);
                s += __shfl_xor(s, 4); s += __shfl_xor(s, 8);
                alpha[tm][reg] = rs8[tm][reg] / (s + 1e-12f);
                rsn[tm][reg] = 0.f;
            }
#pragma unroll
        for (int tm = 0; tm < 2; tm++)
#pragma unroll
            for (int f = 0; f < 4; f++)
#pragma unroll
                for (int reg = 0; reg < 4; reg++) {
                    X[tm][f][reg] += alpha[tm][reg] * P[tm][f][reg];
                    float rv = R[tm][f][reg] - alpha[tm][reg] * AP[tm][f][reg];
                    R[tm][f][reg] = rv;
                    rsn[tm][reg] += rv * rv;
                }
#pragma unroll
        for (int tm = 0; tm < 2; tm++)
#pragma unroll
            for (int reg = 0; reg < 4; reg++) {
                float v = rsn[tm][reg];
                v += __shfl_xor(v, 1); v += __shfl_xor(v, 2);
                v += __shfl_xor(v, 4); v += __shfl_xor(v, 8);
                float btac = v / (rs8[tm][reg] + 1e-12f);
                rs8[tm][reg] = v;
#pragma unroll
                for (int f = 0; f < 4; f++)
                    P[tm][f][reg] = R[tm][f][reg] + btac * P[tm][f][reg];
            }
    }

    // ---- output phase ----
    // X -> sPw, Xa frags
#pragma unroll
    for (int tm = 0; tm < 2; tm++)
#pragma unroll
        for (int reg = 0; reg < 4; reg++)
#pragma unroll
            for (int f = 0; f < 4; f++)
                sPw[16 * tm + 4 * quad + reg][16 * f + l16] = f2bf(X[tm][f][reg]);
    __threadfence_block();
    bf16x8 Xa[2][2];
#pragma unroll
    for (int tm = 0; tm < 2; tm++)
#pragma unroll
        for (int ks = 0; ks < 2; ks++)
            Xa[tm][ks] = *reinterpret_cast<const bf16x8*>(&sPw[16 * tm + l16][8 * quad + 32 * ks]);
    // Do = X@K^T -> Mo
    f32x4 Do[2][2];
#pragma unroll
    for (int tm = 0; tm < 2; tm++)
#pragma unroll
        for (int sn = 0; sn < 2; sn++) {
            f32x4 d = __builtin_amdgcn_mfma_f32_16x16x32_bf16(Xa[tm][0], Kb[sn][0], zero4, 0, 0, 0);
            Do[tm][sn] = __builtin_amdgcn_mfma_f32_16x16x32_bf16(Xa[tm][1], Kb[sn][1], d, 0, 0, 0);
        }
#pragma unroll
    for (int tm = 0; tm < 2; tm++)
#pragma unroll
        for (int sn = 0; sn < 2; sn++)
#pragma unroll
            for (int reg = 0; reg < 4; reg++)
                sMw[16 * tm + 4 * quad + reg][16 * sn + l16] = f2bf(Co[tm][sn][reg] * Do[tm][sn][reg]);
    __threadfence_block();
    bf16x8 Mo[2];
#pragma unroll
    for (int tm = 0; tm < 2; tm++)
        Mo[tm] = *reinterpret_cast<const bf16x8*>(&sMw[16 * tm + l16][8 * quad]);
    // V B-frags (O1 = Mo@V): el j = V[8quad+j][16f+l16]
    bf16x8 Vb[4];
#pragma unroll
    for (int f = 0; f < 4; f++) {
        union { bf16x8 v; unsigned short u[8]; } r;
#pragma unroll
        for (int j = 0; j < 8; j++)
            r.u[j] = f2bf(vbuf[rbase + (size_t)(8 * quad + j) * 1024 + 16 * f + l16]);
        Vb[f] = r.v;
    }
    // HkvT B-frags (O2 = X@Hkv): el jj = Hkv[8quad+32ks+jj][16f+l16] = HkvT[16f+l16][...]
    bf16x8 Hvb[4][2];
#pragma unroll
    for (int f = 0; f < 4; f++) {
        const float* hr = HkvT0 + hbase + (size_t)(16 * f + l16) * 64;
#pragma unroll
        for (int ks = 0; ks < 2; ks++) {
            float4 a = *reinterpret_cast<const float4*>(hr + 8 * quad + 32 * ks);
            float4 c = *reinterpret_cast<const float4*>(hr + 8 * quad + 32 * ks + 4);
            Hvb[f][ks] = pack8(a, c);
        }
    }
    f32x4 O[2][4];
#pragma unroll
    for (int tm = 0; tm < 2; tm++)
#pragma unroll
        for (int f = 0; f < 4; f++) {
            f32x4 o1 = __builtin_amdgcn_mfma_f32_16x16x32_bf16(Mo[tm], Vb[f], zero4, 0, 0, 0);
            f32x4 o2 = __builtin_amdgcn_mfma_f32_16x16x32_bf16(Xa[tm][0], Hvb[f][0], zero4, 0, 0, 0);
            o2 = __builtin_amdgcn_mfma_f32_16x16x32_bf16(Xa[tm][1], Hvb[f][1], o2, 0, 0, 0);
#pragma unroll
            for (int reg = 0; reg < 4; reg++)
                O[tm][f][reg] = o1[reg] + et[tm][reg] * o2[reg];
        }
    // RMS norm per row + store bf16
#pragma unroll
    for (int tm = 0; tm < 2; tm++)
#pragma unroll
        for (int reg = 0; reg < 4; reg++) {
            float s = 0.f;
#pragma unroll
            for (int f = 0; f < 4; f++) s += O[tm][f][reg] * O[tm][f][reg];
            s += __shfl_xor(s, 1); s += __shfl_xor(s, 2);
            s += __shfl_xor(s, 4); s += __shfl_xor(s, 8);
            float scale = rsqrtf(s * (1.f / 64.f) + 1e-5f);
            size_t orow = rbase + (size_t)(16 * tm + 4 * quad + reg) * 1024;
#pragma unroll
            for (int f = 0; f < 4; f++)
                obf[orow + 16 * f + l16] = f2bf(O[tm][f][reg] * scale * nw[f]);
        }
}

// ---------------------------------------------------------------------------
extern "C" void kernel_launch(void* const* d_in, const int* in_sizes, int n_in,
                              void* d_out, int out_size, void* d_ws, size_t ws_size,
                              hipStream_t stream)
{
    const float* hidden   = (const float*)d_in[0];
    const float* Wq       = (const float*)d_in[1];
    const float* Wk       = (const float*)d_in[2];
    const float* Wv       = (const float*)d_in[3];
    const float* Wa       = (const float*)d_in[4];
    const float* Wb       = (const float*)d_in[5];
    const float* bb       = (const float*)d_in[6];
    const float* A_log    = (const float*)d_in[7];
    const float* dt_bias  = (const float*)d_in[8];
    const float* lambda_p = (const float*)d_in[9];
    const float* Wconv_q  = (const float*)d_in[10];
    const float* Wconv_k  = (const float*)d_in[11];
    const float* norm_w   = (const float*)d_in[12];
    const float* Wo       = (const float*)d_in[13];
    float* out = (float*)d_out;

    float* ws = (float*)d_ws;
    const size_t SZ_BIG = (size_t)2 * T_LEN * HIDN;   // 2M floats
    float* qpre = ws;
    float* kpre = qpre + SZ_BIG;
    float* vbuf = kpre + SZ_BIG;
    float* qbuf = vbuf + SZ_BIG;
    float* kbuf = qbuf + SZ_BIG;
    float* gbuf = kbuf + SZ_BIG;
    float* bbuf = gbuf + 32768;
    float* Gbuf = bbuf + 32768;
    float* btT  = Gbuf + 32768;
    float* Hkk0 = btT + 32768;                        // 4M floats
    float* HkvT0 = Hkk0 + (size_t)32 * NC * 4096;     // 4M floats
    unsigned short* WoT = (unsigned short*)(HkvT0 + (size_t)32 * NC * 4096);

    // bf16 staging aliased into regions dead until chunk_carry:
    unsigned short* hidden_bf = (unsigned short*)HkvT0;
    unsigned short* WqT = (unsigned short*)Hkk0;
    unsigned short* WkT = WqT + (size_t)HIDN * HIDN;
    unsigned short* WvT = WkT + (size_t)HIDN * HIDN;
    unsigned short* obuf_bf = (unsigned short*)kpre;  // kpre dead after conv

    const int M = 2 * T_LEN;                          // 2048

    cast_bf16<<<(M * HIDN / 4 + 255) / 256, 256, 0, stream>>>(hidden, hidden_bf, M * HIDN / 4);
    dim3 tg(HIDN / 64, HIDN / 64);
    transpose_cast<<<tg, 256, 0, stream>>>(Wq, WqT, HIDN, HIDN);
    transpose_cast<<<tg, 256, 0, stream>>>(Wk, WkT, HIDN, HIDN);
    transpose_cast<<<tg, 256, 0, stream>>>(Wv, WvT, HIDN, HIDN);
    transpose_cast<<<tg, 256, 0, stream>>>(Wo, WoT, HIDN, HIDN);

    dim3 gg(HIDN / 64, M / 64);
    gemm_bf16<<<gg, 256, 0, stream>>>(hidden_bf, WqT, qpre, M, HIDN, HIDN);
    gemm_bf16<<<gg, 256, 0, stream>>>(hidden_bf, WkT, kpre, M, HIDN, HIDN);
    gemm_bf16<<<gg, 256, 0, stream>>>(hidden_bf, WvT, vbuf, M, HIDN, HIDN);
    proj_gb<<<128, 256, 0, stream>>>(hidden, Wa, Wb, bb, A_log, dt_bias, gbuf, bbuf);
    cumsum_g<<<32, 1024, 0, stream>>>(gbuf, bbuf, Gbuf, btT);
    conv_silu_l2<<<M * NH / 4, 256, 0, stream>>>(qpre, Wconv_q, qbuf);
    conv_silu_l2<<<M * NH / 4, 256, 0, stream>>>(kpre, Wconv_k, kbuf);
    chunk_carry<<<64, 256, 0, stream>>>(kbuf, vbuf, Gbuf, btT, Hkk0, HkvT0);
    scan_mfma<<<256, 256, 0, stream>>>(qbuf, kbuf, vbuf, Gbuf, btT, Hkk0, HkvT0,
                                       lambda_p, norm_w, obuf_bf);
    gemm_bf16<<<gg, 256, 0, stream>>>(obuf_bf, WoT, out, M, HIDN, HIDN);
}

// Round 6
// 304.813 us; speedup vs baseline: 3.0112x; 1.1859x over previous
//
#include <hip/hip_runtime.h>
#include <hip/hip_bf16.h>
#include <stdint.h>

#define T_LEN 1024
#define HIDN  1024
#define NH    16
#define DKV   64
#define KCONV 4
#define CG_IT 15
#define CC    32              // chunk length
#define NC    (T_LEN / CC)    // 32 chunks
#define PAD   68              // padded row stride (fp32 LDS tiles)

typedef __attribute__((ext_vector_type(8))) short          bf16x8;
typedef __attribute__((ext_vector_type(8))) unsigned short u16x8;
typedef __attribute__((ext_vector_type(4))) unsigned short u16x4;
typedef __attribute__((ext_vector_type(4))) float          f32x4;

__device__ __forceinline__ float softplusf(float x) {
    return x > 20.f ? x : log1pf(expf(x));
}
__device__ __forceinline__ unsigned short f2bf(float x) {
    __hip_bfloat16 b = __float2bfloat16(x);
    return *reinterpret_cast<unsigned short*>(&b);
}
__device__ __forceinline__ bf16x8 pack8(float4 a, float4 b) {
    union { bf16x8 v; unsigned short u[8]; } r;
    r.u[0] = f2bf(a.x); r.u[1] = f2bf(a.y); r.u[2] = f2bf(a.z); r.u[3] = f2bf(a.w);
    r.u[4] = f2bf(b.x); r.u[5] = f2bf(b.y); r.u[6] = f2bf(b.z); r.u[7] = f2bf(b.w);
    return r.v;
}

// ---------------------------------------------------------------------------
// cast fp32 -> bf16, vectorized
// ---------------------------------------------------------------------------
__global__ __launch_bounds__(256) void cast_bf16(const float* __restrict__ src,
                                                 unsigned short* __restrict__ dst,
                                                 int n4)
{
    int i = blockIdx.x * 256 + threadIdx.x;
    if (i >= n4) return;
    float4 v = *reinterpret_cast<const float4*>(src + (size_t)i * 4);
    u16x4 o;
    o.x = f2bf(v.x); o.y = f2bf(v.y); o.z = f2bf(v.z); o.w = f2bf(v.w);
    *reinterpret_cast<u16x4*>(dst + (size_t)i * 4) = o;
}

// ---------------------------------------------------------------------------
// cast + transpose: W fp32 [K][N] -> WT bf16 [N][K].
// ---------------------------------------------------------------------------
__global__ __launch_bounds__(256) void transpose_cast(const float* __restrict__ W,
                                                      unsigned short* __restrict__ WT,
                                                      int K, int N)
{
    __shared__ unsigned short sT[64][68];
    int n0 = blockIdx.x * 64, k0 = blockIdx.y * 64;
    int tid = threadIdx.x;
    int rr = tid >> 4, cc4 = (tid & 15) * 4;
#pragma unroll
    for (int p = 0; p < 4; p++) {
        int r = p * 16 + rr;
        float4 v = *reinterpret_cast<const float4*>(&W[(size_t)(k0 + r) * N + n0 + cc4]);
        sT[cc4 + 0][r] = f2bf(v.x);
        sT[cc4 + 1][r] = f2bf(v.y);
        sT[cc4 + 2][r] = f2bf(v.z);
        sT[cc4 + 3][r] = f2bf(v.w);
    }
    __syncthreads();
#pragma unroll
    for (int p = 0; p < 4; p++) {
        int r = p * 16 + rr;
        u16x4 v = *reinterpret_cast<const u16x4*>(&sT[r][cc4]);
        *reinterpret_cast<u16x4*>(&WT[(size_t)(n0 + r) * K + k0 + cc4]) = v;
    }
}

// ---------------------------------------------------------------------------
// bf16 MFMA GEMM (TN): C[M,N] = A[M,K] @ B^T, Bt is [N][K].  64x64 tile.
// ---------------------------------------------------------------------------
__global__ __launch_bounds__(256) void gemm_bf16(const unsigned short* __restrict__ A,
                                                 const unsigned short* __restrict__ Bt,
                                                 float* __restrict__ C,
                                                 int M, int N, int K)
{
    __shared__ unsigned short sA[64][40];
    __shared__ unsigned short sB[64][40];
    const int tid = threadIdx.x;
    const int bm = blockIdx.y * 64, bn = blockIdx.x * 64;
    const int w = tid >> 6, lane = tid & 63;
    const int l16 = lane & 15, quad = lane >> 4;
    const int lrow = tid >> 2, lk = (tid & 3) * 8;

    f32x4 acc[4];
#pragma unroll
    for (int f = 0; f < 4; f++) acc[f] = (f32x4){0.f, 0.f, 0.f, 0.f};

    const size_t arow = (size_t)(bm + lrow) * K;
    const size_t brow = (size_t)(bn + lrow) * K;

    for (int k0 = 0; k0 < K; k0 += 32) {
        u16x8 av = *reinterpret_cast<const u16x8*>(A + arow + k0 + lk);
        u16x8 bv = *reinterpret_cast<const u16x8*>(Bt + brow + k0 + lk);
        *reinterpret_cast<u16x8*>(&sA[lrow][lk]) = av;
        *reinterpret_cast<u16x8*>(&sB[lrow][lk]) = bv;
        __syncthreads();

        bf16x8 aF = *reinterpret_cast<const bf16x8*>(&sA[w * 16 + l16][quad * 8]);
#pragma unroll
        for (int f = 0; f < 4; f++) {
            bf16x8 bF = *reinterpret_cast<const bf16x8*>(&sB[f * 16 + l16][quad * 8]);
            acc[f] = __builtin_amdgcn_mfma_f32_16x16x32_bf16(aF, bF, acc[f], 0, 0, 0);
        }
        __syncthreads();
    }

#pragma unroll
    for (int f = 0; f < 4; f++) {
#pragma unroll
        for (int i = 0; i < 4; i++) {
            int m = bm + w * 16 + quad * 4 + i;
            C[(size_t)m * N + bn + f * 16 + l16] = acc[f][i];
        }
    }
}

// ---------------------------------------------------------------------------
// Merged q/k/v GEMM: Bt = [3072][1024] (WqT|WkT|WvT contiguous).  Each 64-wide
// n-tile is routed to the matching [2048][1024] output (qpre|kpre|vbuf,
// contiguous at stride 2048*1024).  Same math as gemm_bf16.
// ---------------------------------------------------------------------------
__global__ __launch_bounds__(256) void gemm_qkv(const unsigned short* __restrict__ A,
                                                const unsigned short* __restrict__ Bt,
                                                float* __restrict__ C)
{
    const int K = 1024;
    __shared__ unsigned short sA[64][40];
    __shared__ unsigned short sB[64][40];
    const int tid = threadIdx.x;
    const int bm = blockIdx.y * 64, bn = blockIdx.x * 64;
    const int mat = bn >> 10, n0 = bn & 1023;
    const int w = tid >> 6, lane = tid & 63;
    const int l16 = lane & 15, quad = lane >> 4;
    const int lrow = tid >> 2, lk = (tid & 3) * 8;

    f32x4 acc[4];
#pragma unroll
    for (int f = 0; f < 4; f++) acc[f] = (f32x4){0.f, 0.f, 0.f, 0.f};

    const size_t arow = (size_t)(bm + lrow) * K;
    const size_t brow = (size_t)(bn + lrow) * K;

    for (int k0 = 0; k0 < K; k0 += 32) {
        u16x8 av = *reinterpret_cast<const u16x8*>(A + arow + k0 + lk);
        u16x8 bv = *reinterpret_cast<const u16x8*>(Bt + brow + k0 + lk);
        *reinterpret_cast<u16x8*>(&sA[lrow][lk]) = av;
        *reinterpret_cast<u16x8*>(&sB[lrow][lk]) = bv;
        __syncthreads();

        bf16x8 aF = *reinterpret_cast<const bf16x8*>(&sA[w * 16 + l16][quad * 8]);
#pragma unroll
        for (int f = 0; f < 4; f++) {
            bf16x8 bF = *reinterpret_cast<const bf16x8*>(&sB[f * 16 + l16][quad * 8]);
            acc[f] = __builtin_amdgcn_mfma_f32_16x16x32_bf16(aF, bF, acc[f], 0, 0, 0);
        }
        __syncthreads();
    }

    float* Cb = C + (size_t)mat * (2048u * 1024u);
#pragma unroll
    for (int f = 0; f < 4; f++) {
#pragma unroll
        for (int i = 0; i < 4; i++) {
            int m = bm + w * 16 + quad * 4 + i;
            Cb[(size_t)m * 1024 + n0 + f * 16 + l16] = acc[f][i];
        }
    }
}

// ---------------------------------------------------------------------------
// g / beta projections + nonlinearities.
// ---------------------------------------------------------------------------
__global__ __launch_bounds__(256) void proj_gb(const float* __restrict__ hidden,
                                               const float* __restrict__ Wa,
                                               const float* __restrict__ Wb,
                                               const float* __restrict__ bb,
                                               const float* __restrict__ A_log,
                                               const float* __restrict__ dt_bias,
                                               float* __restrict__ g_out,
                                               float* __restrict__ beta_out)
{
    int idx = blockIdx.x * 256 + threadIdx.x;
    int row = idx >> 4, h = idx & 15;
    const float* hr = hidden + (size_t)row * HIDN;
    float da = 0.f, db = 0.f;
    for (int i = 0; i < HIDN; i++) {
        float x = hr[i];
        da += x * Wa[i * NH + h];
        db += x * Wb[i * NH + h];
    }
    float sp = softplusf(da + dt_bias[h]);
    g_out[idx]    = -expf(A_log[h]) * sp;
    beta_out[idx] = 1.f / (1.f + expf(-(db + bb[h])));
}

// ---------------------------------------------------------------------------
// Inclusive cumsum of g over t per (b,h); transposes beta to [b,h,t].
// ---------------------------------------------------------------------------
__global__ __launch_bounds__(1024) void cumsum_g(const float* __restrict__ g_in,
                                                 const float* __restrict__ beta_in,
                                                 float* __restrict__ G_out,
                                                 float* __restrict__ betaT)
{
    __shared__ float s[1024];
    int bh = blockIdx.x;
    int b = bh >> 4, h = bh & 15;
    int t = threadIdx.x;
    size_t src = ((size_t)(b * T_LEN) + t) * NH + h;
    s[t] = g_in[src];
    float bt = beta_in[src];
    __syncthreads();
    for (int off = 1; off < 1024; off <<= 1) {
        float tmp = (t >= off) ? s[t - off] : 0.f;
        __syncthreads();
        s[t] += tmp;
        __syncthreads();
    }
    G_out[(size_t)bh * T_LEN + t] = s[t];
    betaT[(size_t)bh * T_LEN + t] = bt;
}

// ---------------------------------------------------------------------------
// causal depthwise conv (K=4) + silu + per-head l2norm.
// ---------------------------------------------------------------------------
__global__ __launch_bounds__(256) void conv_silu_l2(const float* __restrict__ pre,
                                                    const float* __restrict__ Wc,
                                                    float* __restrict__ out)
{
    int gid = blockIdx.x * 4 + (threadIdx.x >> 6);
    int lane = threadIdx.x & 63;
    int h = gid & 15;
    int t = (gid >> 4) & (T_LEN - 1);
    int b = gid >> 14;
    int c = h * DKV + lane;
    float acc = 0.f;
#pragma unroll
    for (int i = 0; i < KCONV; i++) {
        int ts = t - (KCONV - 1) + i;
        if (ts >= 0)
            acc += pre[((size_t)(b * T_LEN) + ts) * HIDN + c] * Wc[c * KCONV + i];
    }
    float y = acc / (1.f + expf(-acc));
    float ss = y * y;
#pragma unroll
    for (int m = 1; m < 64; m <<= 1) ss += __shfl_xor(ss, m);
    out[((size_t)(b * T_LEN) + t) * HIDN + c] = y * rsqrtf(ss + 1e-6f);
}

// ---------------------------------------------------------------------------
// Stage 1: per-chunk local contributions (fully parallel).
// A_kk[c] = sum_s w_s k_s k_s^T,  A_kvT[c] = sum_s w_s v_s k_s^T,
// w_s = exp(Gend_c - G_s) * beta_s.  grid = 2048 ((bh,chunk) x half).
// Written into Hkk0/HkvT0; stage 2 converts in-place to chunk-start states.
// ---------------------------------------------------------------------------
__global__ __launch_bounds__(256) void chunk_local(const float* __restrict__ kbuf,
                                                   const float* __restrict__ vbuf,
                                                   const float* __restrict__ G,
                                                   const float* __restrict__ betaT,
                                                   float* __restrict__ Akk,
                                                   float* __restrict__ AkvT)
{
    __shared__ float sK[CC][PAD];
    __shared__ float sV[CC][PAD];
    __shared__ float sW[CC];
    int bid = blockIdx.x;                 // 2048
    int half = bid & 1;
    int cidx = bid >> 1;                  // bh*NC + chunk
    int chunk = cidx & (NC - 1), bh = cidx >> 5;
    int b = bh >> 4, h = bh & 15;
    int tid = threadIdx.x;
    int i = half * 32 + (tid >> 3);       // row 0..63 (dk for kk, dv for kvT)
    int j0 = (tid & 7) * 8;
    int ls = tid >> 3, ld = (tid & 7) * 8;
    int t0 = chunk * CC;

    {
        size_t ga = (((size_t)(b * T_LEN) + t0 + ls) * NH + h) * 64 + ld;
        *reinterpret_cast<float4*>(&sK[ls][ld])     = *reinterpret_cast<const float4*>(&kbuf[ga]);
        *reinterpret_cast<float4*>(&sK[ls][ld + 4]) = *reinterpret_cast<const float4*>(&kbuf[ga + 4]);
        *reinterpret_cast<float4*>(&sV[ls][ld])     = *reinterpret_cast<const float4*>(&vbuf[ga]);
        *reinterpret_cast<float4*>(&sV[ls][ld + 4]) = *reinterpret_cast<const float4*>(&vbuf[ga + 4]);
        if (tid < CC) {
            float gv = G[(size_t)bh * T_LEN + t0 + tid];
            float bv = betaT[(size_t)bh * T_LEN + t0 + tid];
            float gend = __shfl(gv, 31);
            sW[tid] = expf(gend - gv) * bv;
        }
    }
    __syncthreads();

    float akk[8], akv[8];
#pragma unroll
    for (int j = 0; j < 8; j++) { akk[j] = 0.f; akv[j] = 0.f; }
#pragma unroll 4
    for (int s = 0; s < CC; s++) {
        float wk = sW[s] * sK[s][i];
        float wv = sW[s] * sV[s][i];
        float4 ka = *reinterpret_cast<const float4*>(&sK[s][j0]);
        float4 kb = *reinterpret_cast<const float4*>(&sK[s][j0 + 4]);
        akk[0] += wk * ka.x; akk[1] += wk * ka.y; akk[2] += wk * ka.z; akk[3] += wk * ka.w;
        akk[4] += wk * kb.x; akk[5] += wk * kb.y; akk[6] += wk * kb.z; akk[7] += wk * kb.w;
        akv[0] += wv * ka.x; akv[1] += wv * ka.y; akv[2] += wv * ka.z; akv[3] += wv * ka.w;
        akv[4] += wv * kb.x; akv[5] += wv * kb.y; akv[6] += wv * kb.z; akv[7] += wv * kb.w;
    }
    size_t ob = ((size_t)cidx * 64 + i) * 64 + j0;
    *reinterpret_cast<float4*>(&Akk[ob])      = make_float4(akk[0], akk[1], akk[2], akk[3]);
    *reinterpret_cast<float4*>(&Akk[ob + 4])  = make_float4(akk[4], akk[5], akk[6], akk[7]);
    *reinterpret_cast<float4*>(&AkvT[ob])     = make_float4(akv[0], akv[1], akv[2], akv[3]);
    *reinterpret_cast<float4*>(&AkvT[ob + 4]) = make_float4(akv[4], akv[5], akv[6], akv[7]);
}

// ---------------------------------------------------------------------------
// Stage 2: element-parallel prefix over chunks, in-place A_c -> H_c.
// H_c = E_{c-1},  E_c = dec_c*E_{c-1} + A_c.  grid = 256 x 256 threads:
// each thread owns one float4 of one matrix for one bh.
// ---------------------------------------------------------------------------
__global__ __launch_bounds__(256) void chunk_prefix(float* __restrict__ Hkk,
                                                    float* __restrict__ HkvT,
                                                    const float* __restrict__ G)
{
    __shared__ float sDec[NC];
    int blk = blockIdx.x;                 // 256
    int bh = blk >> 3, sub = blk & 7;
    int tid = threadIdx.x;
    if (tid < NC)
        sDec[tid] = (tid > 0)
            ? expf(G[(size_t)bh * T_LEN + tid * CC + CC - 1] - G[(size_t)bh * T_LEN + tid * CC - 1])
            : 1.f;
    __syncthreads();
    int flat = sub * 256 + tid;           // 0..2047
    int mat = flat >> 10, e4 = flat & 1023;
    float* base = (mat ? HkvT : Hkk) + (size_t)bh * NC * 4096 + (size_t)e4 * 4;
    float4 state = make_float4(0.f, 0.f, 0.f, 0.f);
#pragma unroll 1
    for (int c = 0; c < NC; c++) {
        float4* p = reinterpret_cast<float4*>(base + (size_t)c * 4096);
        float4 a = *p;
        *p = state;
        float d = sDec[c];
        state.x = d * state.x + a.x;
        state.y = d * state.y + a.y;
        state.z = d * state.z + a.z;
        state.w = d * state.w + a.w;
    }
}

// ---------------------------------------------------------------------------
// MFMA scan: ONE WAVE per (bh, chunk).  256 blocks x 4 waves = 1024 waves.
// ---------------------------------------------------------------------------
__global__ __launch_bounds__(256, 1) void scan_mfma(
    const float* __restrict__ qbuf, const float* __restrict__ kbuf,
    const float* __restrict__ vbuf, const float* __restrict__ G,
    const float* __restrict__ betaT, const float* __restrict__ Hkk0,
    const float* __restrict__ HkvT0, const float* __restrict__ lambda_p,
    const float* __restrict__ norm_w, unsigned short* __restrict__ obf)
{
    __shared__ __align__(16) unsigned short sP[4][32][72];
    __shared__ __align__(16) unsigned short sM[4][32][40];

    const int tid = threadIdx.x;
    const int wv = tid >> 6, lane = tid & 63;
    const int quad = lane >> 4, l16 = lane & 15;
    const int W = blockIdx.x * 4 + wv;          // 0..1023
    const int bh = W >> 5, chunk = W & 31;
    const int b = bh >> 4, h = bh & 15;
    const int t0 = chunk * CC;
    unsigned short (*sPw)[72] = sP[wv];
    unsigned short (*sMw)[40] = sM[wv];

    const size_t rbase = ((size_t)(b * T_LEN + t0) * NH + h) * 64;
    const float* Gb = G + (size_t)bh * T_LEN + t0;
    const float* Bb = betaT + (size_t)bh * T_LEN + t0;
    const float Gprev = (chunk > 0) ? Gb[-1] : 0.f;

    float Gt[2][4], et[2][4];
#pragma unroll
    for (int tm = 0; tm < 2; tm++)
#pragma unroll
        for (int reg = 0; reg < 4; reg++) {
            float g = Gb[16 * tm + 4 * quad + reg];
            Gt[tm][reg] = g;
            et[tm][reg] = expf(g - Gprev);
        }
    float Co[2][2][4];
#pragma unroll
    for (int sn = 0; sn < 2; sn++) {
        int s = 16 * sn + l16;
        float Gs = Gb[s], bts = Bb[s];
#pragma unroll
        for (int tm = 0; tm < 2; tm++)
#pragma unroll
            for (int reg = 0; reg < 4; reg++) {
                int t = 16 * tm + 4 * quad + reg;
                Co[tm][sn][reg] = (s <= t) ? expf(Gt[tm][reg] - Gs) * bts : 0.f;
            }
    }
    float lam[4], nw[4];
#pragma unroll
    for (int f = 0; f < 4; f++) {
        lam[f] = softplusf(lambda_p[h * 64 + 16 * f + l16]) + 0.25f;
        nw[f]  = norm_w[16 * f + l16];
    }

    bf16x8 Kb[2][2];
#pragma unroll
    for (int sn = 0; sn < 2; sn++) {
        const float* kr = kbuf + rbase + (size_t)(16 * sn + l16) * 1024;
#pragma unroll
        for (int ks = 0; ks < 2; ks++) {
            float4 a = *reinterpret_cast<const float4*>(kr + 8 * quad + 32 * ks);
            float4 c = *reinterpret_cast<const float4*>(kr + 8 * quad + 32 * ks + 4);
            Kb[sn][ks] = pack8(a, c);
        }
    }
    bf16x8 KTb[4];
#pragma unroll
    for (int f = 0; f < 4; f++) {
        union { bf16x8 v; unsigned short u[8]; } r;
#pragma unroll
        for (int j = 0; j < 8; j++)
            r.u[j] = f2bf(kbuf[rbase + (size_t)(8 * quad + j) * 1024 + 16 * f + l16]);
        KTb[f] = r.v;
    }
    const size_t hbase = ((size_t)(bh * NC) + chunk) * 4096;
    bf16x8 Hb[4][2];
#pragma unroll
    for (int f = 0; f < 4; f++) {
        const float* hr = Hkk0 + hbase + (size_t)(16 * f + l16) * 64;
#pragma unroll
        for (int ks = 0; ks < 2; ks++) {
            float4 a = *reinterpret_cast<const float4*>(hr + 8 * quad + 32 * ks);
            float4 c = *reinterpret_cast<const float4*>(hr + 8 * quad + 32 * ks + 4);
            Hb[f][ks] = pack8(a, c);
        }
    }

    f32x4 X[2][4], R[2][4], P[2][4];
    float rs8[2][4];
#pragma unroll
    for (int tm = 0; tm < 2; tm++)
#pragma unroll
        for (int reg = 0; reg < 4; reg++) rs8[tm][reg] = 0.f;
#pragma unroll
    for (int tm = 0; tm < 2; tm++)
#pragma unroll
        for (int f = 0; f < 4; f++) {
#pragma unroll
            for (int reg = 0; reg < 4; reg++) {
                float q = qbuf[rbase + (size_t)(16 * tm + 4 * quad + reg) * 1024 + 16 * f + l16];
                P[tm][f][reg] = q; R[tm][f][reg] = q; X[tm][f][reg] = 0.f;
                rs8[tm][reg] += q * q;
            }
        }
#pragma unroll
    for (int tm = 0; tm < 2; tm++)
#pragma unroll
        for (int reg = 0; reg < 4; reg++) {
            float v = rs8[tm][reg];
            v += __shfl_xor(v, 1); v += __shfl_xor(v, 2);
            v += __shfl_xor(v, 4); v += __shfl_xor(v, 8);
            rs8[tm][reg] = v;
        }

    const f32x4 zero4 = {0.f, 0.f, 0.f, 0.f};

#pragma unroll 1
    for (int it = 0; it < CG_IT; it++) {
#pragma unroll
        for (int tm = 0; tm < 2; tm++)
#pragma unroll
            for (int reg = 0; reg < 4; reg++)
#pragma unroll
                for (int f = 0; f < 4; f++)
                    sPw[16 * tm + 4 * quad + reg][16 * f + l16] = f2bf(P[tm][f][reg]);
        __threadfence_block();
        bf16x8 Pa[2][2];
#pragma unroll
        for (int tm = 0; tm < 2; tm++)
#pragma unroll
            for (int ks = 0; ks < 2; ks++)
                Pa[tm][ks] = *reinterpret_cast<const bf16x8*>(&sPw[16 * tm + l16][8 * quad + 32 * ks]);
        f32x4 D[2][2];
#pragma unroll
        for (int tm = 0; tm < 2; tm++)
#pragma unroll
            for (int sn = 0; sn < 2; sn++) {
                f32x4 d = __builtin_amdgcn_mfma_f32_16x16x32_bf16(Pa[tm][0], Kb[sn][0], zero4, 0, 0, 0);
                D[tm][sn] = __builtin_amdgcn_mfma_f32_16x16x32_bf16(Pa[tm][1], Kb[sn][1], d, 0, 0, 0);
            }
#pragma unroll
        for (int tm = 0; tm < 2; tm++)
#pragma unroll
            for (int sn = 0; sn < 2; sn++)
#pragma unroll
                for (int reg = 0; reg < 4; reg++)
                    sMw[16 * tm + 4 * quad + reg][16 * sn + l16] = f2bf(Co[tm][sn][reg] * D[tm][sn][reg]);
        __threadfence_block();
        bf16x8 Ma[2];
#pragma unroll
        for (int tm = 0; tm < 2; tm++)
            Ma[tm] = *reinterpret_cast<const bf16x8*>(&sMw[16 * tm + l16][8 * quad]);
        f32x4 AP[2][4], A2[2][4];
#pragma unroll
        for (int tm = 0; tm < 2; tm++)
#pragma unroll
            for (int f = 0; f < 4; f++) {
                AP[tm][f] = __builtin_amdgcn_mfma_f32_16x16x32_bf16(Ma[tm], KTb[f], zero4, 0, 0, 0);
                f32x4 a = __builtin_amdgcn_mfma_f32_16x16x32_bf16(Pa[tm][0], Hb[f][0], zero4, 0, 0, 0);
                A2[tm][f] = __builtin_amdgcn_mfma_f32_16x16x32_bf16(Pa[tm][1], Hb[f][1], a, 0, 0, 0);
            }
#pragma unroll
        for (int tm = 0; tm < 2; tm++)
#pragma unroll
            for (int f = 0; f < 4; f++)
#pragma unroll
                for (int reg = 0; reg < 4; reg++)
                    AP[tm][f][reg] = lam[f] * P[tm][f][reg] + AP[tm][f][reg] + et[tm][reg] * A2[tm][f][reg];
        float alpha[2][4], rsn[2][4];
#pragma unroll
        for (int tm = 0; tm < 2; tm++)
#pragma unroll
            for (int reg = 0; reg < 4; reg++) {
                float s = 0.f;
#pragma unroll
                for (int f = 0; f < 4; f++) s += P[tm][f][reg] * AP[tm][f][reg];
                s += __shfl_xor(s, 1); s += __shfl_xor(s, 2);
                s += __shfl_xor(s, 4); s += __shfl_xor(s, 8);
                alpha[tm][reg] = rs8[tm][reg] / (s + 1e-12f);
                rsn[tm][reg] = 0.f;
            }
#pragma unroll
        for (int tm = 0; tm < 2; tm++)
#pragma unroll
            for (int f = 0; f < 4; f++)
#pragma unroll
                for (int reg = 0; reg < 4; reg++) {
                    X[tm][f][reg] += alpha[tm][reg] * P[tm][f][reg];
                    float rv = R[tm][f][reg] - alpha[tm][reg] * AP[tm][f][reg];
                    R[tm][f][reg] = rv;
                    rsn[tm][reg] += rv * rv;
                }
#pragma unroll
        for (int tm = 0; tm < 2; tm++)
#pragma unroll
            for (int reg = 0; reg < 4; reg++) {
                float v = rsn[tm][reg];
                v += __shfl_xor(v, 1); v += __shfl_xor(v, 2);
                v += __shfl_xor(v, 4); v += __shfl_xor(v, 8);
                float btac = v / (rs8[tm][reg] + 1e-12f);
                rs8[tm][reg] = v;
#pragma unroll
                for (int f = 0; f < 4; f++)
                    P[tm][f][reg] = R[tm][f][reg] + btac * P[tm][f][reg];
            }
    }

    // ---- output phase ----
#pragma unroll
    for (int tm = 0; tm < 2; tm++)
#pragma unroll
        for (int reg = 0; reg < 4; reg++)
#pragma unroll
            for (int f = 0; f < 4; f++)
                sPw[16 * tm + 4 * quad + reg][16 * f + l16] = f2bf(X[tm][f][reg]);
    __threadfence_block();
    bf16x8 Xa[2][2];
#pragma unroll
    for (int tm = 0; tm < 2; tm++)
#pragma unroll
        for (int ks = 0; ks < 2; ks++)
            Xa[tm][ks] = *reinterpret_cast<const bf16x8*>(&sPw[16 * tm + l16][8 * quad + 32 * ks]);
    f32x4 Do[2][2];
#pragma unroll
    for (int tm = 0; tm < 2; tm++)
#pragma unroll
        for (int sn = 0; sn < 2; sn++) {
            f32x4 d = __builtin_amdgcn_mfma_f32_16x16x32_bf16(Xa[tm][0], Kb[sn][0], zero4, 0, 0, 0);
            Do[tm][sn] = __builtin_amdgcn_mfma_f32_16x16x32_bf16(Xa[tm][1], Kb[sn][1], d, 0, 0, 0);
        }
#pragma unroll
    for (int tm = 0; tm < 2; tm++)
#pragma unroll
        for (int sn = 0; sn < 2; sn++)
#pragma unroll
            for (int reg = 0; reg < 4; reg++)
                sMw[16 * tm + 4 * quad + reg][16 * sn + l16] = f2bf(Co[tm][sn][reg] * Do[tm][sn][reg]);
    __threadfence_block();
    bf16x8 Mo[2];
#pragma unroll
    for (int tm = 0; tm < 2; tm++)
        Mo[tm] = *reinterpret_cast<const bf16x8*>(&sMw[16 * tm + l16][8 * quad]);
    bf16x8 Vb[4];
#pragma unroll
    for (int f = 0; f < 4; f++) {
        union { bf16x8 v; unsigned short u[8]; } r;
#pragma unroll
        for (int j = 0; j < 8; j++)
            r.u[j] = f2bf(vbuf[rbase + (size_t)(8 * quad + j) * 1024 + 16 * f + l16]);
        Vb[f] = r.v;
    }
    bf16x8 Hvb[4][2];
#pragma unroll
    for (int f = 0; f < 4; f++) {
        const float* hr = HkvT0 + hbase + (size_t)(16 * f + l16) * 64;
#pragma unroll
        for (int ks = 0; ks < 2; ks++) {
            float4 a = *reinterpret_cast<const float4*>(hr + 8 * quad + 32 * ks);
            float4 c = *reinterpret_cast<const float4*>(hr + 8 * quad + 32 * ks + 4);
            Hvb[f][ks] = pack8(a, c);
        }
    }
    f32x4 O[2][4];
#pragma unroll
    for (int tm = 0; tm < 2; tm++)
#pragma unroll
        for (int f = 0; f < 4; f++) {
            f32x4 o1 = __builtin_amdgcn_mfma_f32_16x16x32_bf16(Mo[tm], Vb[f], zero4, 0, 0, 0);
            f32x4 o2 = __builtin_amdgcn_mfma_f32_16x16x32_bf16(Xa[tm][0], Hvb[f][0], zero4, 0, 0, 0);
            o2 = __builtin_amdgcn_mfma_f32_16x16x32_bf16(Xa[tm][1], Hvb[f][1], o2, 0, 0, 0);
#pragma unroll
            for (int reg = 0; reg < 4; reg++)
                O[tm][f][reg] = o1[reg] + et[tm][reg] * o2[reg];
        }
#pragma unroll
    for (int tm = 0; tm < 2; tm++)
#pragma unroll
        for (int reg = 0; reg < 4; reg++) {
            float s = 0.f;
#pragma unroll
            for (int f = 0; f < 4; f++) s += O[tm][f][reg] * O[tm][f][reg];
            s += __shfl_xor(s, 1); s += __shfl_xor(s, 2);
            s += __shfl_xor(s, 4); s += __shfl_xor(s, 8);
            float scale = rsqrtf(s * (1.f / 64.f) + 1e-5f);
            size_t orow = rbase + (size_t)(16 * tm + 4 * quad + reg) * 1024;
#pragma unroll
            for (int f = 0; f < 4; f++)
                obf[orow + 16 * f + l16] = f2bf(O[tm][f][reg] * scale * nw[f]);
        }
}

// ---------------------------------------------------------------------------
extern "C" void kernel_launch(void* const* d_in, const int* in_sizes, int n_in,
                              void* d_out, int out_size, void* d_ws, size_t ws_size,
                              hipStream_t stream)
{
    const float* hidden   = (const float*)d_in[0];
    const float* Wq       = (const float*)d_in[1];
    const float* Wk       = (const float*)d_in[2];
    const float* Wv       = (const float*)d_in[3];
    const float* Wa       = (const float*)d_in[4];
    const float* Wb       = (const float*)d_in[5];
    const float* bb       = (const float*)d_in[6];
    const float* A_log    = (const float*)d_in[7];
    const float* dt_bias  = (const float*)d_in[8];
    const float* lambda_p = (const float*)d_in[9];
    const float* Wconv_q  = (const float*)d_in[10];
    const float* Wconv_k  = (const float*)d_in[11];
    const float* norm_w   = (const float*)d_in[12];
    const float* Wo       = (const float*)d_in[13];
    float* out = (float*)d_out;

    float* ws = (float*)d_ws;
    const size_t SZ_BIG = (size_t)2 * T_LEN * HIDN;   // 2M floats
    float* qpre = ws;
    float* kpre = qpre + SZ_BIG;
    float* vbuf = kpre + SZ_BIG;
    float* qbuf = vbuf + SZ_BIG;
    float* kbuf = qbuf + SZ_BIG;
    float* gbuf = kbuf + SZ_BIG;
    float* bbuf = gbuf + 32768;
    float* Gbuf = bbuf + 32768;
    float* btT  = Gbuf + 32768;
    float* Hkk0 = btT + 32768;                        // 4M floats
    float* HkvT0 = Hkk0 + (size_t)32 * NC * 4096;     // 4M floats
    unsigned short* WoT = (unsigned short*)(HkvT0 + (size_t)32 * NC * 4096);

    // bf16 staging aliased into regions dead until chunk_local:
    unsigned short* hidden_bf = (unsigned short*)HkvT0;
    unsigned short* WqT = (unsigned short*)Hkk0;      // WqT|WkT|WvT contiguous = Bt[3072][1024]
    unsigned short* obuf_bf = (unsigned short*)kpre;  // kpre dead after conv

    const int M = 2 * T_LEN;                          // 2048

    cast_bf16<<<(M * HIDN / 4 + 255) / 256, 256, 0, stream>>>(hidden, hidden_bf, M * HIDN / 4);
    dim3 tg(HIDN / 64, HIDN / 64);
    transpose_cast<<<tg, 256, 0, stream>>>(Wq, WqT, HIDN, HIDN);
    transpose_cast<<<tg, 256, 0, stream>>>(Wk, WqT + (size_t)HIDN * HIDN, HIDN, HIDN);
    transpose_cast<<<tg, 256, 0, stream>>>(Wv, WqT + (size_t)2 * HIDN * HIDN, HIDN, HIDN);
    transpose_cast<<<tg, 256, 0, stream>>>(Wo, WoT, HIDN, HIDN);

    dim3 gq(3 * HIDN / 64, M / 64);                   // (48, 32) merged q/k/v
    gemm_qkv<<<gq, 256, 0, stream>>>(hidden_bf, WqT, qpre);
    proj_gb<<<128, 256, 0, stream>>>(hidden, Wa, Wb, bb, A_log, dt_bias, gbuf, bbuf);
    cumsum_g<<<32, 1024, 0, stream>>>(gbuf, bbuf, Gbuf, btT);
    conv_silu_l2<<<M * NH / 4, 256, 0, stream>>>(qpre, Wconv_q, qbuf);
    conv_silu_l2<<<M * NH / 4, 256, 0, stream>>>(kpre, Wconv_k, kbuf);
    chunk_local<<<2048, 256, 0, stream>>>(kbuf, vbuf, Gbuf, btT, Hkk0, HkvT0);
    chunk_prefix<<<256, 256, 0, stream>>>(Hkk0, HkvT0, Gbuf);
    scan_mfma<<<256, 256, 0, stream>>>(qbuf, kbuf, vbuf, Gbuf, btT, Hkk0, HkvT0,
                                       lambda_p, norm_w, obuf_bf);
    dim3 gg(HIDN / 64, M / 64);
    gemm_bf16<<<gg, 256, 0, stream>>>(obuf_bf, WoT, out, M, HIDN, HIDN);
}

// Round 7
// 284.444 us; speedup vs baseline: 3.2268x; 1.0716x over previous
//
#include <hip/hip_runtime.h>
#include <hip/hip_bf16.h>
#include <stdint.h>

#define T_LEN 1024
#define HIDN  1024
#define NH    16
#define DKV   64
#define KCONV 4
#define CG_IT 15
#define CC    32              // chunk length
#define NC    (T_LEN / CC)    // 32 chunks
#define PAD   68              // padded row stride (fp32 LDS tiles)

typedef __attribute__((ext_vector_type(8))) short          bf16x8;
typedef __attribute__((ext_vector_type(8))) unsigned short u16x8;
typedef __attribute__((ext_vector_type(4))) unsigned short u16x4;
typedef __attribute__((ext_vector_type(4))) float          f32x4;

__device__ __forceinline__ float softplusf(float x) {
    return x > 20.f ? x : log1pf(expf(x));
}
__device__ __forceinline__ unsigned short f2bf(float x) {
    __hip_bfloat16 b = __float2bfloat16(x);
    return *reinterpret_cast<unsigned short*>(&b);
}
__device__ __forceinline__ bf16x8 pack8(float4 a, float4 b) {
    union { bf16x8 v; unsigned short u[8]; } r;
    r.u[0] = f2bf(a.x); r.u[1] = f2bf(a.y); r.u[2] = f2bf(a.z); r.u[3] = f2bf(a.w);
    r.u[4] = f2bf(b.x); r.u[5] = f2bf(b.y); r.u[6] = f2bf(b.z); r.u[7] = f2bf(b.w);
    return r.v;
}

// ---------------------------------------------------------------------------
// cast fp32 -> bf16, vectorized
// ---------------------------------------------------------------------------
__global__ __launch_bounds__(256) void cast_bf16(const float* __restrict__ src,
                                                 unsigned short* __restrict__ dst,
                                                 int n4)
{
    int i = blockIdx.x * 256 + threadIdx.x;
    if (i >= n4) return;
    float4 v = *reinterpret_cast<const float4*>(src + (size_t)i * 4);
    u16x4 o;
    o.x = f2bf(v.x); o.y = f2bf(v.y); o.z = f2bf(v.z); o.w = f2bf(v.w);
    *reinterpret_cast<u16x4*>(dst + (size_t)i * 4) = o;
}

// ---------------------------------------------------------------------------
// cast + transpose: W fp32 [K][N] -> WT bf16 [N][K].
// ---------------------------------------------------------------------------
__global__ __launch_bounds__(256) void transpose_cast(const float* __restrict__ W,
                                                      unsigned short* __restrict__ WT,
                                                      int K, int N)
{
    __shared__ unsigned short sT[64][68];
    int n0 = blockIdx.x * 64, k0 = blockIdx.y * 64;
    int tid = threadIdx.x;
    int rr = tid >> 4, cc4 = (tid & 15) * 4;
#pragma unroll
    for (int p = 0; p < 4; p++) {
        int r = p * 16 + rr;
        float4 v = *reinterpret_cast<const float4*>(&W[(size_t)(k0 + r) * N + n0 + cc4]);
        sT[cc4 + 0][r] = f2bf(v.x);
        sT[cc4 + 1][r] = f2bf(v.y);
        sT[cc4 + 2][r] = f2bf(v.z);
        sT[cc4 + 3][r] = f2bf(v.w);
    }
    __syncthreads();
#pragma unroll
    for (int p = 0; p < 4; p++) {
        int r = p * 16 + rr;
        u16x4 v = *reinterpret_cast<const u16x4*>(&sT[r][cc4]);
        *reinterpret_cast<u16x4*>(&WT[(size_t)(n0 + r) * K + k0 + cc4]) = v;
    }
}

// ---------------------------------------------------------------------------
// bf16 MFMA GEMM (TN): C[M,N] = A[M,K] @ B^T, Bt is [N][K].  64x64 tile.
// ---------------------------------------------------------------------------
__global__ __launch_bounds__(256) void gemm_bf16(const unsigned short* __restrict__ A,
                                                 const unsigned short* __restrict__ Bt,
                                                 float* __restrict__ C,
                                                 int M, int N, int K)
{
    __shared__ unsigned short sA[64][40];
    __shared__ unsigned short sB[64][40];
    const int tid = threadIdx.x;
    const int bm = blockIdx.y * 64, bn = blockIdx.x * 64;
    const int w = tid >> 6, lane = tid & 63;
    const int l16 = lane & 15, quad = lane >> 4;
    const int lrow = tid >> 2, lk = (tid & 3) * 8;

    f32x4 acc[4];
#pragma unroll
    for (int f = 0; f < 4; f++) acc[f] = (f32x4){0.f, 0.f, 0.f, 0.f};

    const size_t arow = (size_t)(bm + lrow) * K;
    const size_t brow = (size_t)(bn + lrow) * K;

    for (int k0 = 0; k0 < K; k0 += 32) {
        u16x8 av = *reinterpret_cast<const u16x8*>(A + arow + k0 + lk);
        u16x8 bv = *reinterpret_cast<const u16x8*>(Bt + brow + k0 + lk);
        *reinterpret_cast<u16x8*>(&sA[lrow][lk]) = av;
        *reinterpret_cast<u16x8*>(&sB[lrow][lk]) = bv;
        __syncthreads();

        bf16x8 aF = *reinterpret_cast<const bf16x8*>(&sA[w * 16 + l16][quad * 8]);
#pragma unroll
        for (int f = 0; f < 4; f++) {
            bf16x8 bF = *reinterpret_cast<const bf16x8*>(&sB[f * 16 + l16][quad * 8]);
            acc[f] = __builtin_amdgcn_mfma_f32_16x16x32_bf16(aF, bF, acc[f], 0, 0, 0);
        }
        __syncthreads();
    }

#pragma unroll
    for (int f = 0; f < 4; f++) {
#pragma unroll
        for (int i = 0; i < 4; i++) {
            int m = bm + w * 16 + quad * 4 + i;
            C[(size_t)m * N + bn + f * 16 + l16] = acc[f][i];
        }
    }
}

// ---------------------------------------------------------------------------
// Merged q/k/v GEMM: Bt = [3072][1024].
// ---------------------------------------------------------------------------
__global__ __launch_bounds__(256) void gemm_qkv(const unsigned short* __restrict__ A,
                                                const unsigned short* __restrict__ Bt,
                                                float* __restrict__ C)
{
    const int K = 1024;
    __shared__ unsigned short sA[64][40];
    __shared__ unsigned short sB[64][40];
    const int tid = threadIdx.x;
    const int bm = blockIdx.y * 64, bn = blockIdx.x * 64;
    const int mat = bn >> 10, n0 = bn & 1023;
    const int w = tid >> 6, lane = tid & 63;
    const int l16 = lane & 15, quad = lane >> 4;
    const int lrow = tid >> 2, lk = (tid & 3) * 8;

    f32x4 acc[4];
#pragma unroll
    for (int f = 0; f < 4; f++) acc[f] = (f32x4){0.f, 0.f, 0.f, 0.f};

    const size_t arow = (size_t)(bm + lrow) * K;
    const size_t brow = (size_t)(bn + lrow) * K;

    for (int k0 = 0; k0 < K; k0 += 32) {
        u16x8 av = *reinterpret_cast<const u16x8*>(A + arow + k0 + lk);
        u16x8 bv = *reinterpret_cast<const u16x8*>(Bt + brow + k0 + lk);
        *reinterpret_cast<u16x8*>(&sA[lrow][lk]) = av;
        *reinterpret_cast<u16x8*>(&sB[lrow][lk]) = bv;
        __syncthreads();

        bf16x8 aF = *reinterpret_cast<const bf16x8*>(&sA[w * 16 + l16][quad * 8]);
#pragma unroll
        for (int f = 0; f < 4; f++) {
            bf16x8 bF = *reinterpret_cast<const bf16x8*>(&sB[f * 16 + l16][quad * 8]);
            acc[f] = __builtin_amdgcn_mfma_f32_16x16x32_bf16(aF, bF, acc[f], 0, 0, 0);
        }
        __syncthreads();
    }

    float* Cb = C + (size_t)mat * (2048u * 1024u);
#pragma unroll
    for (int f = 0; f < 4; f++) {
#pragma unroll
        for (int i = 0; i < 4; i++) {
            int m = bm + w * 16 + quad * 4 + i;
            Cb[(size_t)m * 1024 + n0 + f * 16 + l16] = acc[f][i];
        }
    }
}

// ---------------------------------------------------------------------------
// g / beta projections: ONE WAVE PER ROW.  Lane l holds x[16l..16l+16),
// accumulates all 16 heads, butterfly-reduce, lanes 0..15 write.
// ---------------------------------------------------------------------------
__global__ __launch_bounds__(256) void proj_gb(const float* __restrict__ hidden,
                                               const float* __restrict__ Wa,
                                               const float* __restrict__ Wb,
                                               const float* __restrict__ bb,
                                               const float* __restrict__ A_log,
                                               const float* __restrict__ dt_bias,
                                               float* __restrict__ g_out,
                                               float* __restrict__ beta_out)
{
    int wvid = threadIdx.x >> 6, lane = threadIdx.x & 63;
    int row = blockIdx.x * 4 + wvid;            // 0..2047
    const float* hr = hidden + (size_t)row * HIDN + 16 * lane;
    const float* war = Wa + (size_t)(16 * lane) * NH;
    const float* wbr = Wb + (size_t)(16 * lane) * NH;

    float da[16], db[16];
#pragma unroll
    for (int h = 0; h < 16; h++) { da[h] = 0.f; db[h] = 0.f; }

#pragma unroll
    for (int j = 0; j < 16; j += 4) {
        float4 xv = *reinterpret_cast<const float4*>(hr + j);
        float xs[4] = {xv.x, xv.y, xv.z, xv.w};
#pragma unroll
        for (int e = 0; e < 4; e++) {
            int i = j + e;
            float x = xs[e];
            const float4* wa4 = reinterpret_cast<const float4*>(war + i * NH);
            const float4* wb4 = reinterpret_cast<const float4*>(wbr + i * NH);
#pragma unroll
            for (int q = 0; q < 4; q++) {
                float4 wa = wa4[q], wb = wb4[q];
                da[q * 4 + 0] += x * wa.x; da[q * 4 + 1] += x * wa.y;
                da[q * 4 + 2] += x * wa.z; da[q * 4 + 3] += x * wa.w;
                db[q * 4 + 0] += x * wb.x; db[q * 4 + 1] += x * wb.y;
                db[q * 4 + 2] += x * wb.z; db[q * 4 + 3] += x * wb.w;
            }
        }
    }
#pragma unroll
    for (int m = 1; m < 64; m <<= 1) {
#pragma unroll
        for (int h = 0; h < 16; h++) {
            da[h] += __shfl_xor(da[h], m);
            db[h] += __shfl_xor(db[h], m);
        }
    }
    float dah = 0.f, dbh = 0.f;
#pragma unroll
    for (int h = 0; h < 16; h++) {
        bool sel = (lane == h);
        dah = sel ? da[h] : dah;
        dbh = sel ? db[h] : dbh;
    }
    if (lane < 16) {
        float sp = softplusf(dah + dt_bias[lane]);
        g_out[row * NH + lane]    = -expf(A_log[lane]) * sp;
        beta_out[row * NH + lane] = 1.f / (1.f + expf(-(dbh + bb[lane])));
    }
}

// ---------------------------------------------------------------------------
// Inclusive cumsum of g over t per (b,h); transposes beta to [b,h,t].
// ---------------------------------------------------------------------------
__global__ __launch_bounds__(1024) void cumsum_g(const float* __restrict__ g_in,
                                                 const float* __restrict__ beta_in,
                                                 float* __restrict__ G_out,
                                                 float* __restrict__ betaT)
{
    __shared__ float s[1024];
    int bh = blockIdx.x;
    int b = bh >> 4, h = bh & 15;
    int t = threadIdx.x;
    size_t src = ((size_t)(b * T_LEN) + t) * NH + h;
    s[t] = g_in[src];
    float bt = beta_in[src];
    __syncthreads();
    for (int off = 1; off < 1024; off <<= 1) {
        float tmp = (t >= off) ? s[t - off] : 0.f;
        __syncthreads();
        s[t] += tmp;
        __syncthreads();
    }
    G_out[(size_t)bh * T_LEN + t] = s[t];
    betaT[(size_t)bh * T_LEN + t] = bt;
}

// ---------------------------------------------------------------------------
// causal depthwise conv (K=4) + silu + per-head l2norm.
// ---------------------------------------------------------------------------
__global__ __launch_bounds__(256) void conv_silu_l2(const float* __restrict__ pre,
                                                    const float* __restrict__ Wc,
                                                    float* __restrict__ out)
{
    int gid = blockIdx.x * 4 + (threadIdx.x >> 6);
    int lane = threadIdx.x & 63;
    int h = gid & 15;
    int t = (gid >> 4) & (T_LEN - 1);
    int b = gid >> 14;
    int c = h * DKV + lane;
    float acc = 0.f;
#pragma unroll
    for (int i = 0; i < KCONV; i++) {
        int ts = t - (KCONV - 1) + i;
        if (ts >= 0)
            acc += pre[((size_t)(b * T_LEN) + ts) * HIDN + c] * Wc[c * KCONV + i];
    }
    float y = acc / (1.f + expf(-acc));
    float ss = y * y;
#pragma unroll
    for (int m = 1; m < 64; m <<= 1) ss += __shfl_xor(ss, m);
    out[((size_t)(b * T_LEN) + t) * HIDN + c] = y * rsqrtf(ss + 1e-6f);
}

// ---------------------------------------------------------------------------
// Stage 1: per-chunk local contributions (fully parallel).
// ---------------------------------------------------------------------------
__global__ __launch_bounds__(256) void chunk_local(const float* __restrict__ kbuf,
                                                   const float* __restrict__ vbuf,
                                                   const float* __restrict__ G,
                                                   const float* __restrict__ betaT,
                                                   float* __restrict__ Akk,
                                                   float* __restrict__ AkvT)
{
    __shared__ float sK[CC][PAD];
    __shared__ float sV[CC][PAD];
    __shared__ float sW[CC];
    int bid = blockIdx.x;                 // 2048
    int half = bid & 1;
    int cidx = bid >> 1;
    int chunk = cidx & (NC - 1), bh = cidx >> 5;
    int b = bh >> 4, h = bh & 15;
    int tid = threadIdx.x;
    int i = half * 32 + (tid >> 3);
    int j0 = (tid & 7) * 8;
    int ls = tid >> 3, ld = (tid & 7) * 8;
    int t0 = chunk * CC;

    {
        size_t ga = (((size_t)(b * T_LEN) + t0 + ls) * NH + h) * 64 + ld;
        *reinterpret_cast<float4*>(&sK[ls][ld])     = *reinterpret_cast<const float4*>(&kbuf[ga]);
        *reinterpret_cast<float4*>(&sK[ls][ld + 4]) = *reinterpret_cast<const float4*>(&kbuf[ga + 4]);
        *reinterpret_cast<float4*>(&sV[ls][ld])     = *reinterpret_cast<const float4*>(&vbuf[ga]);
        *reinterpret_cast<float4*>(&sV[ls][ld + 4]) = *reinterpret_cast<const float4*>(&vbuf[ga + 4]);
        if (tid < CC) {
            float gv = G[(size_t)bh * T_LEN + t0 + tid];
            float bv = betaT[(size_t)bh * T_LEN + t0 + tid];
            float gend = __shfl(gv, 31);
            sW[tid] = expf(gend - gv) * bv;
        }
    }
    __syncthreads();

    float akk[8], akv[8];
#pragma unroll
    for (int j = 0; j < 8; j++) { akk[j] = 0.f; akv[j] = 0.f; }
#pragma unroll 4
    for (int s = 0; s < CC; s++) {
        float wk = sW[s] * sK[s][i];
        float wv = sW[s] * sV[s][i];
        float4 ka = *reinterpret_cast<const float4*>(&sK[s][j0]);
        float4 kb = *reinterpret_cast<const float4*>(&sK[s][j0 + 4]);
        akk[0] += wk * ka.x; akk[1] += wk * ka.y; akk[2] += wk * ka.z; akk[3] += wk * ka.w;
        akk[4] += wk * kb.x; akk[5] += wk * kb.y; akk[6] += wk * kb.z; akk[7] += wk * kb.w;
        akv[0] += wv * ka.x; akv[1] += wv * ka.y; akv[2] += wv * ka.z; akv[3] += wv * ka.w;
        akv[4] += wv * kb.x; akv[5] += wv * kb.y; akv[6] += wv * kb.z; akv[7] += wv * kb.w;
    }
    size_t ob = ((size_t)cidx * 64 + i) * 64 + j0;
    *reinterpret_cast<float4*>(&Akk[ob])      = make_float4(akk[0], akk[1], akk[2], akk[3]);
    *reinterpret_cast<float4*>(&Akk[ob + 4])  = make_float4(akk[4], akk[5], akk[6], akk[7]);
    *reinterpret_cast<float4*>(&AkvT[ob])     = make_float4(akv[0], akv[1], akv[2], akv[3]);
    *reinterpret_cast<float4*>(&AkvT[ob + 4]) = make_float4(akv[4], akv[5], akv[6], akv[7]);
}

// ---------------------------------------------------------------------------
// Stage 2: element-parallel prefix over chunks, in-place A_c -> H_c.
// ---------------------------------------------------------------------------
__global__ __launch_bounds__(256) void chunk_prefix(float* __restrict__ Hkk,
                                                    float* __restrict__ HkvT,
                                                    const float* __restrict__ G)
{
    __shared__ float sDec[NC];
    int blk = blockIdx.x;                 // 256
    int bh = blk >> 3, sub = blk & 7;
    int tid = threadIdx.x;
    if (tid < NC)
        sDec[tid] = (tid > 0)
            ? expf(G[(size_t)bh * T_LEN + tid * CC + CC - 1] - G[(size_t)bh * T_LEN + tid * CC - 1])
            : 1.f;
    __syncthreads();
    int flat = sub * 256 + tid;           // 0..2047
    int mat = flat >> 10, e4 = flat & 1023;
    float* base = (mat ? HkvT : Hkk) + (size_t)bh * NC * 4096 + (size_t)e4 * 4;
    float4 state = make_float4(0.f, 0.f, 0.f, 0.f);
#pragma unroll 1
    for (int c = 0; c < NC; c++) {
        float4* p = reinterpret_cast<float4*>(base + (size_t)c * 4096);
        float4 a = *p;
        *p = state;
        float d = sDec[c];
        state.x = d * state.x + a.x;
        state.y = d * state.y + a.y;
        state.z = d * state.z + a.z;
        state.w = d * state.w + a.w;
    }
}

// ---------------------------------------------------------------------------
// MFMA scan: ONE WAVE per (bh, chunk, half16) -> 2048 waves, 512 blocks.
// Each wave owns 16 t-rows; per-row CG solves are independent, so results
// are bitwise-identical to the 32-row version.
// ---------------------------------------------------------------------------
__global__ __launch_bounds__(256, 2) void scan_mfma(
    const float* __restrict__ qbuf, const float* __restrict__ kbuf,
    const float* __restrict__ vbuf, const float* __restrict__ G,
    const float* __restrict__ betaT, const float* __restrict__ Hkk0,
    const float* __restrict__ HkvT0, const float* __restrict__ lambda_p,
    const float* __restrict__ norm_w, unsigned short* __restrict__ obf)
{
    __shared__ __align__(16) unsigned short sP[4][16][72];
    __shared__ __align__(16) unsigned short sM[4][16][40];

    const int tid = threadIdx.x;
    const int wv = tid >> 6, lane = tid & 63;
    const int quad = lane >> 4, l16 = lane & 15;
    const int W = blockIdx.x * 4 + wv;          // 0..2047
    const int half = W & 1;
    const int cidx = W >> 1;                    // 0..1023
    const int bh = cidx >> 5, chunk = cidx & 31;
    const int b = bh >> 4, h = bh & 15;
    const int t0 = chunk * CC;
    const int rbofs = 16 * half + 4 * quad;     // +reg -> local t-row
    unsigned short (*sPw)[72] = sP[wv];
    unsigned short (*sMw)[40] = sM[wv];

    const size_t rbase = ((size_t)(b * T_LEN + t0) * NH + h) * 64;
    const float* Gb = G + (size_t)bh * T_LEN + t0;
    const float* Bb = betaT + (size_t)bh * T_LEN + t0;
    const float Gprev = (chunk > 0) ? Gb[-1] : 0.f;

    float Gt[4], et[4];
#pragma unroll
    for (int reg = 0; reg < 4; reg++) {
        float g = Gb[rbofs + reg];
        Gt[reg] = g;
        et[reg] = expf(g - Gprev);
    }
    float Co[2][4];
#pragma unroll
    for (int sn = 0; sn < 2; sn++) {
        int s = 16 * sn + l16;
        float Gs = Gb[s], bts = Bb[s];
#pragma unroll
        for (int reg = 0; reg < 4; reg++) {
            int t = rbofs + reg;
            Co[sn][reg] = (s <= t) ? expf(Gt[reg] - Gs) * bts : 0.f;
        }
    }
    float lam[4], nw[4];
#pragma unroll
    for (int f = 0; f < 4; f++) {
        lam[f] = softplusf(lambda_p[h * 64 + 16 * f + l16]) + 0.25f;
        nw[f]  = norm_w[16 * f + l16];
    }

    bf16x8 Kb[2][2];
#pragma unroll
    for (int sn = 0; sn < 2; sn++) {
        const float* kr = kbuf + rbase + (size_t)(16 * sn + l16) * 1024;
#pragma unroll
        for (int ks = 0; ks < 2; ks++) {
            float4 a = *reinterpret_cast<const float4*>(kr + 8 * quad + 32 * ks);
            float4 c = *reinterpret_cast<const float4*>(kr + 8 * quad + 32 * ks + 4);
            Kb[sn][ks] = pack8(a, c);
        }
    }
    bf16x8 KTb[4];
#pragma unroll
    for (int f = 0; f < 4; f++) {
        union { bf16x8 v; unsigned short u[8]; } r;
#pragma unroll
        for (int j = 0; j < 8; j++)
            r.u[j] = f2bf(kbuf[rbase + (size_t)(8 * quad + j) * 1024 + 16 * f + l16]);
        KTb[f] = r.v;
    }
    const size_t hbase = ((size_t)(bh * NC) + chunk) * 4096;
    bf16x8 Hb[4][2];
#pragma unroll
    for (int f = 0; f < 4; f++) {
        const float* hr = Hkk0 + hbase + (size_t)(16 * f + l16) * 64;
#pragma unroll
        for (int ks = 0; ks < 2; ks++) {
            float4 a = *reinterpret_cast<const float4*>(hr + 8 * quad + 32 * ks);
            float4 c = *reinterpret_cast<const float4*>(hr + 8 * quad + 32 * ks + 4);
            Hb[f][ks] = pack8(a, c);
        }
    }

    f32x4 X[4], R[4], P[4];
    float rs8[4];
#pragma unroll
    for (int reg = 0; reg < 4; reg++) rs8[reg] = 0.f;
#pragma unroll
    for (int f = 0; f < 4; f++) {
#pragma unroll
        for (int reg = 0; reg < 4; reg++) {
            float q = qbuf[rbase + (size_t)(rbofs + reg) * 1024 + 16 * f + l16];
            P[f][reg] = q; R[f][reg] = q; X[f][reg] = 0.f;
            rs8[reg] += q * q;
        }
    }
#pragma unroll
    for (int reg = 0; reg < 4; reg++) {
        float v = rs8[reg];
        v += __shfl_xor(v, 1); v += __shfl_xor(v, 2);
        v += __shfl_xor(v, 4); v += __shfl_xor(v, 8);
        rs8[reg] = v;
    }

    const f32x4 zero4 = {0.f, 0.f, 0.f, 0.f};

#pragma unroll 1
    for (int it = 0; it < CG_IT; it++) {
#pragma unroll
        for (int reg = 0; reg < 4; reg++)
#pragma unroll
            for (int f = 0; f < 4; f++)
                sPw[4 * quad + reg][16 * f + l16] = f2bf(P[f][reg]);
        __threadfence_block();
        bf16x8 Pa[2];
#pragma unroll
        for (int ks = 0; ks < 2; ks++)
            Pa[ks] = *reinterpret_cast<const bf16x8*>(&sPw[l16][8 * quad + 32 * ks]);
        f32x4 D[2];
#pragma unroll
        for (int sn = 0; sn < 2; sn++) {
            f32x4 d = __builtin_amdgcn_mfma_f32_16x16x32_bf16(Pa[0], Kb[sn][0], zero4, 0, 0, 0);
            D[sn] = __builtin_amdgcn_mfma_f32_16x16x32_bf16(Pa[1], Kb[sn][1], d, 0, 0, 0);
        }
#pragma unroll
        for (int sn = 0; sn < 2; sn++)
#pragma unroll
            for (int reg = 0; reg < 4; reg++)
                sMw[4 * quad + reg][16 * sn + l16] = f2bf(Co[sn][reg] * D[sn][reg]);
        __threadfence_block();
        bf16x8 Ma = *reinterpret_cast<const bf16x8*>(&sMw[l16][8 * quad]);
        f32x4 AP[4], A2[4];
#pragma unroll
        for (int f = 0; f < 4; f++) {
            AP[f] = __builtin_amdgcn_mfma_f32_16x16x32_bf16(Ma, KTb[f], zero4, 0, 0, 0);
            f32x4 a = __builtin_amdgcn_mfma_f32_16x16x32_bf16(Pa[0], Hb[f][0], zero4, 0, 0, 0);
            A2[f] = __builtin_amdgcn_mfma_f32_16x16x32_bf16(Pa[1], Hb[f][1], a, 0, 0, 0);
        }
#pragma unroll
        for (int f = 0; f < 4; f++)
#pragma unroll
            for (int reg = 0; reg < 4; reg++)
                AP[f][reg] = lam[f] * P[f][reg] + AP[f][reg] + et[reg] * A2[f][reg];
        float alpha[4], rsn[4];
#pragma unroll
        for (int reg = 0; reg < 4; reg++) {
            float s = 0.f;
#pragma unroll
            for (int f = 0; f < 4; f++) s += P[f][reg] * AP[f][reg];
            s += __shfl_xor(s, 1); s += __shfl_xor(s, 2);
            s += __shfl_xor(s, 4); s += __shfl_xor(s, 8);
            alpha[reg] = rs8[reg] / (s + 1e-12f);
            rsn[reg] = 0.f;
        }
#pragma unroll
        for (int f = 0; f < 4; f++)
#pragma unroll
            for (int reg = 0; reg < 4; reg++) {
                X[f][reg] += alpha[reg] * P[f][reg];
                float rv = R[f][reg] - alpha[reg] * AP[f][reg];
                R[f][reg] = rv;
                rsn[reg] += rv * rv;
            }
#pragma unroll
        for (int reg = 0; reg < 4; reg++) {
            float v = rsn[reg];
            v += __shfl_xor(v, 1); v += __shfl_xor(v, 2);
            v += __shfl_xor(v, 4); v += __shfl_xor(v, 8);
            float btac = v / (rs8[reg] + 1e-12f);
            rs8[reg] = v;
#pragma unroll
            for (int f = 0; f < 4; f++)
                P[f][reg] = R[f][reg] + btac * P[f][reg];
        }
    }

    // ---- output phase ----
#pragma unroll
    for (int reg = 0; reg < 4; reg++)
#pragma unroll
        for (int f = 0; f < 4; f++)
            sPw[4 * quad + reg][16 * f + l16] = f2bf(X[f][reg]);
    __threadfence_block();
    bf16x8 Xa[2];
#pragma unroll
    for (int ks = 0; ks < 2; ks++)
        Xa[ks] = *reinterpret_cast<const bf16x8*>(&sPw[l16][8 * quad + 32 * ks]);
    f32x4 Do[2];
#pragma unroll
    for (int sn = 0; sn < 2; sn++) {
        f32x4 d = __builtin_amdgcn_mfma_f32_16x16x32_bf16(Xa[0], Kb[sn][0], zero4, 0, 0, 0);
        Do[sn] = __builtin_amdgcn_mfma_f32_16x16x32_bf16(Xa[1], Kb[sn][1], d, 0, 0, 0);
    }
#pragma unroll
    for (int sn = 0; sn < 2; sn++)
#pragma unroll
        for (int reg = 0; reg < 4; reg++)
            sMw[4 * quad + reg][16 * sn + l16] = f2bf(Co[sn][reg] * Do[sn][reg]);
    __threadfence_block();
    bf16x8 Mo = *reinterpret_cast<const bf16x8*>(&sMw[l16][8 * quad]);
    bf16x8 Vb[4];
#pragma unroll
    for (int f = 0; f < 4; f++) {
        union { bf16x8 v; unsigned short u[8]; } r;
#pragma unroll
        for (int j = 0; j < 8; j++)
            r.u[j] = f2bf(vbuf[rbase + (size_t)(8 * quad + j) * 1024 + 16 * f + l16]);
        Vb[f] = r.v;
    }
    bf16x8 Hvb[4][2];
#pragma unroll
    for (int f = 0; f < 4; f++) {
        const float* hr = HkvT0 + hbase + (size_t)(16 * f + l16) * 64;
#pragma unroll
        for (int ks = 0; ks < 2; ks++) {
            float4 a = *reinterpret_cast<const float4*>(hr + 8 * quad + 32 * ks);
            float4 c = *reinterpret_cast<const float4*>(hr + 8 * quad + 32 * ks + 4);
            Hvb[f][ks] = pack8(a, c);
        }
    }
    f32x4 O[4];
#pragma unroll
    for (int f = 0; f < 4; f++) {
        f32x4 o1 = __builtin_amdgcn_mfma_f32_16x16x32_bf16(Mo, Vb[f], zero4, 0, 0, 0);
        f32x4 o2 = __builtin_amdgcn_mfma_f32_16x16x32_bf16(Xa[0], Hvb[f][0], zero4, 0, 0, 0);
        o2 = __builtin_amdgcn_mfma_f32_16x16x32_bf16(Xa[1], Hvb[f][1], o2, 0, 0, 0);
#pragma unroll
        for (int reg = 0; reg < 4; reg++)
            O[f][reg] = o1[reg] + et[reg] * o2[reg];
    }
#pragma unroll
    for (int reg = 0; reg < 4; reg++) {
        float s = 0.f;
#pragma unroll
        for (int f = 0; f < 4; f++) s += O[f][reg] * O[f][reg];
        s += __shfl_xor(s, 1); s += __shfl_xor(s, 2);
        s += __shfl_xor(s, 4); s += __shfl_xor(s, 8);
        float scale = rsqrtf(s * (1.f / 64.f) + 1e-5f);
        size_t orow = rbase + (size_t)(rbofs + reg) * 1024;
#pragma unroll
        for (int f = 0; f < 4; f++)
            obf[orow + 16 * f + l16] = f2bf(O[f][reg] * scale * nw[f]);
    }
}

// ---------------------------------------------------------------------------
extern "C" void kernel_launch(void* const* d_in, const int* in_sizes, int n_in,
                              void* d_out, int out_size, void* d_ws, size_t ws_size,
                              hipStream_t stream)
{
    const float* hidden   = (const float*)d_in[0];
    const float* Wq       = (const float*)d_in[1];
    const float* Wk       = (const float*)d_in[2];
    const float* Wv       = (const float*)d_in[3];
    const float* Wa       = (const float*)d_in[4];
    const float* Wb       = (const float*)d_in[5];
    const float* bb       = (const float*)d_in[6];
    const float* A_log    = (const float*)d_in[7];
    const float* dt_bias  = (const float*)d_in[8];
    const float* lambda_p = (const float*)d_in[9];
    const float* Wconv_q  = (const float*)d_in[10];
    const float* Wconv_k  = (const float*)d_in[11];
    const float* norm_w   = (const float*)d_in[12];
    const float* Wo       = (const float*)d_in[13];
    float* out = (float*)d_out;

    float* ws = (float*)d_ws;
    const size_t SZ_BIG = (size_t)2 * T_LEN * HIDN;   // 2M floats
    float* qpre = ws;
    float* kpre = qpre + SZ_BIG;
    float* vbuf = kpre + SZ_BIG;
    float* qbuf = vbuf + SZ_BIG;
    float* kbuf = qbuf + SZ_BIG;
    float* gbuf = kbuf + SZ_BIG;
    float* bbuf = gbuf + 32768;
    float* Gbuf = bbuf + 32768;
    float* btT  = Gbuf + 32768;
    float* Hkk0 = btT + 32768;                        // 4M floats
    float* HkvT0 = Hkk0 + (size_t)32 * NC * 4096;     // 4M floats
    unsigned short* WoT = (unsigned short*)(HkvT0 + (size_t)32 * NC * 4096);

    unsigned short* hidden_bf = (unsigned short*)HkvT0;
    unsigned short* WqT = (unsigned short*)Hkk0;      // WqT|WkT|WvT contiguous
    unsigned short* obuf_bf = (unsigned short*)kpre;

    const int M = 2 * T_LEN;                          // 2048

    cast_bf16<<<(M * HIDN / 4 + 255) / 256, 256, 0, stream>>>(hidden, hidden_bf, M * HIDN / 4);
    dim3 tg(HIDN / 64, HIDN / 64);
    transpose_cast<<<tg, 256, 0, stream>>>(Wq, WqT, HIDN, HIDN);
    transpose_cast<<<tg, 256, 0, stream>>>(Wk, WqT + (size_t)HIDN * HIDN, HIDN, HIDN);
    transpose_cast<<<tg, 256, 0, stream>>>(Wv, WqT + (size_t)2 * HIDN * HIDN, HIDN, HIDN);
    transpose_cast<<<tg, 256, 0, stream>>>(Wo, WoT, HIDN, HIDN);

    dim3 gq(3 * HIDN / 64, M / 64);                   // merged q/k/v
    gemm_qkv<<<gq, 256, 0, stream>>>(hidden_bf, WqT, qpre);
    proj_gb<<<M / 4, 256, 0, stream>>>(hidden, Wa, Wb, bb, A_log, dt_bias, gbuf, bbuf);
    cumsum_g<<<32, 1024, 0, stream>>>(gbuf, bbuf, Gbuf, btT);
    conv_silu_l2<<<M * NH / 4, 256, 0, stream>>>(qpre, Wconv_q, qbuf);
    conv_silu_l2<<<M * NH / 4, 256, 0, stream>>>(kpre, Wconv_k, kbuf);
    chunk_local<<<2048, 256, 0, stream>>>(kbuf, vbuf, Gbuf, btT, Hkk0, HkvT0);
    chunk_prefix<<<256, 256, 0, stream>>>(Hkk0, HkvT0, Gbuf);
    scan_mfma<<<512, 256, 0, stream>>>(qbuf, kbuf, vbuf, Gbuf, btT, Hkk0, HkvT0,
                                       lambda_p, norm_w, obuf_bf);
    dim3 gg(HIDN / 64, M / 64);
    gemm_bf16<<<gg, 256, 0, stream>>>(obuf_bf, WoT, out, M, HIDN, HIDN);
}

// Round 8
// 269.482 us; speedup vs baseline: 3.4060x; 1.0555x over previous
//
#include <hip/hip_runtime.h>
#include <hip/hip_bf16.h>
#include <stdint.h>

#define T_LEN 1024
#define HIDN  1024
#define NH    16
#define DKV   64
#define KCONV 4
#define CG_IT 15
#define CC    32              // chunk length
#define NC    (T_LEN / CC)    // 32 chunks
#define PAD   68              // padded row stride (fp32 LDS tiles)

typedef __attribute__((ext_vector_type(8))) short          bf16x8;
typedef __attribute__((ext_vector_type(8))) unsigned short u16x8;
typedef __attribute__((ext_vector_type(4))) unsigned short u16x4;
typedef __attribute__((ext_vector_type(4))) float          f32x4;

__device__ __forceinline__ float softplusf(float x) {
    return x > 20.f ? x : log1pf(expf(x));
}
__device__ __forceinline__ unsigned short f2bf(float x) {
    __hip_bfloat16 b = __float2bfloat16(x);
    return *reinterpret_cast<unsigned short*>(&b);
}
__device__ __forceinline__ bf16x8 pack8(float4 a, float4 b) {
    union { bf16x8 v; unsigned short u[8]; } r;
    r.u[0] = f2bf(a.x); r.u[1] = f2bf(a.y); r.u[2] = f2bf(a.z); r.u[3] = f2bf(a.w);
    r.u[4] = f2bf(b.x); r.u[5] = f2bf(b.y); r.u[6] = f2bf(b.z); r.u[7] = f2bf(b.w);
    return r.v;
}

// ---------------------------------------------------------------------------
// Fused prep: blocks [0,2048) cast hidden fp32->bf16; blocks [2048,3072)
// transpose+cast the four weight matrices (256 tile-blocks each).
// ---------------------------------------------------------------------------
__global__ __launch_bounds__(256) void prep(const float* __restrict__ hidden,
                                            const float* __restrict__ Wq,
                                            const float* __restrict__ Wk,
                                            const float* __restrict__ Wv,
                                            const float* __restrict__ Wo,
                                            unsigned short* __restrict__ hidden_bf,
                                            unsigned short* __restrict__ WqkvT,
                                            unsigned short* __restrict__ WoT)
{
    __shared__ unsigned short sT[64][68];
    int blk = blockIdx.x;
    int tid = threadIdx.x;
    if (blk < 2048) {
        int i = blk * 256 + tid;
        float4 v = *reinterpret_cast<const float4*>(hidden + (size_t)i * 4);
        u16x4 o;
        o.x = f2bf(v.x); o.y = f2bf(v.y); o.z = f2bf(v.z); o.w = f2bf(v.w);
        *reinterpret_cast<u16x4*>(hidden_bf + (size_t)i * 4) = o;
        return;
    }
    int r = blk - 2048;                 // 0..1023
    int m = r >> 8;                     // matrix 0..3
    int local = r & 255;
    int n0 = (local & 15) * 64, k0 = (local >> 4) * 64;
    const float* W = (m == 0) ? Wq : (m == 1) ? Wk : (m == 2) ? Wv : Wo;
    unsigned short* WT = (m < 3) ? (WqkvT + (size_t)m * HIDN * HIDN) : WoT;

    int rr = tid >> 4, cc4 = (tid & 15) * 4;
#pragma unroll
    for (int p = 0; p < 4; p++) {
        int rw = p * 16 + rr;
        float4 v = *reinterpret_cast<const float4*>(&W[(size_t)(k0 + rw) * HIDN + n0 + cc4]);
        sT[cc4 + 0][rw] = f2bf(v.x);
        sT[cc4 + 1][rw] = f2bf(v.y);
        sT[cc4 + 2][rw] = f2bf(v.z);
        sT[cc4 + 3][rw] = f2bf(v.w);
    }
    __syncthreads();
#pragma unroll
    for (int p = 0; p < 4; p++) {
        int rw = p * 16 + rr;
        u16x4 v = *reinterpret_cast<const u16x4*>(&sT[rw][cc4]);
        *reinterpret_cast<u16x4*>(&WT[(size_t)(n0 + rw) * HIDN + k0 + cc4]) = v;
    }
}

// ---------------------------------------------------------------------------
// bf16 MFMA GEMM (TN): C[M,N] = A[M,K] @ B^T, Bt is [N][K].  64x64 tile.
// (kept for the output projection, N=1024 -> 512 blocks)
// ---------------------------------------------------------------------------
__global__ __launch_bounds__(256) void gemm_bf16(const unsigned short* __restrict__ A,
                                                 const unsigned short* __restrict__ Bt,
                                                 float* __restrict__ C,
                                                 int M, int N, int K)
{
    __shared__ unsigned short sA[64][40];
    __shared__ unsigned short sB[64][40];
    const int tid = threadIdx.x;
    const int bm = blockIdx.y * 64, bn = blockIdx.x * 64;
    const int w = tid >> 6, lane = tid & 63;
    const int l16 = lane & 15, quad = lane >> 4;
    const int lrow = tid >> 2, lk = (tid & 3) * 8;

    f32x4 acc[4];
#pragma unroll
    for (int f = 0; f < 4; f++) acc[f] = (f32x4){0.f, 0.f, 0.f, 0.f};

    const size_t arow = (size_t)(bm + lrow) * K;
    const size_t brow = (size_t)(bn + lrow) * K;

    for (int k0 = 0; k0 < K; k0 += 32) {
        u16x8 av = *reinterpret_cast<const u16x8*>(A + arow + k0 + lk);
        u16x8 bv = *reinterpret_cast<const u16x8*>(Bt + brow + k0 + lk);
        *reinterpret_cast<u16x8*>(&sA[lrow][lk]) = av;
        *reinterpret_cast<u16x8*>(&sB[lrow][lk]) = bv;
        __syncthreads();

        bf16x8 aF = *reinterpret_cast<const bf16x8*>(&sA[w * 16 + l16][quad * 8]);
#pragma unroll
        for (int f = 0; f < 4; f++) {
            bf16x8 bF = *reinterpret_cast<const bf16x8*>(&sB[f * 16 + l16][quad * 8]);
            acc[f] = __builtin_amdgcn_mfma_f32_16x16x32_bf16(aF, bF, acc[f], 0, 0, 0);
        }
        __syncthreads();
    }

#pragma unroll
    for (int f = 0; f < 4; f++) {
#pragma unroll
        for (int i = 0; i < 4; i++) {
            int m = bm + w * 16 + quad * 4 + i;
            C[(size_t)m * N + bn + f * 16 + l16] = acc[f][i];
        }
    }
}

// ---------------------------------------------------------------------------
// Merged q/k/v GEMM, 128x128 tile, BK=32, 4 waves x (4x4 16x16x32 MFMA tiles).
// Bt = [3072][1024]; 64-col groups route to qpre|kpre|vbuf.
// Same per-acc K-chain as the 64-tile version -> bit-identical results.
// ---------------------------------------------------------------------------
__global__ __launch_bounds__(256) void gemm_qkv128(const unsigned short* __restrict__ A,
                                                   const unsigned short* __restrict__ Bt,
                                                   float* __restrict__ C)
{
    const int K = 1024;
    __shared__ unsigned short sA[128][40];
    __shared__ unsigned short sB[128][40];
    const int tid = threadIdx.x;
    const int bm = blockIdx.y * 128;
    const int bn = blockIdx.x * 128;
    const int w = tid >> 6, lane = tid & 63;
    const int l16 = lane & 15, quad = lane >> 4;
    const int wm = (w >> 1) * 64, wn = (w & 1) * 64;
    const int lrow = tid >> 1, lk = (tid & 1) * 16;

    f32x4 acc[4][4];
#pragma unroll
    for (int i = 0; i < 4; i++)
#pragma unroll
        for (int f = 0; f < 4; f++) acc[i][f] = (f32x4){0.f, 0.f, 0.f, 0.f};

    const size_t arow = (size_t)(bm + lrow) * K + lk;
    const size_t brow = (size_t)(bn + lrow) * K + lk;

    for (int k0 = 0; k0 < K; k0 += 32) {
        u16x8 a0 = *reinterpret_cast<const u16x8*>(A + arow + k0);
        u16x8 a1 = *reinterpret_cast<const u16x8*>(A + arow + k0 + 8);
        u16x8 b0 = *reinterpret_cast<const u16x8*>(Bt + brow + k0);
        u16x8 b1 = *reinterpret_cast<const u16x8*>(Bt + brow + k0 + 8);
        *reinterpret_cast<u16x8*>(&sA[lrow][lk])     = a0;
        *reinterpret_cast<u16x8*>(&sA[lrow][lk + 8]) = a1;
        *reinterpret_cast<u16x8*>(&sB[lrow][lk])     = b0;
        *reinterpret_cast<u16x8*>(&sB[lrow][lk + 8]) = b1;
        __syncthreads();

        bf16x8 af[4], bf[4];
#pragma unroll
        for (int i = 0; i < 4; i++)
            af[i] = *reinterpret_cast<const bf16x8*>(&sA[wm + 16 * i + l16][8 * quad]);
#pragma unroll
        for (int f = 0; f < 4; f++)
            bf[f] = *reinterpret_cast<const bf16x8*>(&sB[wn + 16 * f + l16][8 * quad]);
#pragma unroll
        for (int i = 0; i < 4; i++)
#pragma unroll
            for (int f = 0; f < 4; f++)
                acc[i][f] = __builtin_amdgcn_mfma_f32_16x16x32_bf16(af[i], bf[f], acc[i][f], 0, 0, 0);
        __syncthreads();
    }

#pragma unroll
    for (int i = 0; i < 4; i++) {
#pragma unroll
        for (int f = 0; f < 4; f++) {
            int ncol = bn + wn + 16 * f + l16;
            int mat = ncol >> 10, nc = ncol & 1023;
            float* Cb = C + (size_t)mat * (2048u * 1024u) + nc;
            int mrow = bm + wm + 16 * i + 4 * quad;
#pragma unroll
            for (int reg = 0; reg < 4; reg++)
                Cb[(size_t)(mrow + reg) * 1024] = acc[i][f][reg];
        }
    }
}

// ---------------------------------------------------------------------------
// g / beta projections: one wave per row.
// ---------------------------------------------------------------------------
__global__ __launch_bounds__(256) void proj_gb(const float* __restrict__ hidden,
                                               const float* __restrict__ Wa,
                                               const float* __restrict__ Wb,
                                               const float* __restrict__ bb,
                                               const float* __restrict__ A_log,
                                               const float* __restrict__ dt_bias,
                                               float* __restrict__ g_out,
                                               float* __restrict__ beta_out)
{
    int wvid = threadIdx.x >> 6, lane = threadIdx.x & 63;
    int row = blockIdx.x * 4 + wvid;            // 0..2047
    const float* hr = hidden + (size_t)row * HIDN + 16 * lane;
    const float* war = Wa + (size_t)(16 * lane) * NH;
    const float* wbr = Wb + (size_t)(16 * lane) * NH;

    float da[16], db[16];
#pragma unroll
    for (int h = 0; h < 16; h++) { da[h] = 0.f; db[h] = 0.f; }

#pragma unroll
    for (int j = 0; j < 16; j += 4) {
        float4 xv = *reinterpret_cast<const float4*>(hr + j);
        float xs[4] = {xv.x, xv.y, xv.z, xv.w};
#pragma unroll
        for (int e = 0; e < 4; e++) {
            int i = j + e;
            float x = xs[e];
            const float4* wa4 = reinterpret_cast<const float4*>(war + i * NH);
            const float4* wb4 = reinterpret_cast<const float4*>(wbr + i * NH);
#pragma unroll
            for (int q = 0; q < 4; q++) {
                float4 wa = wa4[q], wb = wb4[q];
                da[q * 4 + 0] += x * wa.x; da[q * 4 + 1] += x * wa.y;
                da[q * 4 + 2] += x * wa.z; da[q * 4 + 3] += x * wa.w;
                db[q * 4 + 0] += x * wb.x; db[q * 4 + 1] += x * wb.y;
                db[q * 4 + 2] += x * wb.z; db[q * 4 + 3] += x * wb.w;
            }
        }
    }
#pragma unroll
    for (int m = 1; m < 64; m <<= 1) {
#pragma unroll
        for (int h = 0; h < 16; h++) {
            da[h] += __shfl_xor(da[h], m);
            db[h] += __shfl_xor(db[h], m);
        }
    }
    float dah = 0.f, dbh = 0.f;
#pragma unroll
    for (int h = 0; h < 16; h++) {
        bool sel = (lane == h);
        dah = sel ? da[h] : dah;
        dbh = sel ? db[h] : dbh;
    }
    if (lane < 16) {
        float sp = softplusf(dah + dt_bias[lane]);
        g_out[row * NH + lane]    = -expf(A_log[lane]) * sp;
        beta_out[row * NH + lane] = 1.f / (1.f + expf(-(dbh + bb[lane])));
    }
}

// ---------------------------------------------------------------------------
// Inclusive cumsum of g over t per (b,h); transposes beta to [b,h,t].
// ---------------------------------------------------------------------------
__global__ __launch_bounds__(1024) void cumsum_g(const float* __restrict__ g_in,
                                                 const float* __restrict__ beta_in,
                                                 float* __restrict__ G_out,
                                                 float* __restrict__ betaT)
{
    __shared__ float s[1024];
    int bh = blockIdx.x;
    int b = bh >> 4, h = bh & 15;
    int t = threadIdx.x;
    size_t src = ((size_t)(b * T_LEN) + t) * NH + h;
    s[t] = g_in[src];
    float bt = beta_in[src];
    __syncthreads();
    for (int off = 1; off < 1024; off <<= 1) {
        float tmp = (t >= off) ? s[t - off] : 0.f;
        __syncthreads();
        s[t] += tmp;
        __syncthreads();
    }
    G_out[(size_t)bh * T_LEN + t] = s[t];
    betaT[(size_t)bh * T_LEN + t] = bt;
}

// ---------------------------------------------------------------------------
// causal depthwise conv (K=4) + silu + per-head l2norm.
// ---------------------------------------------------------------------------
__global__ __launch_bounds__(256) void conv_silu_l2(const float* __restrict__ pre,
                                                    const float* __restrict__ Wc,
                                                    float* __restrict__ out)
{
    int gid = blockIdx.x * 4 + (threadIdx.x >> 6);
    int lane = threadIdx.x & 63;
    int h = gid & 15;
    int t = (gid >> 4) & (T_LEN - 1);
    int b = gid >> 14;
    int c = h * DKV + lane;
    float acc = 0.f;
#pragma unroll
    for (int i = 0; i < KCONV; i++) {
        int ts = t - (KCONV - 1) + i;
        if (ts >= 0)
            acc += pre[((size_t)(b * T_LEN) + ts) * HIDN + c] * Wc[c * KCONV + i];
    }
    float y = acc / (1.f + expf(-acc));
    float ss = y * y;
#pragma unroll
    for (int m = 1; m < 64; m <<= 1) ss += __shfl_xor(ss, m);
    out[((size_t)(b * T_LEN) + t) * HIDN + c] = y * rsqrtf(ss + 1e-6f);
}

// ---------------------------------------------------------------------------
// Stage 1: per-chunk local contributions (fully parallel).
// ---------------------------------------------------------------------------
__global__ __launch_bounds__(256) void chunk_local(const float* __restrict__ kbuf,
                                                   const float* __restrict__ vbuf,
                                                   const float* __restrict__ G,
                                                   const float* __restrict__ betaT,
                                                   float* __restrict__ Akk,
                                                   float* __restrict__ AkvT)
{
    __shared__ float sK[CC][PAD];
    __shared__ float sV[CC][PAD];
    __shared__ float sW[CC];
    int bid = blockIdx.x;                 // 2048
    int half = bid & 1;
    int cidx = bid >> 1;
    int chunk = cidx & (NC - 1), bh = cidx >> 5;
    int b = bh >> 4, h = bh & 15;
    int tid = threadIdx.x;
    int i = half * 32 + (tid >> 3);
    int j0 = (tid & 7) * 8;
    int ls = tid >> 3, ld = (tid & 7) * 8;
    int t0 = chunk * CC;

    {
        size_t ga = (((size_t)(b * T_LEN) + t0 + ls) * NH + h) * 64 + ld;
        *reinterpret_cast<float4*>(&sK[ls][ld])     = *reinterpret_cast<const float4*>(&kbuf[ga]);
        *reinterpret_cast<float4*>(&sK[ls][ld + 4]) = *reinterpret_cast<const float4*>(&kbuf[ga + 4]);
        *reinterpret_cast<float4*>(&sV[ls][ld])     = *reinterpret_cast<const float4*>(&vbuf[ga]);
        *reinterpret_cast<float4*>(&sV[ls][ld + 4]) = *reinterpret_cast<const float4*>(&vbuf[ga + 4]);
        if (tid < CC) {
            float gv = G[(size_t)bh * T_LEN + t0 + tid];
            float bv = betaT[(size_t)bh * T_LEN + t0 + tid];
            float gend = __shfl(gv, 31);
            sW[tid] = expf(gend - gv) * bv;
        }
    }
    __syncthreads();

    float akk[8], akv[8];
#pragma unroll
    for (int j = 0; j < 8; j++) { akk[j] = 0.f; akv[j] = 0.f; }
#pragma unroll 4
    for (int s = 0; s < CC; s++) {
        float wk = sW[s] * sK[s][i];
        float wv = sW[s] * sV[s][i];
        float4 ka = *reinterpret_cast<const float4*>(&sK[s][j0]);
        float4 kb = *reinterpret_cast<const float4*>(&sK[s][j0 + 4]);
        akk[0] += wk * ka.x; akk[1] += wk * ka.y; akk[2] += wk * ka.z; akk[3] += wk * ka.w;
        akk[4] += wk * kb.x; akk[5] += wk * kb.y; akk[6] += wk * kb.z; akk[7] += wk * kb.w;
        akv[0] += wv * ka.x; akv[1] += wv * ka.y; akv[2] += wv * ka.z; akv[3] += wv * ka.w;
        akv[4] += wv * kb.x; akv[5] += wv * kb.y; akv[6] += wv * kb.z; akv[7] += wv * kb.w;
    }
    size_t ob = ((size_t)cidx * 64 + i) * 64 + j0;
    *reinterpret_cast<float4*>(&Akk[ob])      = make_float4(akk[0], akk[1], akk[2], akk[3]);
    *reinterpret_cast<float4*>(&Akk[ob + 4])  = make_float4(akk[4], akk[5], akk[6], akk[7]);
    *reinterpret_cast<float4*>(&AkvT[ob])     = make_float4(akv[0], akv[1], akv[2], akv[3]);
    *reinterpret_cast<float4*>(&AkvT[ob + 4]) = make_float4(akv[4], akv[5], akv[6], akv[7]);
}

// ---------------------------------------------------------------------------
// Stage 2: element-parallel prefix over chunks.  Hkk written as BF16 (the same
// f2bf the scan applied before -> bit-identical); HkvT stays fp32 in-place.
// ---------------------------------------------------------------------------
__global__ __launch_bounds__(256) void chunk_prefix(const float* __restrict__ Akk,
                                                    float* __restrict__ HkvT,
                                                    const float* __restrict__ G,
                                                    unsigned short* __restrict__ Hkk_bf)
{
    __shared__ float sDec[NC];
    int blk = blockIdx.x;                 // 256
    int bh = blk >> 3, sub = blk & 7;
    int tid = threadIdx.x;
    if (tid < NC)
        sDec[tid] = (tid > 0)
            ? expf(G[(size_t)bh * T_LEN + tid * CC + CC - 1] - G[(size_t)bh * T_LEN + tid * CC - 1])
            : 1.f;
    __syncthreads();
    int flat = sub * 256 + tid;           // 0..2047
    int mat = flat >> 10, e4 = flat & 1023;
    float4 state = make_float4(0.f, 0.f, 0.f, 0.f);
    if (mat == 0) {
        const float* src = Akk + (size_t)bh * NC * 4096 + (size_t)e4 * 4;
        unsigned short* dst = Hkk_bf + (size_t)bh * NC * 4096 + (size_t)e4 * 4;
#pragma unroll 1
        for (int c = 0; c < NC; c++) {
            float4 a = *reinterpret_cast<const float4*>(src + (size_t)c * 4096);
            u16x4 o;
            o.x = f2bf(state.x); o.y = f2bf(state.y); o.z = f2bf(state.z); o.w = f2bf(state.w);
            *reinterpret_cast<u16x4*>(dst + (size_t)c * 4096) = o;
            float d = sDec[c];
            state.x = d * state.x + a.x;
            state.y = d * state.y + a.y;
            state.z = d * state.z + a.z;
            state.w = d * state.w + a.w;
        }
    } else {
        float* base = HkvT + (size_t)bh * NC * 4096 + (size_t)e4 * 4;
#pragma unroll 1
        for (int c = 0; c < NC; c++) {
            float4* p = reinterpret_cast<float4*>(base + (size_t)c * 4096);
            float4 a = *p;
            *p = state;
            float d = sDec[c];
            state.x = d * state.x + a.x;
            state.y = d * state.y + a.y;
            state.z = d * state.z + a.z;
            state.w = d * state.w + a.w;
        }
    }
}

// ---------------------------------------------------------------------------
// MFMA scan: ONE WAVE per (bh, chunk, half16) -> 2048 waves, 512 blocks.
// ---------------------------------------------------------------------------
__global__ __launch_bounds__(256, 2) void scan_mfma(
    const float* __restrict__ qbuf, const float* __restrict__ kbuf,
    const float* __restrict__ vbuf, const float* __restrict__ G,
    const float* __restrict__ betaT, const unsigned short* __restrict__ Hkk_bf,
    const float* __restrict__ HkvT0, const float* __restrict__ lambda_p,
    const float* __restrict__ norm_w, unsigned short* __restrict__ obf)
{
    __shared__ __align__(16) unsigned short sP[4][16][72];
    __shared__ __align__(16) unsigned short sM[4][16][40];

    const int tid = threadIdx.x;
    const int wv = tid >> 6, lane = tid & 63;
    const int quad = lane >> 4, l16 = lane & 15;
    const int W = blockIdx.x * 4 + wv;          // 0..2047
    const int half = W & 1;
    const int cidx = W >> 1;                    // 0..1023
    const int bh = cidx >> 5, chunk = cidx & 31;
    const int b = bh >> 4, h = bh & 15;
    const int t0 = chunk * CC;
    const int rbofs = 16 * half + 4 * quad;     // +reg -> local t-row
    unsigned short (*sPw)[72] = sP[wv];
    unsigned short (*sMw)[40] = sM[wv];

    const size_t rbase = ((size_t)(b * T_LEN + t0) * NH + h) * 64;
    const float* Gb = G + (size_t)bh * T_LEN + t0;
    const float* Bb = betaT + (size_t)bh * T_LEN + t0;
    const float Gprev = (chunk > 0) ? Gb[-1] : 0.f;

    float Gt[4], et[4];
#pragma unroll
    for (int reg = 0; reg < 4; reg++) {
        float g = Gb[rbofs + reg];
        Gt[reg] = g;
        et[reg] = expf(g - Gprev);
    }
    float Co[2][4];
#pragma unroll
    for (int sn = 0; sn < 2; sn++) {
        int s = 16 * sn + l16;
        float Gs = Gb[s], bts = Bb[s];
#pragma unroll
        for (int reg = 0; reg < 4; reg++) {
            int t = rbofs + reg;
            Co[sn][reg] = (s <= t) ? expf(Gt[reg] - Gs) * bts : 0.f;
        }
    }
    float lam[4], nw[4];
#pragma unroll
    for (int f = 0; f < 4; f++) {
        lam[f] = softplusf(lambda_p[h * 64 + 16 * f + l16]) + 0.25f;
        nw[f]  = norm_w[16 * f + l16];
    }

    bf16x8 Kb[2][2];
#pragma unroll
    for (int sn = 0; sn < 2; sn++) {
        const float* kr = kbuf + rbase + (size_t)(16 * sn + l16) * 1024;
#pragma unroll
        for (int ks = 0; ks < 2; ks++) {
            float4 a = *reinterpret_cast<const float4*>(kr + 8 * quad + 32 * ks);
            float4 c = *reinterpret_cast<const float4*>(kr + 8 * quad + 32 * ks + 4);
            Kb[sn][ks] = pack8(a, c);
        }
    }
    bf16x8 KTb[4];
#pragma unroll
    for (int f = 0; f < 4; f++) {
        union { bf16x8 v; unsigned short u[8]; } r;
#pragma unroll
        for (int j = 0; j < 8; j++)
            r.u[j] = f2bf(kbuf[rbase + (size_t)(8 * quad + j) * 1024 + 16 * f + l16]);
        KTb[f] = r.v;
    }
    const size_t hbase = ((size_t)(bh * NC) + chunk) * 4096;
    bf16x8 Hb[4][2];
#pragma unroll
    for (int f = 0; f < 4; f++) {
        const unsigned short* hr = Hkk_bf + hbase + (size_t)(16 * f + l16) * 64;
#pragma unroll
        for (int ks = 0; ks < 2; ks++)
            Hb[f][ks] = *reinterpret_cast<const bf16x8*>(hr + 8 * quad + 32 * ks);
    }

    f32x4 X[4], R[4], P[4];
    float rs8[4];
#pragma unroll
    for (int reg = 0; reg < 4; reg++) rs8[reg] = 0.f;
#pragma unroll
    for (int f = 0; f < 4; f++) {
#pragma unroll
        for (int reg = 0; reg < 4; reg++) {
            float q = qbuf[rbase + (size_t)(rbofs + reg) * 1024 + 16 * f + l16];
            P[f][reg] = q; R[f][reg] = q; X[f][reg] = 0.f;
            rs8[reg] += q * q;
        }
    }
#pragma unroll
    for (int reg = 0; reg < 4; reg++) {
        float v = rs8[reg];
        v += __shfl_xor(v, 1); v += __shfl_xor(v, 2);
        v += __shfl_xor(v, 4); v += __shfl_xor(v, 8);
        rs8[reg] = v;
    }

    const f32x4 zero4 = {0.f, 0.f, 0.f, 0.f};

#pragma unroll 1
    for (int it = 0; it < CG_IT; it++) {
#pragma unroll
        for (int reg = 0; reg < 4; reg++)
#pragma unroll
            for (int f = 0; f < 4; f++)
                sPw[4 * quad + reg][16 * f + l16] = f2bf(P[f][reg]);
        __threadfence_block();
        bf16x8 Pa[2];
#pragma unroll
        for (int ks = 0; ks < 2; ks++)
            Pa[ks] = *reinterpret_cast<const bf16x8*>(&sPw[l16][8 * quad + 32 * ks]);
        f32x4 D[2];
#pragma unroll
        for (int sn = 0; sn < 2; sn++) {
            f32x4 d = __builtin_amdgcn_mfma_f32_16x16x32_bf16(Pa[0], Kb[sn][0], zero4, 0, 0, 0);
            D[sn] = __builtin_amdgcn_mfma_f32_16x16x32_bf16(Pa[1], Kb[sn][1], d, 0, 0, 0);
        }
#pragma unroll
        for (int sn = 0; sn < 2; sn++)
#pragma unroll
            for (int reg = 0; reg < 4; reg++)
                sMw[4 * quad + reg][16 * sn + l16] = f2bf(Co[sn][reg] * D[sn][reg]);
        __threadfence_block();
        bf16x8 Ma = *reinterpret_cast<const bf16x8*>(&sMw[l16][8 * quad]);
        f32x4 AP[4], A2[4];
#pragma unroll
        for (int f = 0; f < 4; f++) {
            AP[f] = __builtin_amdgcn_mfma_f32_16x16x32_bf16(Ma, KTb[f], zero4, 0, 0, 0);
            f32x4 a = __builtin_amdgcn_mfma_f32_16x16x32_bf16(Pa[0], Hb[f][0], zero4, 0, 0, 0);
            A2[f] = __builtin_amdgcn_mfma_f32_16x16x32_bf16(Pa[1], Hb[f][1], a, 0, 0, 0);
        }
#pragma unroll
        for (int f = 0; f < 4; f++)
#pragma unroll
            for (int reg = 0; reg < 4; reg++)
                AP[f][reg] = lam[f] * P[f][reg] + AP[f][reg] + et[reg] * A2[f][reg];
        float alpha[4], rsn[4];
#pragma unroll
        for (int reg = 0; reg < 4; reg++) {
            float s = 0.f;
#pragma unroll
            for (int f = 0; f < 4; f++) s += P[f][reg] * AP[f][reg];
            s += __shfl_xor(s, 1); s += __shfl_xor(s, 2);
            s += __shfl_xor(s, 4); s += __shfl_xor(s, 8);
            alpha[reg] = rs8[reg] / (s + 1e-12f);
            rsn[reg] = 0.f;
        }
#pragma unroll
        for (int f = 0; f < 4; f++)
#pragma unroll
            for (int reg = 0; reg < 4; reg++) {
                X[f][reg] += alpha[reg] * P[f][reg];
                float rv = R[f][reg] - alpha[reg] * AP[f][reg];
                R[f][reg] = rv;
                rsn[reg] += rv * rv;
            }
#pragma unroll
        for (int reg = 0; reg < 4; reg++) {
            float v = rsn[reg];
            v += __shfl_xor(v, 1); v += __shfl_xor(v, 2);
            v += __shfl_xor(v, 4); v += __shfl_xor(v, 8);
            float btac = v / (rs8[reg] + 1e-12f);
            rs8[reg] = v;
#pragma unroll
            for (int f = 0; f < 4; f++)
                P[f][reg] = R[f][reg] + btac * P[f][reg];
        }
    }

    // ---- output phase ----
#pragma unroll
    for (int reg = 0; reg < 4; reg++)
#pragma unroll
        for (int f = 0; f < 4; f++)
            sPw[4 * quad + reg][16 * f + l16] = f2bf(X[f][reg]);
    __threadfence_block();
    bf16x8 Xa[2];
#pragma unroll
    for (int ks = 0; ks < 2; ks++)
        Xa[ks] = *reinterpret_cast<const bf16x8*>(&sPw[l16][8 * quad + 32 * ks]);
    f32x4 Do[2];
#pragma unroll
    for (int sn = 0; sn < 2; sn++) {
        f32x4 d = __builtin_amdgcn_mfma_f32_16x16x32_bf16(Xa[0], Kb[sn][0], zero4, 0, 0, 0);
        Do[sn] = __builtin_amdgcn_mfma_f32_16x16x32_bf16(Xa[1], Kb[sn][1], d, 0, 0, 0);
    }
#pragma unroll
    for (int sn = 0; sn < 2; sn++)
#pragma unroll
        for (int reg = 0; reg < 4; reg++)
            sMw[4 * quad + reg][16 * sn + l16] = f2bf(Co[sn][reg] * Do[sn][reg]);
    __threadfence_block();
    bf16x8 Mo = *reinterpret_cast<const bf16x8*>(&sMw[l16][8 * quad]);
    bf16x8 Vb[4];
#pragma unroll
    for (int f = 0; f < 4; f++) {
        union { bf16x8 v; unsigned short u[8]; } r;
#pragma unroll
        for (int j = 0; j < 8; j++)
            r.u[j] = f2bf(vbuf[rbase + (size_t)(8 * quad + j) * 1024 + 16 * f + l16]);
        Vb[f] = r.v;
    }
    bf16x8 Hvb[4][2];
#pragma unroll
    for (int f = 0; f < 4; f++) {
        const float* hr = HkvT0 + hbase + (size_t)(16 * f + l16) * 64;
#pragma unroll
        for (int ks = 0; ks < 2; ks++) {
            float4 a = *reinterpret_cast<const float4*>(hr + 8 * quad + 32 * ks);
            float4 c = *reinterpret_cast<const float4*>(hr + 8 * quad + 32 * ks + 4);
            Hvb[f][ks] = pack8(a, c);
        }
    }
    f32x4 O[4];
#pragma unroll
    for (int f = 0; f < 4; f++) {
        f32x4 o1 = __builtin_amdgcn_mfma_f32_16x16x32_bf16(Mo, Vb[f], zero4, 0, 0, 0);
        f32x4 o2 = __builtin_amdgcn_mfma_f32_16x16x32_bf16(Xa[0], Hvb[f][0], zero4, 0, 0, 0);
        o2 = __builtin_amdgcn_mfma_f32_16x16x32_bf16(Xa[1], Hvb[f][1], o2, 0, 0, 0);
#pragma unroll
        for (int reg = 0; reg < 4; reg++)
            O[f][reg] = o1[reg] + et[reg] * o2[reg];
    }
#pragma unroll
    for (int reg = 0; reg < 4; reg++) {
        float s = 0.f;
#pragma unroll
        for (int f = 0; f < 4; f++) s += O[f][reg] * O[f][reg];
        s += __shfl_xor(s, 1); s += __shfl_xor(s, 2);
        s += __shfl_xor(s, 4); s += __shfl_xor(s, 8);
        float scale = rsqrtf(s * (1.f / 64.f) + 1e-5f);
        size_t orow = rbase + (size_t)(rbofs + reg) * 1024;
#pragma unroll
        for (int f = 0; f < 4; f++)
            obf[orow + 16 * f + l16] = f2bf(O[f][reg] * scale * nw[f]);
    }
}

// ---------------------------------------------------------------------------
extern "C" void kernel_launch(void* const* d_in, const int* in_sizes, int n_in,
                              void* d_out, int out_size, void* d_ws, size_t ws_size,
                              hipStream_t stream)
{
    const float* hidden   = (const float*)d_in[0];
    const float* Wq       = (const float*)d_in[1];
    const float* Wk       = (const float*)d_in[2];
    const float* Wv       = (const float*)d_in[3];
    const float* Wa       = (const float*)d_in[4];
    const float* Wb       = (const float*)d_in[5];
    const float* bb       = (const float*)d_in[6];
    const float* A_log    = (const float*)d_in[7];
    const float* dt_bias  = (const float*)d_in[8];
    const float* lambda_p = (const float*)d_in[9];
    const float* Wconv_q  = (const float*)d_in[10];
    const float* Wconv_k  = (const float*)d_in[11];
    const float* norm_w   = (const float*)d_in[12];
    const float* Wo       = (const float*)d_in[13];
    float* out = (float*)d_out;

    float* ws = (float*)d_ws;
    const size_t SZ_BIG = (size_t)2 * T_LEN * HIDN;   // 2M floats
    float* qpre = ws;
    float* kpre = qpre + SZ_BIG;
    float* vbuf = kpre + SZ_BIG;
    float* qbuf = vbuf + SZ_BIG;
    float* kbuf = qbuf + SZ_BIG;
    float* gbuf = kbuf + SZ_BIG;
    float* bbuf = gbuf + 32768;
    float* Gbuf = bbuf + 32768;
    float* btT  = Gbuf + 32768;
    float* Hkk0 = btT + 32768;                        // 4M floats (Akk)
    float* HkvT0 = Hkk0 + (size_t)32 * NC * 4096;     // 4M floats (AkvT -> HkvT)
    unsigned short* WoT = (unsigned short*)(HkvT0 + (size_t)32 * NC * 4096);

    unsigned short* hidden_bf = (unsigned short*)HkvT0;   // dead before chunk_local
    unsigned short* WqkvT = (unsigned short*)Hkk0;        // dead before chunk_local
    unsigned short* obuf_bf = (unsigned short*)kpre;      // kpre dead after conv
    unsigned short* Hkk_bf = (unsigned short*)qpre;       // qpre dead after conv

    const int M = 2 * T_LEN;                          // 2048

    prep<<<3072, 256, 0, stream>>>(hidden, Wq, Wk, Wv, Wo, hidden_bf, WqkvT, WoT);

    dim3 gq(3 * HIDN / 128, M / 128);                 // (24, 16)
    gemm_qkv128<<<gq, 256, 0, stream>>>(hidden_bf, WqkvT, qpre);
    proj_gb<<<M / 4, 256, 0, stream>>>(hidden, Wa, Wb, bb, A_log, dt_bias, gbuf, bbuf);
    cumsum_g<<<32, 1024, 0, stream>>>(gbuf, bbuf, Gbuf, btT);
    conv_silu_l2<<<M * NH / 4, 256, 0, stream>>>(qpre, Wconv_q, qbuf);
    conv_silu_l2<<<M * NH / 4, 256, 0, stream>>>(kpre, Wconv_k, kbuf);
    chunk_local<<<2048, 256, 0, stream>>>(kbuf, vbuf, Gbuf, btT, Hkk0, HkvT0);
    chunk_prefix<<<256, 256, 0, stream>>>(Hkk0, HkvT0, Gbuf, Hkk_bf);
    scan_mfma<<<512, 256, 0, stream>>>(qbuf, kbuf, vbuf, Gbuf, btT, Hkk_bf, HkvT0,
                                       lambda_p, norm_w, obuf_bf);
    dim3 gg(HIDN / 64, M / 64);
    gemm_bf16<<<gg, 256, 0, stream>>>(obuf_bf, WoT, out, M, HIDN, HIDN);
}